// Round 1
// baseline (5718.175 us; speedup 1.0000x reference)
//
#include <hip/hip_runtime.h>
#include <math.h>

#define EPS 1e-4f

__device__ __forceinline__ float sigmoidf_(float x){ return 1.0f/(1.0f+expf(-x)); }

// ---- ordered-uint mapping for float atomic min/max ----
__device__ __forceinline__ unsigned f2u_(float f){
    unsigned u = __float_as_uint(f);
    return (u & 0x80000000u) ? ~u : (u | 0x80000000u);
}
__device__ __forceinline__ float u2f_(unsigned u){
    unsigned b = (u & 0x80000000u) ? (u & 0x7FFFFFFFu) : ~u;
    return __uint_as_float(b);
}

// ================= min/max of pos =================
__global__ void minmax_kernel(const float* __restrict__ p, int n, unsigned* mm){
    float lo = INFINITY, hi = -INFINITY;
    for (int i = blockIdx.x*blockDim.x + threadIdx.x; i < n; i += gridDim.x*blockDim.x){
        float v = p[i]; lo = fminf(lo, v); hi = fmaxf(hi, v);
    }
    for (int off = 32; off > 0; off >>= 1){
        lo = fminf(lo, __shfl_down(lo, off));
        hi = fmaxf(hi, __shfl_down(hi, off));
    }
    __shared__ float slo[8], shi[8];
    int wid = threadIdx.x >> 6;
    if ((threadIdx.x & 63) == 0){ slo[wid] = lo; shi[wid] = hi; }
    __syncthreads();
    if (threadIdx.x == 0){
        int nw = blockDim.x >> 6;
        for (int w = 1; w < nw; w++){ lo = fminf(lo, slo[w]); hi = fmaxf(hi, shi[w]); }
        atomicMin(&mm[0], f2u_(lo));
        atomicMax(&mm[1], f2u_(hi));
    }
}

// ================= spline conv over edges =================
// W staged in LDS with stride 17 to break bank aliasing on k*16.
__global__ void spline_kernel(const float* __restrict__ x, const float* __restrict__ pseudo,
                              const int* __restrict__ ei, const float* __restrict__ W,
                              float* __restrict__ agg, float* __restrict__ deg, int E){
    __shared__ float Ws[125*17];
    for (int i = threadIdx.x; i < 125*16; i += blockDim.x)
        Ws[(i >> 4)*17 + (i & 15)] = W[i];
    __syncthreads();
    int e = blockIdx.x*blockDim.x + threadIdx.x;
    if (e >= E) return;
    int s = ei[e], d = ei[E + e];
    float p0 = pseudo[3*e], p1 = pseudo[3*e+1], p2 = pseudo[3*e+2];
    float v0 = p0*4.f, v1 = p1*4.f, v2 = p2*4.f;
    float f0 = fminf(fmaxf(floorf(v0), 0.f), 3.f);
    float f1 = fminf(fmaxf(floorf(v1), 0.f), 3.f);
    float f2 = fminf(fmaxf(floorf(v2), 0.f), 3.f);
    float fr0 = v0 - f0, fr1 = v1 - f1, fr2 = v2 - f2;
    int i0 = (int)f0, i1 = (int)f1, i2 = (int)f2;
    float wk[16];
    #pragma unroll
    for (int o = 0; o < 16; o++) wk[o] = 0.f;
    #pragma unroll
    for (int b = 0; b < 8; b++){
        int b0 = (b >> 2) & 1, b1 = (b >> 1) & 1, b2 = b & 1;
        float w = (b0 ? fr0 : 1.f - fr0) * (b1 ? fr1 : 1.f - fr1) * (b2 ? fr2 : 1.f - fr2);
        int k = ((i0 + b0)*5 + (i1 + b1))*5 + (i2 + b2);
        const float* Wr = &Ws[k*17];
        #pragma unroll
        for (int o = 0; o < 16; o++) wk[o] += w * Wr[o];
    }
    float xs = x[s];
    float* ad = &agg[(size_t)d*16];
    #pragma unroll
    for (int o = 0; o < 16; o++) atomicAdd(&ad[o], xs * wk[o]);
    atomicAdd(&deg[d], 1.0f);
}

// ================= node finalize: h -> elu -> lin -> normalized quat =================
__global__ void node_kernel(const float* __restrict__ x, const float* __restrict__ agg,
                            const float* __restrict__ deg,
                            const float* __restrict__ root, const float* __restrict__ bias,
                            const float* __restrict__ lin_w, const float* __restrict__ lin_b,
                            float* __restrict__ pose, float* __restrict__ act, int N){
    int n = blockIdx.x*blockDim.x + threadIdx.x;
    if (n >= N) return;
    float xs = x[n];
    float dg = fmaxf(deg[n], 1.0f);
    float qv0 = lin_b[0], qv1 = lin_b[1], qv2 = lin_b[2], qv3 = lin_b[3];
    #pragma unroll
    for (int o = 0; o < 16; o++){
        float h = agg[(size_t)n*16 + o] / dg + xs * root[o] + bias[o];
        float e = (h > 0.f) ? h : expm1f(h);
        qv0 += e * lin_w[o*4 + 0];
        qv1 += e * lin_w[o*4 + 1];
        qv2 += e * lin_w[o*4 + 2];
        qv3 += e * lin_w[o*4 + 3];
    }
    float inv = 1.0f / (sqrtf(qv0*qv0 + qv1*qv1 + qv2*qv2 + qv3*qv3) + EPS);
    pose[(size_t)n*4 + 0] = qv0*inv;
    pose[(size_t)n*4 + 1] = qv1*inv;
    pose[(size_t)n*4 + 2] = qv2*inv;
    pose[(size_t)n*4 + 3] = qv3*inv;
    act[n] = xs;
}

// ================= capsule routing layer =================
template<int I, int J>
__device__ __forceinline__ void pred_ij(const float* qn, int i, int j,
                                        float rx, float ry, float rz, float rw,
                                        float& ox, float& oy, float& oz, float& ow){
    const float* qq = &qn[(i*J + j)*4];
    float qx = qq[0], qy = qq[1], qz = qq[2], qw = qq[3];
    float tx = qw*rx + qx*rw + qy*rz - qz*ry;
    float ty = qw*ry - qx*rz + qy*rw + qz*rx;
    float tz = qw*rz + qx*ry - qy*rx + qz*rw;
    float tw = qw*rw - qx*rx - qy*ry - qz*rz;
    float inv = 1.0f / (sqrtf(tx*tx + ty*ty + tz*tz + tw*tw) + EPS);
    ox = tx*inv; oy = ty*inv; oz = tz*inv; ow = tw*inv;
}

template<int I, int J>
__global__ void caps_kernel(const float* __restrict__ poseIn, const float* __restrict__ actIn,
                            const float* __restrict__ q, float* __restrict__ poseOut,
                            float* __restrict__ actOut, int N){
    __shared__ float qn[I*J*4];
    for (int t = threadIdx.x; t < I*J; t += blockDim.x){
        float a = q[t*4], b = q[t*4+1], c = q[t*4+2], d = q[t*4+3];
        float inv = 1.0f / (sqrtf(a*a + b*b + c*c + d*d) + EPS);
        qn[t*4] = a*inv; qn[t*4+1] = b*inv; qn[t*4+2] = c*inv; qn[t*4+3] = d*inv;
    }
    __syncthreads();
    int n = blockIdx.x*blockDim.x + threadIdx.x;
    if (n >= N) return;

    float px[I], py[I], pz[I], pw[I], a[I];
    #pragma unroll
    for (int i = 0; i < I; i++){
        size_t base = ((size_t)n*I + i)*4;
        px[i] = poseIn[base]; py[i] = poseIn[base+1];
        pz[i] = poseIn[base+2]; pw[i] = poseIn[base+3];
        a[i] = actIn[(size_t)n*I + i];
    }
    float bb[I][J], cc[I][J], v[J][4], logit[J];
    #pragma unroll
    for (int i = 0; i < I; i++)
        #pragma unroll
        for (int j = 0; j < J; j++) bb[i][j] = 0.f;

    for (int t = 0; t < 3; t++){
        // c = softmax(b over J) * act
        #pragma unroll
        for (int i = 0; i < I; i++){
            float mb = bb[i][0];
            #pragma unroll
            for (int j = 1; j < J; j++) mb = fmaxf(mb, bb[i][j]);
            float sum = 0.f;
            #pragma unroll
            for (int j = 0; j < J; j++){ float e = expf(bb[i][j] - mb); cc[i][j] = e; sum += e; }
            float sc = a[i] / sum;
            #pragma unroll
            for (int j = 0; j < J; j++) cc[i][j] *= sc;
        }
        // s = sum_i c * pred ; v = normalize(s)
        #pragma unroll
        for (int j = 0; j < J; j++){ v[j][0]=0.f; v[j][1]=0.f; v[j][2]=0.f; v[j][3]=0.f; }
        #pragma unroll
        for (int i = 0; i < I; i++){
            #pragma unroll
            for (int j = 0; j < J; j++){
                float ox, oy, oz, ow;
                pred_ij<I,J>(qn, i, j, px[i], py[i], pz[i], pw[i], ox, oy, oz, ow);
                float ci = cc[i][j];
                v[j][0] += ci*ox; v[j][1] += ci*oy; v[j][2] += ci*oz; v[j][3] += ci*ow;
            }
        }
        #pragma unroll
        for (int j = 0; j < J; j++){
            float inv = 1.0f / (sqrtf(v[j][0]*v[j][0] + v[j][1]*v[j][1] +
                                      v[j][2]*v[j][2] + v[j][3]*v[j][3]) + EPS);
            v[j][0] *= inv; v[j][1] *= inv; v[j][2] *= inv; v[j][3] *= inv;
        }
        if (t < 2){
            #pragma unroll
            for (int i = 0; i < I; i++)
                #pragma unroll
                for (int j = 0; j < J; j++){
                    float ox, oy, oz, ow;
                    pred_ij<I,J>(qn, i, j, px[i], py[i], pz[i], pw[i], ox, oy, oz, ow);
                    bb[i][j] += ox*v[j][0] + oy*v[j][1] + oz*v[j][2] + ow*v[j][3];
                }
        } else {
            #pragma unroll
            for (int j = 0; j < J; j++) logit[j] = 0.f;
            #pragma unroll
            for (int i = 0; i < I; i++)
                #pragma unroll
                for (int j = 0; j < J; j++){
                    float ox, oy, oz, ow;
                    pred_ij<I,J>(qn, i, j, px[i], py[i], pz[i], pw[i], ox, oy, oz, ow);
                    logit[j] += cc[i][j]*(ox*v[j][0] + oy*v[j][1] + oz*v[j][2] + ow*v[j][3]);
                }
        }
    }
    #pragma unroll
    for (int j = 0; j < J; j++){
        size_t base = ((size_t)n*J + j)*4;
        poseOut[base]   = v[j][0];
        poseOut[base+1] = v[j][1];
        poseOut[base+2] = v[j][2];
        poseOut[base+3] = v[j][3];
        actOut[(size_t)n*J + j] = sigmoidf_(logit[j]);
    }
}

// ================= pooling =================
__device__ __forceinline__ int voxel_id(const float* __restrict__ pos, int n, int G,
                                        float start, float size){
    int g[3];
    #pragma unroll
    for (int k = 0; k < 3; k++){
        float gg = floorf((pos[(size_t)n*3 + k] - start) / size);
        gg = fminf(fmaxf(gg, 0.f), (float)(G - 1));
        g[k] = (int)gg;
    }
    return (g[0]*G + g[1])*G + g[2];
}

__device__ __forceinline__ void pool_geom(const unsigned* mm, int G, int mode,
                                          float& start, float& size){
    float mn = u2f_(mm[0]), mx = u2f_(mm[1]);
    if (mode == 0){ start = mn; size = (mx + 0.001f - mn) / (float)G; }
    else          { start = mn - 0.5f; size = mx - mn + 1.0f; }
}

__global__ void pool_scatter1(const float* __restrict__ pose, const float* __restrict__ act,
                              const float* __restrict__ pos,
                              float* __restrict__ s, float* __restrict__ wsum,
                              float* __restrict__ cnt, float* __restrict__ psum,
                              int N, int J, int G, int mode, const unsigned* __restrict__ mm){
    int n = blockIdx.x*blockDim.x + threadIdx.x;
    if (n >= N) return;
    float start, size; pool_geom(mm, G, mode, start, size);
    int vid = voxel_id(pos, n, G, start, size);
    for (int j = 0; j < J; j++){
        float aj = act[(size_t)n*J + j];
        size_t pb = ((size_t)n*J + j)*4;
        size_t sb = ((size_t)vid*J + j)*4;
        atomicAdd(&s[sb],   aj*pose[pb]);
        atomicAdd(&s[sb+1], aj*pose[pb+1]);
        atomicAdd(&s[sb+2], aj*pose[pb+2]);
        atomicAdd(&s[sb+3], aj*pose[pb+3]);
        atomicAdd(&wsum[(size_t)vid*J + j], aj);
    }
    atomicAdd(&cnt[vid], 1.0f);
    atomicAdd(&psum[(size_t)vid*3 + 0], pos[(size_t)n*3 + 0]);
    atomicAdd(&psum[(size_t)vid*3 + 1], pos[(size_t)n*3 + 1]);
    atomicAdd(&psum[(size_t)vid*3 + 2], pos[(size_t)n*3 + 2]);
}

__global__ void pool_m(const float* __restrict__ s, float* __restrict__ m, int VJ){
    int t = blockIdx.x*blockDim.x + threadIdx.x;
    if (t >= VJ) return;
    float a = s[(size_t)t*4], b = s[(size_t)t*4+1], c = s[(size_t)t*4+2], d = s[(size_t)t*4+3];
    float inv = 1.0f / (sqrtf(a*a + b*b + c*c + d*d) + EPS);
    m[(size_t)t*4]   = a*inv;
    m[(size_t)t*4+1] = b*inv;
    m[(size_t)t*4+2] = c*inv;
    m[(size_t)t*4+3] = d*inv;
}

__global__ void pool_scatter2(const float* __restrict__ pose, const float* __restrict__ act,
                              const float* __restrict__ pos, const float* __restrict__ m,
                              float* __restrict__ agacc,
                              int N, int J, int G, int mode, const unsigned* __restrict__ mm){
    int n = blockIdx.x*blockDim.x + threadIdx.x;
    if (n >= N) return;
    float start, size; pool_geom(mm, G, mode, start, size);
    int vid = voxel_id(pos, n, G, start, size);
    for (int j = 0; j < J; j++){
        size_t pb = ((size_t)n*J + j)*4;
        size_t mb = ((size_t)vid*J + j)*4;
        float agree = pose[pb]*m[mb] + pose[pb+1]*m[mb+1] + pose[pb+2]*m[mb+2] + pose[pb+3]*m[mb+3];
        atomicAdd(&agacc[(size_t)vid*J + j], act[(size_t)n*J + j]*agree);
    }
}

__global__ void pool_fin(const float* __restrict__ agacc, const float* __restrict__ wsum,
                         const float* __restrict__ cnt, const float* __restrict__ psum,
                         float* __restrict__ actOut, float* __restrict__ posOut, int V, int J){
    int t = blockIdx.x*blockDim.x + threadIdx.x;
    if (t >= V*J) return;
    int v = t / J, j = t % J;
    actOut[t] = sigmoidf_(agacc[t] / (wsum[t] + EPS));
    if (j == 0){
        float c = cnt[v] + EPS;
        posOut[(size_t)v*3 + 0] = psum[(size_t)v*3 + 0] / c;
        posOut[(size_t)v*3 + 1] = psum[(size_t)v*3 + 1] / c;
        posOut[(size_t)v*3 + 2] = psum[(size_t)v*3 + 2] / c;
    }
}

// ================= host-side pool sequence =================
static void pool_run(hipStream_t stream, const float* poseIn, const float* actIn, const float* posIn,
                     int N, int J, int G, int mode, const unsigned* mm,
                     float* s, float* wsum, float* agacc, float* cnt, float* psum,
                     float* mOut, float* actOut, float* posOut){
    int V = G*G*G;
    hipMemsetAsync(s,     0, (size_t)V*J*4*sizeof(float), stream);
    hipMemsetAsync(wsum,  0, (size_t)V*J*sizeof(float),   stream);
    hipMemsetAsync(agacc, 0, (size_t)V*J*sizeof(float),   stream);
    hipMemsetAsync(cnt,   0, (size_t)V*sizeof(float),     stream);
    hipMemsetAsync(psum,  0, (size_t)V*3*sizeof(float),   stream);
    int gN = (N + 255)/256, gV = (V*J + 255)/256;
    pool_scatter1<<<gN, 256, 0, stream>>>(poseIn, actIn, posIn, s, wsum, cnt, psum, N, J, G, mode, mm);
    pool_m<<<gV, 256, 0, stream>>>(s, mOut, V*J);
    pool_scatter2<<<gN, 256, 0, stream>>>(poseIn, actIn, posIn, mOut, agacc, N, J, G, mode, mm);
    pool_fin<<<gV, 256, 0, stream>>>(agacc, wsum, cnt, psum, actOut, posOut, V, J);
}

extern "C" void kernel_launch(void* const* d_in, const int* in_sizes, int n_in,
                              void* d_out, int out_size, void* d_ws, size_t ws_size,
                              hipStream_t stream){
    const float* x      = (const float*)d_in[0];
    const float* pos    = (const float*)d_in[1];
    const float* pseudo = (const float*)d_in[2];
    const float* Wsp    = (const float*)d_in[3];
    const float* root   = (const float*)d_in[4];
    const float* bias   = (const float*)d_in[5];
    const float* lin_w  = (const float*)d_in[6];
    const float* lin_b  = (const float*)d_in[7];
    const float* q0     = (const float*)d_in[8];
    const float* q1     = (const float*)d_in[9];
    const float* q3     = (const float*)d_in[10];
    const float* q5     = (const float*)d_in[11];
    const float* q6     = (const float*)d_in[12];
    const float* q7     = (const float*)d_in[13];
    const int*   ei     = (const int*)d_in[14];
    const int N = in_sizes[0];
    const int E = in_sizes[2] / 3;

    char* ws = (char*)d_ws;
    size_t off = 0;
    auto alloc = [&](size_t bytes)->void*{
        void* p = ws + off;
        off += (bytes + 255) & ~(size_t)255;
        return p;
    };
    unsigned* mm = (unsigned*)alloc(8);
    float* agg = (float*)alloc((size_t)N*16*sizeof(float));
    float* deg = (float*)alloc((size_t)N*sizeof(float));
    float* P0  = (float*)alloc((size_t)1250000*sizeof(float));
    float* P1  = (float*)alloc((size_t)1250000*sizeof(float));
    float* A0  = (float*)alloc((size_t)310000*sizeof(float));
    float* A1  = (float*)alloc((size_t)310000*sizeof(float));
    float* PB0 = (float*)alloc((size_t)100000*sizeof(float));
    float* PB1 = (float*)alloc((size_t)100000*sizeof(float));
    float* vs  = (float*)alloc((size_t)800000*sizeof(float));
    float* vw  = (float*)alloc((size_t)200000*sizeof(float));
    float* va  = (float*)alloc((size_t)200000*sizeof(float));
    float* vc  = (float*)alloc((size_t)33000*sizeof(float));
    float* vp  = (float*)alloc((size_t)100000*sizeof(float));

    hipMemsetAsync(mm,     0xFF, 4, stream);   // min slot = 0xFFFFFFFF
    hipMemsetAsync(mm + 1, 0x00, 4, stream);   // max slot = 0
    hipMemsetAsync(agg, 0, (size_t)N*16*sizeof(float), stream);
    hipMemsetAsync(deg, 0, (size_t)N*sizeof(float), stream);

    minmax_kernel<<<80, 256, 0, stream>>>(pos, N*3, mm);
    spline_kernel<<<(E + 255)/256, 256, 0, stream>>>(x, pseudo, ei, Wsp, agg, deg, E);
    node_kernel<<<(N + 255)/256, 256, 0, stream>>>(x, agg, deg, root, bias, lin_w, lin_b, P0, A0, N);

    caps_kernel<1,6><<<(N + 63)/64, 64, 0, stream>>>(P0, A0, q0, P1, A1, N);
    caps_kernel<6,6><<<(N + 63)/64, 64, 0, stream>>>(P1, A1, q1, P0, A0, N);

    // pool1: 50000 nodes -> 32768 voxels (G=32), J=6
    pool_run(stream, P0, A0, pos, N, 6, 32, 0, mm, vs, vw, va, vc, vp, P1, A1, PB0);
    caps_kernel<6,8><<<(32768 + 63)/64, 64, 0, stream>>>(P1, A1, q3, P0, A0, 32768);

    // pool2: 32768 -> 512 (G=8), J=8
    pool_run(stream, P0, A0, PB0, 32768, 8, 8, 0, mm, vs, vw, va, vc, vp, P1, A1, PB1);
    caps_kernel<8,12><<<(512 + 63)/64, 64, 0, stream>>>(P1, A1, q5, P0, A0, 512);

    // pool3: 512 -> 8 (G=2), J=12
    pool_run(stream, P0, A0, PB1, 512, 12, 2, 0, mm, vs, vw, va, vc, vp, P1, A1, PB0);
    caps_kernel<12,14><<<1, 64, 0, stream>>>(P1, A1, q6, P0, A0, 8);

    // pool4: 8 -> 1 (G=1, mode=1), J=14
    pool_run(stream, P0, A0, PB0, 8, 14, 1, 1, mm, vs, vw, va, vc, vp, P1, A1, PB1);
    caps_kernel<14,10><<<1, 64, 0, stream>>>(P1, A1, q7, P0, (float*)d_out, 1);
}

// Round 2
// 3797.935 us; speedup vs baseline: 1.5056x; 1.5056x over previous
//
#include <hip/hip_runtime.h>
#include <math.h>

#define EPS 1e-4f

__device__ __forceinline__ float sigmoidf_(float x){ return 1.0f/(1.0f+expf(-x)); }

// ---- ordered-uint mapping for float atomic min/max ----
__device__ __forceinline__ unsigned f2u_(float f){
    unsigned u = __float_as_uint(f);
    return (u & 0x80000000u) ? ~u : (u | 0x80000000u);
}
__device__ __forceinline__ float u2f_(unsigned u){
    unsigned b = (u & 0x80000000u) ? (u & 0x7FFFFFFFu) : ~u;
    return __uint_as_float(b);
}

// ================= min/max of pos =================
__global__ void minmax_kernel(const float* __restrict__ p, int n, unsigned* mm){
    float lo = INFINITY, hi = -INFINITY;
    for (int i = blockIdx.x*blockDim.x + threadIdx.x; i < n; i += gridDim.x*blockDim.x){
        float v = p[i]; lo = fminf(lo, v); hi = fmaxf(hi, v);
    }
    for (int off = 32; off > 0; off >>= 1){
        lo = fminf(lo, __shfl_down(lo, off));
        hi = fmaxf(hi, __shfl_down(hi, off));
    }
    __shared__ float slo[8], shi[8];
    int wid = threadIdx.x >> 6;
    if ((threadIdx.x & 63) == 0){ slo[wid] = lo; shi[wid] = hi; }
    __syncthreads();
    if (threadIdx.x == 0){
        int nw = blockDim.x >> 6;
        for (int w = 1; w < nw; w++){ lo = fminf(lo, slo[w]); hi = fmaxf(hi, shi[w]); }
        atomicMin(&mm[0], f2u_(lo));
        atomicMax(&mm[1], f2u_(hi));
    }
}

// ================= spline conv over edges =================
__global__ void spline_kernel(const float* __restrict__ x, const float* __restrict__ pseudo,
                              const int* __restrict__ ei, const float* __restrict__ W,
                              float* __restrict__ agg, float* __restrict__ deg, int E){
    __shared__ float Ws[125*17];
    for (int i = threadIdx.x; i < 125*16; i += blockDim.x)
        Ws[(i >> 4)*17 + (i & 15)] = W[i];
    __syncthreads();
    int e = blockIdx.x*blockDim.x + threadIdx.x;
    if (e >= E) return;
    int s = ei[e], d = ei[E + e];
    float p0 = pseudo[3*e], p1 = pseudo[3*e+1], p2 = pseudo[3*e+2];
    float v0 = p0*4.f, v1 = p1*4.f, v2 = p2*4.f;
    float f0 = fminf(fmaxf(floorf(v0), 0.f), 3.f);
    float f1 = fminf(fmaxf(floorf(v1), 0.f), 3.f);
    float f2 = fminf(fmaxf(floorf(v2), 0.f), 3.f);
    float fr0 = v0 - f0, fr1 = v1 - f1, fr2 = v2 - f2;
    int i0 = (int)f0, i1 = (int)f1, i2 = (int)f2;
    float wk[16];
    #pragma unroll
    for (int o = 0; o < 16; o++) wk[o] = 0.f;
    #pragma unroll
    for (int b = 0; b < 8; b++){
        int b0 = (b >> 2) & 1, b1 = (b >> 1) & 1, b2 = b & 1;
        float w = (b0 ? fr0 : 1.f - fr0) * (b1 ? fr1 : 1.f - fr1) * (b2 ? fr2 : 1.f - fr2);
        int k = ((i0 + b0)*5 + (i1 + b1))*5 + (i2 + b2);
        const float* Wr = &Ws[k*17];
        #pragma unroll
        for (int o = 0; o < 16; o++) wk[o] += w * Wr[o];
    }
    float xs = x[s];
    float* ad = &agg[(size_t)d*16];
    #pragma unroll
    for (int o = 0; o < 16; o++) atomicAdd(&ad[o], xs * wk[o]);
    atomicAdd(&deg[d], 1.0f);
}

// ================= node finalize =================
__global__ void node_kernel(const float* __restrict__ x, const float* __restrict__ agg,
                            const float* __restrict__ deg,
                            const float* __restrict__ root, const float* __restrict__ bias,
                            const float* __restrict__ lin_w, const float* __restrict__ lin_b,
                            float* __restrict__ pose, float* __restrict__ act, int N){
    int n = blockIdx.x*blockDim.x + threadIdx.x;
    if (n >= N) return;
    float xs = x[n];
    float dg = fmaxf(deg[n], 1.0f);
    float qv0 = lin_b[0], qv1 = lin_b[1], qv2 = lin_b[2], qv3 = lin_b[3];
    #pragma unroll
    for (int o = 0; o < 16; o++){
        float h = agg[(size_t)n*16 + o] / dg + xs * root[o] + bias[o];
        float e = (h > 0.f) ? h : expm1f(h);
        qv0 += e * lin_w[o*4 + 0];
        qv1 += e * lin_w[o*4 + 1];
        qv2 += e * lin_w[o*4 + 2];
        qv3 += e * lin_w[o*4 + 3];
    }
    float inv = 1.0f / (sqrtf(qv0*qv0 + qv1*qv1 + qv2*qv2 + qv3*qv3) + EPS);
    pose[(size_t)n*4 + 0] = qv0*inv;
    pose[(size_t)n*4 + 1] = qv1*inv;
    pose[(size_t)n*4 + 2] = qv2*inv;
    pose[(size_t)n*4 + 3] = qv3*inv;
    act[n] = xs;
}

// ================= capsule routing layer =================
template<int I, int J>
__device__ __forceinline__ void pred_ij(const float* qn, int i, int j,
                                        float rx, float ry, float rz, float rw,
                                        float& ox, float& oy, float& oz, float& ow){
    const float* qq = &qn[(i*J + j)*4];
    float qx = qq[0], qy = qq[1], qz = qq[2], qw = qq[3];
    float tx = qw*rx + qx*rw + qy*rz - qz*ry;
    float ty = qw*ry - qx*rz + qy*rw + qz*rx;
    float tz = qw*rz + qx*ry - qy*rx + qz*rw;
    float tw = qw*rw - qx*rx - qy*ry - qz*rz;
    float inv = 1.0f / (sqrtf(tx*tx + ty*ty + tz*tz + tw*tw) + EPS);
    ox = tx*inv; oy = ty*inv; oz = tz*inv; ow = tw*inv;
}

template<int I, int J>
__global__ void caps_kernel(const float* __restrict__ poseIn, const float* __restrict__ actIn,
                            const float* __restrict__ q, float* __restrict__ poseOut,
                            float* __restrict__ actOut, int N){
    __shared__ float qn[I*J*4];
    for (int t = threadIdx.x; t < I*J; t += blockDim.x){
        float a = q[t*4], b = q[t*4+1], c = q[t*4+2], d = q[t*4+3];
        float inv = 1.0f / (sqrtf(a*a + b*b + c*c + d*d) + EPS);
        qn[t*4] = a*inv; qn[t*4+1] = b*inv; qn[t*4+2] = c*inv; qn[t*4+3] = d*inv;
    }
    __syncthreads();
    int n = blockIdx.x*blockDim.x + threadIdx.x;
    if (n >= N) return;

    float px[I], py[I], pz[I], pw[I], a[I];
    #pragma unroll
    for (int i = 0; i < I; i++){
        size_t base = ((size_t)n*I + i)*4;
        px[i] = poseIn[base]; py[i] = poseIn[base+1];
        pz[i] = poseIn[base+2]; pw[i] = poseIn[base+3];
        a[i] = actIn[(size_t)n*I + i];
    }
    float bb[I][J], cc[I][J], v[J][4], logit[J];
    #pragma unroll
    for (int i = 0; i < I; i++)
        #pragma unroll
        for (int j = 0; j < J; j++) bb[i][j] = 0.f;

    for (int t = 0; t < 3; t++){
        #pragma unroll
        for (int i = 0; i < I; i++){
            float mb = bb[i][0];
            #pragma unroll
            for (int j = 1; j < J; j++) mb = fmaxf(mb, bb[i][j]);
            float sum = 0.f;
            #pragma unroll
            for (int j = 0; j < J; j++){ float e = expf(bb[i][j] - mb); cc[i][j] = e; sum += e; }
            float sc = a[i] / sum;
            #pragma unroll
            for (int j = 0; j < J; j++) cc[i][j] *= sc;
        }
        #pragma unroll
        for (int j = 0; j < J; j++){ v[j][0]=0.f; v[j][1]=0.f; v[j][2]=0.f; v[j][3]=0.f; }
        #pragma unroll
        for (int i = 0; i < I; i++){
            #pragma unroll
            for (int j = 0; j < J; j++){
                float ox, oy, oz, ow;
                pred_ij<I,J>(qn, i, j, px[i], py[i], pz[i], pw[i], ox, oy, oz, ow);
                float ci = cc[i][j];
                v[j][0] += ci*ox; v[j][1] += ci*oy; v[j][2] += ci*oz; v[j][3] += ci*ow;
            }
        }
        #pragma unroll
        for (int j = 0; j < J; j++){
            float inv = 1.0f / (sqrtf(v[j][0]*v[j][0] + v[j][1]*v[j][1] +
                                      v[j][2]*v[j][2] + v[j][3]*v[j][3]) + EPS);
            v[j][0] *= inv; v[j][1] *= inv; v[j][2] *= inv; v[j][3] *= inv;
        }
        if (t < 2){
            #pragma unroll
            for (int i = 0; i < I; i++)
                #pragma unroll
                for (int j = 0; j < J; j++){
                    float ox, oy, oz, ow;
                    pred_ij<I,J>(qn, i, j, px[i], py[i], pz[i], pw[i], ox, oy, oz, ow);
                    bb[i][j] += ox*v[j][0] + oy*v[j][1] + oz*v[j][2] + ow*v[j][3];
                }
        } else {
            #pragma unroll
            for (int j = 0; j < J; j++) logit[j] = 0.f;
            #pragma unroll
            for (int i = 0; i < I; i++)
                #pragma unroll
                for (int j = 0; j < J; j++){
                    float ox, oy, oz, ow;
                    pred_ij<I,J>(qn, i, j, px[i], py[i], pz[i], pw[i], ox, oy, oz, ow);
                    logit[j] += cc[i][j]*(ox*v[j][0] + oy*v[j][1] + oz*v[j][2] + ow*v[j][3]);
                }
        }
    }
    #pragma unroll
    for (int j = 0; j < J; j++){
        size_t base = ((size_t)n*J + j)*4;
        poseOut[base]   = v[j][0];
        poseOut[base+1] = v[j][1];
        poseOut[base+2] = v[j][2];
        poseOut[base+3] = v[j][3];
        actOut[(size_t)n*J + j] = sigmoidf_(logit[j]);
    }
}

// ================= pooling (shared helpers) =================
__device__ __forceinline__ int voxel_id(const float* __restrict__ pos, int n, int G,
                                        float start, float size){
    int g[3];
    #pragma unroll
    for (int k = 0; k < 3; k++){
        float gg = floorf((pos[(size_t)n*3 + k] - start) / size);
        gg = fminf(fmaxf(gg, 0.f), (float)(G - 1));
        g[k] = (int)gg;
    }
    return (g[0]*G + g[1])*G + g[2];
}

__device__ __forceinline__ void pool_geom(const unsigned* mm, int G, int mode,
                                          float& start, float& size){
    float mn = u2f_(mm[0]), mx = u2f_(mm[1]);
    if (mode == 0){ start = mn; size = (mx + 0.001f - mn) / (float)G; }
    else          { start = mn - 0.5f; size = mx - mn + 1.0f; }
}

// ---------- pool1 (large V) : global-atomic path ----------
__global__ void pool_scatter1(const float* __restrict__ pose, const float* __restrict__ act,
                              const float* __restrict__ pos,
                              float* __restrict__ s, float* __restrict__ wsum,
                              float* __restrict__ cnt, float* __restrict__ psum,
                              int N, int J, int G, int mode, const unsigned* __restrict__ mm){
    int n = blockIdx.x*blockDim.x + threadIdx.x;
    if (n >= N) return;
    float start, size; pool_geom(mm, G, mode, start, size);
    int vid = voxel_id(pos, n, G, start, size);
    for (int j = 0; j < J; j++){
        float aj = act[(size_t)n*J + j];
        size_t pb = ((size_t)n*J + j)*4;
        size_t sb = ((size_t)vid*J + j)*4;
        atomicAdd(&s[sb],   aj*pose[pb]);
        atomicAdd(&s[sb+1], aj*pose[pb+1]);
        atomicAdd(&s[sb+2], aj*pose[pb+2]);
        atomicAdd(&s[sb+3], aj*pose[pb+3]);
        atomicAdd(&wsum[(size_t)vid*J + j], aj);
    }
    atomicAdd(&cnt[vid], 1.0f);
    atomicAdd(&psum[(size_t)vid*3 + 0], pos[(size_t)n*3 + 0]);
    atomicAdd(&psum[(size_t)vid*3 + 1], pos[(size_t)n*3 + 1]);
    atomicAdd(&psum[(size_t)vid*3 + 2], pos[(size_t)n*3 + 2]);
}

__global__ void pool_m(const float* __restrict__ s, float* __restrict__ m, int VJ){
    int t = blockIdx.x*blockDim.x + threadIdx.x;
    if (t >= VJ) return;
    float a = s[(size_t)t*4], b = s[(size_t)t*4+1], c = s[(size_t)t*4+2], d = s[(size_t)t*4+3];
    float inv = 1.0f / (sqrtf(a*a + b*b + c*c + d*d) + EPS);
    m[(size_t)t*4]   = a*inv;
    m[(size_t)t*4+1] = b*inv;
    m[(size_t)t*4+2] = c*inv;
    m[(size_t)t*4+3] = d*inv;
}

__global__ void pool_scatter2(const float* __restrict__ pose, const float* __restrict__ act,
                              const float* __restrict__ pos, const float* __restrict__ m,
                              float* __restrict__ agacc,
                              int N, int J, int G, int mode, const unsigned* __restrict__ mm){
    int n = blockIdx.x*blockDim.x + threadIdx.x;
    if (n >= N) return;
    float start, size; pool_geom(mm, G, mode, start, size);
    int vid = voxel_id(pos, n, G, start, size);
    for (int j = 0; j < J; j++){
        size_t pb = ((size_t)n*J + j)*4;
        size_t mb = ((size_t)vid*J + j)*4;
        float agree = pose[pb]*m[mb] + pose[pb+1]*m[mb+1] + pose[pb+2]*m[mb+2] + pose[pb+3]*m[mb+3];
        atomicAdd(&agacc[(size_t)vid*J + j], act[(size_t)n*J + j]*agree);
    }
}

__global__ void pool_fin(const float* __restrict__ agacc, const float* __restrict__ wsum,
                         const float* __restrict__ cnt, const float* __restrict__ psum,
                         float* __restrict__ actOut, float* __restrict__ posOut, int V, int J){
    int t = blockIdx.x*blockDim.x + threadIdx.x;
    if (t >= V*J) return;
    int v = t / J, j = t % J;
    actOut[t] = sigmoidf_(agacc[t] / (wsum[t] + EPS));
    if (j == 0){
        float c = cnt[v] + EPS;
        posOut[(size_t)v*3 + 0] = psum[(size_t)v*3 + 0] / c;
        posOut[(size_t)v*3 + 1] = psum[(size_t)v*3 + 1] / c;
        posOut[(size_t)v*3 + 2] = psum[(size_t)v*3 + 2] / c;
    }
}

// ---------- pools 2-4 (small V) : fused LDS-privatized kernel ----------
// grid.x = J/CH blocks; block b handles output caps j in [b*CH, (b+1)*CH).
// Block 0 additionally owns cnt/psum/pos_out. All segment sums in LDS.
template<int V, int J, int CH>
__global__ void pool_fused_kernel(const float* __restrict__ poseIn, const float* __restrict__ actIn,
                                  const float* __restrict__ posIn,
                                  float* __restrict__ poseOut, float* __restrict__ actOut,
                                  float* __restrict__ posOut,
                                  int N, int G, int mode, const unsigned* __restrict__ mm){
    __shared__ float s_[V*CH*4];
    __shared__ float wsum_[V*CH];
    __shared__ float ag_[V*CH];
    __shared__ float cnt_[V];
    __shared__ float psum_[V*3];
    const int c0 = blockIdx.x * CH;

    for (int t = threadIdx.x; t < V*CH*4; t += blockDim.x) s_[t] = 0.f;
    for (int t = threadIdx.x; t < V*CH; t += blockDim.x){ wsum_[t] = 0.f; ag_[t] = 0.f; }
    if (blockIdx.x == 0){
        for (int t = threadIdx.x; t < V; t += blockDim.x) cnt_[t] = 0.f;
        for (int t = threadIdx.x; t < V*3; t += blockDim.x) psum_[t] = 0.f;
    }
    __syncthreads();

    float start, size; pool_geom(mm, G, mode, start, size);

    // pass 1: s, wsum (+ cnt, psum on block 0)
    for (int n = threadIdx.x; n < N; n += blockDim.x){
        int vid = voxel_id(posIn, n, G, start, size);
        #pragma unroll
        for (int jj = 0; jj < CH; jj++){
            int j = c0 + jj;
            float aj = actIn[(size_t)n*J + j];
            const float* pb = &poseIn[((size_t)n*J + j)*4];
            int b = (vid*CH + jj)*4;
            atomicAdd(&s_[b+0], aj*pb[0]);
            atomicAdd(&s_[b+1], aj*pb[1]);
            atomicAdd(&s_[b+2], aj*pb[2]);
            atomicAdd(&s_[b+3], aj*pb[3]);
            atomicAdd(&wsum_[vid*CH + jj], aj);
        }
        if (blockIdx.x == 0){
            atomicAdd(&cnt_[vid], 1.0f);
            atomicAdd(&psum_[vid*3+0], posIn[(size_t)n*3+0]);
            atomicAdd(&psum_[vid*3+1], posIn[(size_t)n*3+1]);
            atomicAdd(&psum_[vid*3+2], posIn[(size_t)n*3+2]);
        }
    }
    __syncthreads();

    // m = normalize(s) in place
    for (int t = threadIdx.x; t < V*CH; t += blockDim.x){
        float a = s_[t*4], b = s_[t*4+1], c = s_[t*4+2], d = s_[t*4+3];
        float inv = 1.0f / (sqrtf(a*a + b*b + c*c + d*d) + EPS);
        s_[t*4] = a*inv; s_[t*4+1] = b*inv; s_[t*4+2] = c*inv; s_[t*4+3] = d*inv;
    }
    __syncthreads();

    // pass 2: agacc += act * (pose . m[vid])
    for (int n = threadIdx.x; n < N; n += blockDim.x){
        int vid = voxel_id(posIn, n, G, start, size);
        #pragma unroll
        for (int jj = 0; jj < CH; jj++){
            int j = c0 + jj;
            const float* pb = &poseIn[((size_t)n*J + j)*4];
            const float* mb = &s_[(vid*CH + jj)*4];
            float agree = pb[0]*mb[0] + pb[1]*mb[1] + pb[2]*mb[2] + pb[3]*mb[3];
            atomicAdd(&ag_[vid*CH + jj], actIn[(size_t)n*J + j]*agree);
        }
    }
    __syncthreads();

    // finalize
    for (int t = threadIdx.x; t < V*CH; t += blockDim.x){
        int v = t / CH, jj = t % CH;
        size_t o = (size_t)v*J + c0 + jj;
        actOut[o] = sigmoidf_(ag_[t] / (wsum_[t] + EPS));
        poseOut[o*4+0] = s_[t*4+0];
        poseOut[o*4+1] = s_[t*4+1];
        poseOut[o*4+2] = s_[t*4+2];
        poseOut[o*4+3] = s_[t*4+3];
    }
    if (blockIdx.x == 0){
        for (int v = threadIdx.x; v < V; v += blockDim.x){
            float c = cnt_[v] + EPS;
            posOut[(size_t)v*3+0] = psum_[(size_t)v*3+0] / c;
            posOut[(size_t)v*3+1] = psum_[(size_t)v*3+1] / c;
            posOut[(size_t)v*3+2] = psum_[(size_t)v*3+2] / c;
        }
    }
}

extern "C" void kernel_launch(void* const* d_in, const int* in_sizes, int n_in,
                              void* d_out, int out_size, void* d_ws, size_t ws_size,
                              hipStream_t stream){
    const float* x      = (const float*)d_in[0];
    const float* pos    = (const float*)d_in[1];
    const float* pseudo = (const float*)d_in[2];
    const float* Wsp    = (const float*)d_in[3];
    const float* root   = (const float*)d_in[4];
    const float* bias   = (const float*)d_in[5];
    const float* lin_w  = (const float*)d_in[6];
    const float* lin_b  = (const float*)d_in[7];
    const float* q0     = (const float*)d_in[8];
    const float* q1     = (const float*)d_in[9];
    const float* q3     = (const float*)d_in[10];
    const float* q5     = (const float*)d_in[11];
    const float* q6     = (const float*)d_in[12];
    const float* q7     = (const float*)d_in[13];
    const int*   ei     = (const int*)d_in[14];
    const int N = in_sizes[0];
    const int E = in_sizes[2] / 3;

    char* ws = (char*)d_ws;
    size_t off = 0;
    auto alloc = [&](size_t bytes)->void*{
        void* p = ws + off;
        off += (bytes + 255) & ~(size_t)255;
        return p;
    };
    unsigned* mm = (unsigned*)alloc(8);
    float* agg = (float*)alloc((size_t)N*16*sizeof(float));
    float* deg = (float*)alloc((size_t)N*sizeof(float));
    float* P0  = (float*)alloc((size_t)1250000*sizeof(float));
    float* P1  = (float*)alloc((size_t)1250000*sizeof(float));
    float* A0  = (float*)alloc((size_t)310000*sizeof(float));
    float* A1  = (float*)alloc((size_t)310000*sizeof(float));
    float* PB0 = (float*)alloc((size_t)100000*sizeof(float));
    float* PB1 = (float*)alloc((size_t)100000*sizeof(float));
    float* vs  = (float*)alloc((size_t)800000*sizeof(float));
    float* vw  = (float*)alloc((size_t)200000*sizeof(float));
    float* va  = (float*)alloc((size_t)200000*sizeof(float));
    float* vc  = (float*)alloc((size_t)33000*sizeof(float));
    float* vp  = (float*)alloc((size_t)100000*sizeof(float));

    hipMemsetAsync(mm,     0xFF, 4, stream);
    hipMemsetAsync(mm + 1, 0x00, 4, stream);
    hipMemsetAsync(agg, 0, (size_t)N*16*sizeof(float), stream);
    hipMemsetAsync(deg, 0, (size_t)N*sizeof(float), stream);

    minmax_kernel<<<80, 256, 0, stream>>>(pos, N*3, mm);
    spline_kernel<<<(E + 255)/256, 256, 0, stream>>>(x, pseudo, ei, Wsp, agg, deg, E);
    node_kernel<<<(N + 255)/256, 256, 0, stream>>>(x, agg, deg, root, bias, lin_w, lin_b, P0, A0, N);

    caps_kernel<1,6><<<(N + 63)/64, 64, 0, stream>>>(P0, A0, q0, P1, A1, N);
    caps_kernel<6,6><<<(N + 63)/64, 64, 0, stream>>>(P1, A1, q1, P0, A0, N);

    // pool1: 50000 nodes -> 32768 voxels (G=32), J=6 — global-atomic path (low contention)
    {
        const int V = 32768, J = 6, G = 32;
        hipMemsetAsync(vs, 0, (size_t)V*J*4*sizeof(float), stream);
        hipMemsetAsync(vw, 0, (size_t)V*J*sizeof(float),   stream);
        hipMemsetAsync(va, 0, (size_t)V*J*sizeof(float),   stream);
        hipMemsetAsync(vc, 0, (size_t)V*sizeof(float),     stream);
        hipMemsetAsync(vp, 0, (size_t)V*3*sizeof(float),   stream);
        int gN = (N + 255)/256, gV = (V*J + 255)/256;
        pool_scatter1<<<gN, 256, 0, stream>>>(P0, A0, pos, vs, vw, vc, vp, N, J, G, 0, mm);
        pool_m<<<gV, 256, 0, stream>>>(vs, P1, V*J);
        pool_scatter2<<<gN, 256, 0, stream>>>(P0, A0, pos, P1, va, N, J, G, 0, mm);
        pool_fin<<<gV, 256, 0, stream>>>(va, vw, vc, vp, A1, PB0, V, J);
    }
    caps_kernel<6,8><<<(32768 + 63)/64, 64, 0, stream>>>(P1, A1, q3, P0, A0, 32768);

    // pool2: 32768 -> 512 (G=8), J=8 — fused LDS path, 2 blocks (CH=4, 56KB LDS each)
    pool_fused_kernel<512,8,4><<<2, 1024, 0, stream>>>(P0, A0, PB0, P1, A1, PB1, 32768, 8, 0, mm);
    caps_kernel<8,12><<<(512 + 63)/64, 64, 0, stream>>>(P1, A1, q5, P0, A0, 512);

    // pool3: 512 -> 8 (G=2), J=12 — fused LDS path, 1 block
    pool_fused_kernel<8,12,12><<<1, 1024, 0, stream>>>(P0, A0, PB1, P1, A1, PB0, 512, 2, 0, mm);
    caps_kernel<12,14><<<1, 64, 0, stream>>>(P1, A1, q6, P0, A0, 8);

    // pool4: 8 -> 1 (G=1, mode=1), J=14 — fused LDS path, 1 block
    pool_fused_kernel<1,14,14><<<1, 1024, 0, stream>>>(P0, A0, PB0, P1, A1, PB1, 8, 1, 1, mm);
    caps_kernel<14,10><<<1, 64, 0, stream>>>(P1, A1, q7, P0, (float*)d_out, 1);
}

// Round 3
// 2572.502 us; speedup vs baseline: 2.2228x; 1.4764x over previous
//
#include <hip/hip_runtime.h>
#include <math.h>

#define EPS 1e-4f

__device__ __forceinline__ float sigmoidf_(float x){ return 1.0f/(1.0f+expf(-x)); }

// ---- ordered-uint mapping for float atomic min/max ----
__device__ __forceinline__ unsigned f2u_(float f){
    unsigned u = __float_as_uint(f);
    return (u & 0x80000000u) ? ~u : (u | 0x80000000u);
}
__device__ __forceinline__ float u2f_(unsigned u){
    unsigned b = (u & 0x80000000u) ? (u & 0x7FFFFFFFu) : ~u;
    return __uint_as_float(b);
}

// ================= min/max of pos =================
__global__ void minmax_kernel(const float* __restrict__ p, int n, unsigned* mm){
    float lo = INFINITY, hi = -INFINITY;
    for (int i = blockIdx.x*blockDim.x + threadIdx.x; i < n; i += gridDim.x*blockDim.x){
        float v = p[i]; lo = fminf(lo, v); hi = fmaxf(hi, v);
    }
    for (int off = 32; off > 0; off >>= 1){
        lo = fminf(lo, __shfl_down(lo, off));
        hi = fmaxf(hi, __shfl_down(hi, off));
    }
    __shared__ float slo[8], shi[8];
    int wid = threadIdx.x >> 6;
    if ((threadIdx.x & 63) == 0){ slo[wid] = lo; shi[wid] = hi; }
    __syncthreads();
    if (threadIdx.x == 0){
        int nw = blockDim.x >> 6;
        for (int w = 1; w < nw; w++){ lo = fminf(lo, slo[w]); hi = fmaxf(hi, shi[w]); }
        atomicMin(&mm[0], f2u_(lo));
        atomicMax(&mm[1], f2u_(hi));
    }
}

// ================= spline conv over edges =================
__global__ void spline_kernel(const float* __restrict__ x, const float* __restrict__ pseudo,
                              const int* __restrict__ ei, const float* __restrict__ W,
                              float* __restrict__ agg, float* __restrict__ deg, int E){
    __shared__ float Ws[125*17];
    for (int i = threadIdx.x; i < 125*16; i += blockDim.x)
        Ws[(i >> 4)*17 + (i & 15)] = W[i];
    __syncthreads();
    int e = blockIdx.x*blockDim.x + threadIdx.x;
    if (e >= E) return;
    int s = ei[e], d = ei[E + e];
    float p0 = pseudo[3*e], p1 = pseudo[3*e+1], p2 = pseudo[3*e+2];
    float v0 = p0*4.f, v1 = p1*4.f, v2 = p2*4.f;
    float f0 = fminf(fmaxf(floorf(v0), 0.f), 3.f);
    float f1 = fminf(fmaxf(floorf(v1), 0.f), 3.f);
    float f2 = fminf(fmaxf(floorf(v2), 0.f), 3.f);
    float fr0 = v0 - f0, fr1 = v1 - f1, fr2 = v2 - f2;
    int i0 = (int)f0, i1 = (int)f1, i2 = (int)f2;
    float wk[16];
    #pragma unroll
    for (int o = 0; o < 16; o++) wk[o] = 0.f;
    #pragma unroll
    for (int b = 0; b < 8; b++){
        int b0 = (b >> 2) & 1, b1 = (b >> 1) & 1, b2 = b & 1;
        float w = (b0 ? fr0 : 1.f - fr0) * (b1 ? fr1 : 1.f - fr1) * (b2 ? fr2 : 1.f - fr2);
        int k = ((i0 + b0)*5 + (i1 + b1))*5 + (i2 + b2);
        const float* Wr = &Ws[k*17];
        #pragma unroll
        for (int o = 0; o < 16; o++) wk[o] += w * Wr[o];
    }
    float xs = x[s];
    float* ad = &agg[(size_t)d*16];
    #pragma unroll
    for (int o = 0; o < 16; o++) atomicAdd(&ad[o], xs * wk[o]);
    atomicAdd(&deg[d], 1.0f);
}

// ================= node finalize =================
__global__ void node_kernel(const float* __restrict__ x, const float* __restrict__ agg,
                            const float* __restrict__ deg,
                            const float* __restrict__ root, const float* __restrict__ bias,
                            const float* __restrict__ lin_w, const float* __restrict__ lin_b,
                            float* __restrict__ pose, float* __restrict__ act, int N){
    int n = blockIdx.x*blockDim.x + threadIdx.x;
    if (n >= N) return;
    float xs = x[n];
    float dg = fmaxf(deg[n], 1.0f);
    float qv0 = lin_b[0], qv1 = lin_b[1], qv2 = lin_b[2], qv3 = lin_b[3];
    #pragma unroll
    for (int o = 0; o < 16; o++){
        float h = agg[(size_t)n*16 + o] / dg + xs * root[o] + bias[o];
        float e = (h > 0.f) ? h : expm1f(h);
        qv0 += e * lin_w[o*4 + 0];
        qv1 += e * lin_w[o*4 + 1];
        qv2 += e * lin_w[o*4 + 2];
        qv3 += e * lin_w[o*4 + 3];
    }
    float inv = 1.0f / (sqrtf(qv0*qv0 + qv1*qv1 + qv2*qv2 + qv3*qv3) + EPS);
    pose[(size_t)n*4 + 0] = qv0*inv;
    pose[(size_t)n*4 + 1] = qv1*inv;
    pose[(size_t)n*4 + 2] = qv2*inv;
    pose[(size_t)n*4 + 3] = qv3*inv;
    act[n] = xs;
}

// ================= capsule routing layer =================
template<int I, int J>
__device__ __forceinline__ void pred_ij(const float* qn, int i, int j,
                                        float rx, float ry, float rz, float rw,
                                        float& ox, float& oy, float& oz, float& ow){
    const float* qq = &qn[(i*J + j)*4];
    float qx = qq[0], qy = qq[1], qz = qq[2], qw = qq[3];
    float tx = qw*rx + qx*rw + qy*rz - qz*ry;
    float ty = qw*ry - qx*rz + qy*rw + qz*rx;
    float tz = qw*rz + qx*ry - qy*rx + qz*rw;
    float tw = qw*rw - qx*rx - qy*ry - qz*rz;
    float inv = 1.0f / (sqrtf(tx*tx + ty*ty + tz*tz + tw*tw) + EPS);
    ox = tx*inv; oy = ty*inv; oz = tz*inv; ow = tw*inv;
}

template<int I, int J>
__global__ void caps_kernel(const float* __restrict__ poseIn, const float* __restrict__ actIn,
                            const float* __restrict__ q, float* __restrict__ poseOut,
                            float* __restrict__ actOut, int N){
    __shared__ float qn[I*J*4];
    for (int t = threadIdx.x; t < I*J; t += blockDim.x){
        float a = q[t*4], b = q[t*4+1], c = q[t*4+2], d = q[t*4+3];
        float inv = 1.0f / (sqrtf(a*a + b*b + c*c + d*d) + EPS);
        qn[t*4] = a*inv; qn[t*4+1] = b*inv; qn[t*4+2] = c*inv; qn[t*4+3] = d*inv;
    }
    __syncthreads();
    int n = blockIdx.x*blockDim.x + threadIdx.x;
    if (n >= N) return;

    float px[I], py[I], pz[I], pw[I], a[I];
    #pragma unroll
    for (int i = 0; i < I; i++){
        size_t base = ((size_t)n*I + i)*4;
        px[i] = poseIn[base]; py[i] = poseIn[base+1];
        pz[i] = poseIn[base+2]; pw[i] = poseIn[base+3];
        a[i] = actIn[(size_t)n*I + i];
    }
    float bb[I][J], cc[I][J], v[J][4], logit[J];
    #pragma unroll
    for (int i = 0; i < I; i++)
        #pragma unroll
        for (int j = 0; j < J; j++) bb[i][j] = 0.f;

    for (int t = 0; t < 3; t++){
        #pragma unroll
        for (int i = 0; i < I; i++){
            float mb = bb[i][0];
            #pragma unroll
            for (int j = 1; j < J; j++) mb = fmaxf(mb, bb[i][j]);
            float sum = 0.f;
            #pragma unroll
            for (int j = 0; j < J; j++){ float e = expf(bb[i][j] - mb); cc[i][j] = e; sum += e; }
            float sc = a[i] / sum;
            #pragma unroll
            for (int j = 0; j < J; j++) cc[i][j] *= sc;
        }
        #pragma unroll
        for (int j = 0; j < J; j++){ v[j][0]=0.f; v[j][1]=0.f; v[j][2]=0.f; v[j][3]=0.f; }
        #pragma unroll
        for (int i = 0; i < I; i++){
            #pragma unroll
            for (int j = 0; j < J; j++){
                float ox, oy, oz, ow;
                pred_ij<I,J>(qn, i, j, px[i], py[i], pz[i], pw[i], ox, oy, oz, ow);
                float ci = cc[i][j];
                v[j][0] += ci*ox; v[j][1] += ci*oy; v[j][2] += ci*oz; v[j][3] += ci*ow;
            }
        }
        #pragma unroll
        for (int j = 0; j < J; j++){
            float inv = 1.0f / (sqrtf(v[j][0]*v[j][0] + v[j][1]*v[j][1] +
                                      v[j][2]*v[j][2] + v[j][3]*v[j][3]) + EPS);
            v[j][0] *= inv; v[j][1] *= inv; v[j][2] *= inv; v[j][3] *= inv;
        }
        if (t < 2){
            #pragma unroll
            for (int i = 0; i < I; i++)
                #pragma unroll
                for (int j = 0; j < J; j++){
                    float ox, oy, oz, ow;
                    pred_ij<I,J>(qn, i, j, px[i], py[i], pz[i], pw[i], ox, oy, oz, ow);
                    bb[i][j] += ox*v[j][0] + oy*v[j][1] + oz*v[j][2] + ow*v[j][3];
                }
        } else {
            #pragma unroll
            for (int j = 0; j < J; j++) logit[j] = 0.f;
            #pragma unroll
            for (int i = 0; i < I; i++)
                #pragma unroll
                for (int j = 0; j < J; j++){
                    float ox, oy, oz, ow;
                    pred_ij<I,J>(qn, i, j, px[i], py[i], pz[i], pw[i], ox, oy, oz, ow);
                    logit[j] += cc[i][j]*(ox*v[j][0] + oy*v[j][1] + oz*v[j][2] + ow*v[j][3]);
                }
        }
    }
    #pragma unroll
    for (int j = 0; j < J; j++){
        size_t base = ((size_t)n*J + j)*4;
        poseOut[base]   = v[j][0];
        poseOut[base+1] = v[j][1];
        poseOut[base+2] = v[j][2];
        poseOut[base+3] = v[j][3];
        actOut[(size_t)n*J + j] = sigmoidf_(logit[j]);
    }
}

// ================= pooling (shared helpers) =================
__device__ __forceinline__ int voxel_id(const float* __restrict__ pos, int n, int G,
                                        float start, float size){
    int g[3];
    #pragma unroll
    for (int k = 0; k < 3; k++){
        float gg = floorf((pos[(size_t)n*3 + k] - start) / size);
        gg = fminf(fmaxf(gg, 0.f), (float)(G - 1));
        g[k] = (int)gg;
    }
    return (g[0]*G + g[1])*G + g[2];
}

__device__ __forceinline__ void pool_geom(const unsigned* mm, int G, int mode,
                                          float& start, float& size){
    float mn = u2f_(mm[0]), mx = u2f_(mm[1]);
    if (mode == 0){ start = mn; size = (mx + 0.001f - mn) / (float)G; }
    else          { start = mn - 0.5f; size = mx - mn + 1.0f; }
}

// ---------- pool1 (large V) : global-atomic path ----------
__global__ void pool_scatter1(const float* __restrict__ pose, const float* __restrict__ act,
                              const float* __restrict__ pos,
                              float* __restrict__ s, float* __restrict__ wsum,
                              float* __restrict__ cnt, float* __restrict__ psum,
                              int N, int J, int G, int mode, const unsigned* __restrict__ mm){
    int n = blockIdx.x*blockDim.x + threadIdx.x;
    if (n >= N) return;
    float start, size; pool_geom(mm, G, mode, start, size);
    int vid = voxel_id(pos, n, G, start, size);
    for (int j = 0; j < J; j++){
        float aj = act[(size_t)n*J + j];
        size_t pb = ((size_t)n*J + j)*4;
        size_t sb = ((size_t)vid*J + j)*4;
        atomicAdd(&s[sb],   aj*pose[pb]);
        atomicAdd(&s[sb+1], aj*pose[pb+1]);
        atomicAdd(&s[sb+2], aj*pose[pb+2]);
        atomicAdd(&s[sb+3], aj*pose[pb+3]);
        atomicAdd(&wsum[(size_t)vid*J + j], aj);
    }
    atomicAdd(&cnt[vid], 1.0f);
    atomicAdd(&psum[(size_t)vid*3 + 0], pos[(size_t)n*3 + 0]);
    atomicAdd(&psum[(size_t)vid*3 + 1], pos[(size_t)n*3 + 1]);
    atomicAdd(&psum[(size_t)vid*3 + 2], pos[(size_t)n*3 + 2]);
}

__global__ void pool_m(const float* __restrict__ s, float* __restrict__ m, int VJ){
    int t = blockIdx.x*blockDim.x + threadIdx.x;
    if (t >= VJ) return;
    float a = s[(size_t)t*4], b = s[(size_t)t*4+1], c = s[(size_t)t*4+2], d = s[(size_t)t*4+3];
    float inv = 1.0f / (sqrtf(a*a + b*b + c*c + d*d) + EPS);
    m[(size_t)t*4]   = a*inv;
    m[(size_t)t*4+1] = b*inv;
    m[(size_t)t*4+2] = c*inv;
    m[(size_t)t*4+3] = d*inv;
}

__global__ void pool_scatter2(const float* __restrict__ pose, const float* __restrict__ act,
                              const float* __restrict__ pos, const float* __restrict__ m,
                              float* __restrict__ agacc,
                              int N, int J, int G, int mode, const unsigned* __restrict__ mm){
    int n = blockIdx.x*blockDim.x + threadIdx.x;
    if (n >= N) return;
    float start, size; pool_geom(mm, G, mode, start, size);
    int vid = voxel_id(pos, n, G, start, size);
    for (int j = 0; j < J; j++){
        size_t pb = ((size_t)n*J + j)*4;
        size_t mb = ((size_t)vid*J + j)*4;
        float agree = pose[pb]*m[mb] + pose[pb+1]*m[mb+1] + pose[pb+2]*m[mb+2] + pose[pb+3]*m[mb+3];
        atomicAdd(&agacc[(size_t)vid*J + j], act[(size_t)n*J + j]*agree);
    }
}

__global__ void pool_fin(const float* __restrict__ agacc, const float* __restrict__ wsum,
                         const float* __restrict__ cnt, const float* __restrict__ psum,
                         float* __restrict__ actOut, float* __restrict__ posOut, int V, int J){
    int t = blockIdx.x*blockDim.x + threadIdx.x;
    if (t >= V*J) return;
    int v = t / J, j = t % J;
    actOut[t] = sigmoidf_(agacc[t] / (wsum[t] + EPS));
    if (j == 0){
        float c = cnt[v] + EPS;
        posOut[(size_t)v*3 + 0] = psum[(size_t)v*3 + 0] / c;
        posOut[(size_t)v*3 + 1] = psum[(size_t)v*3 + 1] / c;
        posOut[(size_t)v*3 + 2] = psum[(size_t)v*3 + 2] / c;
    }
}

// ---------- pool2 (mid V) : multi-block LDS-privatized, global-atomic merge ----------
// grid = NCHUNK * nslices blocks; chunk = blockIdx.x % NCHUNK handles caps
// [chunk*CH, (chunk+1)*CH); slice = blockIdx.x / NCHUNK handles a node range.
template<int V, int J, int CH, int NCHUNK>
__global__ void pool_priv1(const float4* __restrict__ poseIn, const float* __restrict__ actIn,
                           const float* __restrict__ posIn,
                           float* __restrict__ s, float* __restrict__ wsum,
                           float* __restrict__ cnt, float* __restrict__ psum,
                           int N, int G, int mode, const unsigned* __restrict__ mm){
    __shared__ float s_[V*CH*4];     // 32 KB for V=512,CH=4
    __shared__ float wsum_[V*CH];    // 8 KB
    __shared__ float cnt_[V];        // 2 KB
    __shared__ float psum_[V*3];     // 6 KB
    const int chunk = blockIdx.x % NCHUNK;
    const int slice = blockIdx.x / NCHUNK;
    const int nslices = gridDim.x / NCHUNK;
    const int c0 = chunk * CH;

    for (int t = threadIdx.x; t < V*CH*4; t += blockDim.x) s_[t] = 0.f;
    for (int t = threadIdx.x; t < V*CH; t += blockDim.x) wsum_[t] = 0.f;
    if (chunk == 0){
        for (int t = threadIdx.x; t < V; t += blockDim.x) cnt_[t] = 0.f;
        for (int t = threadIdx.x; t < V*3; t += blockDim.x) psum_[t] = 0.f;
    }
    __syncthreads();

    float start, size; pool_geom(mm, G, mode, start, size);
    int per = (N + nslices - 1) / nslices;
    int n0 = slice * per, n1 = min(N, n0 + per);

    for (int n = n0 + (int)threadIdx.x; n < n1; n += blockDim.x){
        int vid = voxel_id(posIn, n, G, start, size);
        #pragma unroll
        for (int jj = 0; jj < CH; jj++){
            int j = c0 + jj;
            float aj = actIn[(size_t)n*J + j];
            float4 p = poseIn[(size_t)n*J + j];
            int b = (vid*CH + jj)*4;
            atomicAdd(&s_[b+0], aj*p.x);
            atomicAdd(&s_[b+1], aj*p.y);
            atomicAdd(&s_[b+2], aj*p.z);
            atomicAdd(&s_[b+3], aj*p.w);
            atomicAdd(&wsum_[vid*CH + jj], aj);
        }
        if (chunk == 0){
            atomicAdd(&cnt_[vid], 1.0f);
            atomicAdd(&psum_[vid*3+0], posIn[(size_t)n*3+0]);
            atomicAdd(&psum_[vid*3+1], posIn[(size_t)n*3+1]);
            atomicAdd(&psum_[vid*3+2], posIn[(size_t)n*3+2]);
        }
    }
    __syncthreads();

    // coalesced merge to global (contention = nslices per address)
    for (int t = threadIdx.x; t < V*CH*4; t += blockDim.x){
        float val = s_[t];
        if (val != 0.f){
            int v = t / (CH*4), r = t % (CH*4);
            atomicAdd(&s[((size_t)v*J + c0)*4 + r], val);
        }
    }
    for (int t = threadIdx.x; t < V*CH; t += blockDim.x){
        float val = wsum_[t];
        if (val != 0.f){
            int v = t / CH, jj = t % CH;
            atomicAdd(&wsum[(size_t)v*J + c0 + jj], val);
        }
    }
    if (chunk == 0){
        for (int t = threadIdx.x; t < V; t += blockDim.x)
            if (cnt_[t] != 0.f) atomicAdd(&cnt[t], cnt_[t]);
        for (int t = threadIdx.x; t < V*3; t += blockDim.x)
            if (psum_[t] != 0.f) atomicAdd(&psum[t], psum_[t]);
    }
}

template<int V, int J>
__global__ void pool_priv2(const float4* __restrict__ poseIn, const float* __restrict__ actIn,
                           const float* __restrict__ posIn, const float4* __restrict__ m,
                           float* __restrict__ agacc,
                           int N, int G, int mode, const unsigned* __restrict__ mm){
    __shared__ float ag_[V*J];       // 16 KB for V=512,J=8
    for (int t = threadIdx.x; t < V*J; t += blockDim.x) ag_[t] = 0.f;
    __syncthreads();
    float start, size; pool_geom(mm, G, mode, start, size);
    int nslices = gridDim.x;
    int per = (N + nslices - 1) / nslices;
    int n0 = blockIdx.x * per, n1 = min(N, n0 + per);
    for (int n = n0 + (int)threadIdx.x; n < n1; n += blockDim.x){
        int vid = voxel_id(posIn, n, G, start, size);
        #pragma unroll
        for (int j = 0; j < J; j++){
            float4 p  = poseIn[(size_t)n*J + j];
            float4 mv = m[(size_t)vid*J + j];
            float agree = p.x*mv.x + p.y*mv.y + p.z*mv.z + p.w*mv.w;
            atomicAdd(&ag_[vid*J + j], actIn[(size_t)n*J + j]*agree);
        }
    }
    __syncthreads();
    for (int t = threadIdx.x; t < V*J; t += blockDim.x)
        if (ag_[t] != 0.f) atomicAdd(&agacc[t], ag_[t]);
}

// ---------- pools 3-4 (tiny) : single fused LDS kernel ----------
template<int V, int J, int CH>
__global__ void pool_fused_kernel(const float* __restrict__ poseIn, const float* __restrict__ actIn,
                                  const float* __restrict__ posIn,
                                  float* __restrict__ poseOut, float* __restrict__ actOut,
                                  float* __restrict__ posOut,
                                  int N, int G, int mode, const unsigned* __restrict__ mm){
    __shared__ float s_[V*CH*4];
    __shared__ float wsum_[V*CH];
    __shared__ float ag_[V*CH];
    __shared__ float cnt_[V];
    __shared__ float psum_[V*3];
    const int c0 = blockIdx.x * CH;

    for (int t = threadIdx.x; t < V*CH*4; t += blockDim.x) s_[t] = 0.f;
    for (int t = threadIdx.x; t < V*CH; t += blockDim.x){ wsum_[t] = 0.f; ag_[t] = 0.f; }
    if (blockIdx.x == 0){
        for (int t = threadIdx.x; t < V; t += blockDim.x) cnt_[t] = 0.f;
        for (int t = threadIdx.x; t < V*3; t += blockDim.x) psum_[t] = 0.f;
    }
    __syncthreads();

    float start, size; pool_geom(mm, G, mode, start, size);

    for (int n = threadIdx.x; n < N; n += blockDim.x){
        int vid = voxel_id(posIn, n, G, start, size);
        #pragma unroll
        for (int jj = 0; jj < CH; jj++){
            int j = c0 + jj;
            float aj = actIn[(size_t)n*J + j];
            const float* pb = &poseIn[((size_t)n*J + j)*4];
            int b = (vid*CH + jj)*4;
            atomicAdd(&s_[b+0], aj*pb[0]);
            atomicAdd(&s_[b+1], aj*pb[1]);
            atomicAdd(&s_[b+2], aj*pb[2]);
            atomicAdd(&s_[b+3], aj*pb[3]);
            atomicAdd(&wsum_[vid*CH + jj], aj);
        }
        if (blockIdx.x == 0){
            atomicAdd(&cnt_[vid], 1.0f);
            atomicAdd(&psum_[vid*3+0], posIn[(size_t)n*3+0]);
            atomicAdd(&psum_[vid*3+1], posIn[(size_t)n*3+1]);
            atomicAdd(&psum_[vid*3+2], posIn[(size_t)n*3+2]);
        }
    }
    __syncthreads();

    for (int t = threadIdx.x; t < V*CH; t += blockDim.x){
        float a = s_[t*4], b = s_[t*4+1], c = s_[t*4+2], d = s_[t*4+3];
        float inv = 1.0f / (sqrtf(a*a + b*b + c*c + d*d) + EPS);
        s_[t*4] = a*inv; s_[t*4+1] = b*inv; s_[t*4+2] = c*inv; s_[t*4+3] = d*inv;
    }
    __syncthreads();

    for (int n = threadIdx.x; n < N; n += blockDim.x){
        int vid = voxel_id(posIn, n, G, start, size);
        #pragma unroll
        for (int jj = 0; jj < CH; jj++){
            int j = c0 + jj;
            const float* pb = &poseIn[((size_t)n*J + j)*4];
            const float* mb = &s_[(vid*CH + jj)*4];
            float agree = pb[0]*mb[0] + pb[1]*mb[1] + pb[2]*mb[2] + pb[3]*mb[3];
            atomicAdd(&ag_[vid*CH + jj], actIn[(size_t)n*J + j]*agree);
        }
    }
    __syncthreads();

    for (int t = threadIdx.x; t < V*CH; t += blockDim.x){
        int v = t / CH, jj = t % CH;
        size_t o = (size_t)v*J + c0 + jj;
        actOut[o] = sigmoidf_(ag_[t] / (wsum_[t] + EPS));
        poseOut[o*4+0] = s_[t*4+0];
        poseOut[o*4+1] = s_[t*4+1];
        poseOut[o*4+2] = s_[t*4+2];
        poseOut[o*4+3] = s_[t*4+3];
    }
    if (blockIdx.x == 0){
        for (int v = threadIdx.x; v < V; v += blockDim.x){
            float c = cnt_[v] + EPS;
            posOut[(size_t)v*3+0] = psum_[(size_t)v*3+0] / c;
            posOut[(size_t)v*3+1] = psum_[(size_t)v*3+1] / c;
            posOut[(size_t)v*3+2] = psum_[(size_t)v*3+2] / c;
        }
    }
}

extern "C" void kernel_launch(void* const* d_in, const int* in_sizes, int n_in,
                              void* d_out, int out_size, void* d_ws, size_t ws_size,
                              hipStream_t stream){
    const float* x      = (const float*)d_in[0];
    const float* pos    = (const float*)d_in[1];
    const float* pseudo = (const float*)d_in[2];
    const float* Wsp    = (const float*)d_in[3];
    const float* root   = (const float*)d_in[4];
    const float* bias   = (const float*)d_in[5];
    const float* lin_w  = (const float*)d_in[6];
    const float* lin_b  = (const float*)d_in[7];
    const float* q0     = (const float*)d_in[8];
    const float* q1     = (const float*)d_in[9];
    const float* q3     = (const float*)d_in[10];
    const float* q5     = (const float*)d_in[11];
    const float* q6     = (const float*)d_in[12];
    const float* q7     = (const float*)d_in[13];
    const int*   ei     = (const int*)d_in[14];
    const int N = in_sizes[0];
    const int E = in_sizes[2] / 3;

    char* ws = (char*)d_ws;
    size_t off = 0;
    auto alloc = [&](size_t bytes)->void*{
        void* p = ws + off;
        off += (bytes + 255) & ~(size_t)255;
        return p;
    };
    unsigned* mm = (unsigned*)alloc(8);
    float* agg = (float*)alloc((size_t)N*16*sizeof(float));
    float* deg = (float*)alloc((size_t)N*sizeof(float));
    float* P0  = (float*)alloc((size_t)1250000*sizeof(float));
    float* P1  = (float*)alloc((size_t)1250000*sizeof(float));
    float* A0  = (float*)alloc((size_t)310000*sizeof(float));
    float* A1  = (float*)alloc((size_t)310000*sizeof(float));
    float* PB0 = (float*)alloc((size_t)100000*sizeof(float));
    float* PB1 = (float*)alloc((size_t)100000*sizeof(float));
    float* vs  = (float*)alloc((size_t)800000*sizeof(float));
    float* vw  = (float*)alloc((size_t)200000*sizeof(float));
    float* va  = (float*)alloc((size_t)200000*sizeof(float));
    float* vc  = (float*)alloc((size_t)33000*sizeof(float));
    float* vp  = (float*)alloc((size_t)100000*sizeof(float));

    hipMemsetAsync(mm,     0xFF, 4, stream);
    hipMemsetAsync(mm + 1, 0x00, 4, stream);
    hipMemsetAsync(agg, 0, (size_t)N*16*sizeof(float), stream);
    hipMemsetAsync(deg, 0, (size_t)N*sizeof(float), stream);

    minmax_kernel<<<80, 256, 0, stream>>>(pos, N*3, mm);
    spline_kernel<<<(E + 255)/256, 256, 0, stream>>>(x, pseudo, ei, Wsp, agg, deg, E);
    node_kernel<<<(N + 255)/256, 256, 0, stream>>>(x, agg, deg, root, bias, lin_w, lin_b, P0, A0, N);

    caps_kernel<1,6><<<(N + 63)/64, 64, 0, stream>>>(P0, A0, q0, P1, A1, N);
    caps_kernel<6,6><<<(N + 63)/64, 64, 0, stream>>>(P1, A1, q1, P0, A0, N);

    // pool1: 50000 nodes -> 32768 voxels (G=32), J=6 — global-atomic path (low contention)
    {
        const int V = 32768, J = 6, G = 32;
        hipMemsetAsync(vs, 0, (size_t)V*J*4*sizeof(float), stream);
        hipMemsetAsync(vw, 0, (size_t)V*J*sizeof(float),   stream);
        hipMemsetAsync(va, 0, (size_t)V*J*sizeof(float),   stream);
        hipMemsetAsync(vc, 0, (size_t)V*sizeof(float),     stream);
        hipMemsetAsync(vp, 0, (size_t)V*3*sizeof(float),   stream);
        int gN = (N + 255)/256, gV = (V*J + 255)/256;
        pool_scatter1<<<gN, 256, 0, stream>>>(P0, A0, pos, vs, vw, vc, vp, N, J, G, 0, mm);
        pool_m<<<gV, 256, 0, stream>>>(vs, P1, V*J);
        pool_scatter2<<<gN, 256, 0, stream>>>(P0, A0, pos, P1, va, N, J, G, 0, mm);
        pool_fin<<<gV, 256, 0, stream>>>(va, vw, vc, vp, A1, PB0, V, J);
    }
    caps_kernel<6,8><<<(32768 + 63)/64, 64, 0, stream>>>(P1, A1, q3, P0, A0, 32768);

    // pool2: 32768 -> 512 (G=8), J=8 — multi-block LDS-privatized path
    {
        const int V = 512, J = 8, G = 8, NSL = 16;
        hipMemsetAsync(vs, 0, (size_t)V*J*4*sizeof(float), stream);
        hipMemsetAsync(vw, 0, (size_t)V*J*sizeof(float),   stream);
        hipMemsetAsync(va, 0, (size_t)V*J*sizeof(float),   stream);
        hipMemsetAsync(vc, 0, (size_t)V*sizeof(float),     stream);
        hipMemsetAsync(vp, 0, (size_t)V*3*sizeof(float),   stream);
        pool_priv1<V,J,4,2><<<2*NSL, 256, 0, stream>>>((const float4*)P0, A0, PB0,
                                                       vs, vw, vc, vp, 32768, G, 0, mm);
        pool_m<<<(V*J + 255)/256, 256, 0, stream>>>(vs, P1, V*J);
        pool_priv2<V,J><<<NSL, 256, 0, stream>>>((const float4*)P0, A0, PB0,
                                                 (const float4*)P1, va, 32768, G, 0, mm);
        pool_fin<<<(V*J + 255)/256, 256, 0, stream>>>(va, vw, vc, vp, A1, PB1, V, J);
    }
    caps_kernel<8,12><<<(512 + 63)/64, 64, 0, stream>>>(P1, A1, q5, P0, A0, 512);

    // pool3: 512 -> 8 (G=2), J=12 — fused LDS path, 1 block
    pool_fused_kernel<8,12,12><<<1, 1024, 0, stream>>>(P0, A0, PB1, P1, A1, PB0, 512, 2, 0, mm);
    caps_kernel<12,14><<<1, 64, 0, stream>>>(P1, A1, q6, P0, A0, 8);

    // pool4: 8 -> 1 (G=1, mode=1), J=14 — fused LDS path, 1 block
    pool_fused_kernel<1,14,14><<<1, 1024, 0, stream>>>(P0, A0, PB0, P1, A1, PB1, 8, 1, 1, mm);
    caps_kernel<14,10><<<1, 64, 0, stream>>>(P1, A1, q7, P0, (float*)d_out, 1);
}

// Round 4
// 2116.305 us; speedup vs baseline: 2.7020x; 1.2156x over previous
//
#include <hip/hip_runtime.h>
#include <math.h>

#define EPS 1e-4f

__device__ __forceinline__ float sigmoidf_(float x){ return 1.0f/(1.0f+expf(-x)); }

// ---- ordered-uint mapping for float atomic min/max ----
__device__ __forceinline__ unsigned f2u_(float f){
    unsigned u = __float_as_uint(f);
    return (u & 0x80000000u) ? ~u : (u | 0x80000000u);
}
__device__ __forceinline__ float u2f_(unsigned u){
    unsigned b = (u & 0x80000000u) ? (u & 0x7FFFFFFFu) : ~u;
    return __uint_as_float(b);
}

// ================= min/max of pos =================
__global__ void minmax_kernel(const float* __restrict__ p, int n, unsigned* mm){
    float lo = INFINITY, hi = -INFINITY;
    for (int i = blockIdx.x*blockDim.x + threadIdx.x; i < n; i += gridDim.x*blockDim.x){
        float v = p[i]; lo = fminf(lo, v); hi = fmaxf(hi, v);
    }
    for (int off = 32; off > 0; off >>= 1){
        lo = fminf(lo, __shfl_down(lo, off));
        hi = fmaxf(hi, __shfl_down(hi, off));
    }
    __shared__ float slo[8], shi[8];
    int wid = threadIdx.x >> 6;
    if ((threadIdx.x & 63) == 0){ slo[wid] = lo; shi[wid] = hi; }
    __syncthreads();
    if (threadIdx.x == 0){
        int nw = blockDim.x >> 6;
        for (int w = 1; w < nw; w++){ lo = fminf(lo, slo[w]); hi = fmaxf(hi, shi[w]); }
        atomicMin(&mm[0], f2u_(lo));
        atomicMax(&mm[1], f2u_(hi));
    }
}

// ================= CSR build for spline conv =================
__global__ void hist_kernel(const int* __restrict__ ei, int* __restrict__ cnt, int E){
    int e = blockIdx.x*blockDim.x + threadIdx.x;
    if (e < E) atomicAdd(&cnt[ei[E + e]], 1);
}

// single block, 1024 threads: exclusive scan of cnt[0..N) -> rowptr[0..N], cursor copy
__global__ void scan_kernel(const int* __restrict__ cnt, int* __restrict__ rowptr,
                            int* __restrict__ cursor, int N){
    __shared__ int part[1025];
    const int T = blockDim.x;
    int t = threadIdx.x;
    int per = (N + T - 1) / T;
    int b0 = t*per, b1 = min(N, b0 + per);
    int sum = 0;
    for (int i = b0; i < b1; i++) sum += cnt[i];
    part[t+1] = sum;
    __syncthreads();
    if (t == 0){ part[0] = 0; for (int i = 1; i <= T; i++) part[i] += part[i-1]; }
    __syncthreads();
    int run = part[t];
    for (int i = b0; i < b1; i++){ rowptr[i] = run; cursor[i] = run; run += cnt[i]; }
    if (b1 == N && b0 <= N) rowptr[N] = part[T];
}

// scatter edge payload into CSR slot order
__global__ void scatter_kernel(const float* __restrict__ pseudo, const int* __restrict__ ei,
                               int* __restrict__ cursor, float4* __restrict__ payload, int E){
    int e = blockIdx.x*blockDim.x + threadIdx.x;
    if (e >= E) return;
    int d = ei[E + e];
    int slot = atomicAdd(&cursor[d], 1);
    payload[slot] = make_float4(pseudo[3*e], pseudo[3*e+1], pseudo[3*e+2],
                                __int_as_float(ei[e]));
}

// ================= fused spline gather + node finalize =================
// one thread per node: accumulate spline messages from CSR edges (no atomics),
// then deg-divide + root/bias + ELU + lin -> normalized quaternion pose.
__global__ void spline_node_kernel(const float* __restrict__ x, const float4* __restrict__ payload,
                                   const int* __restrict__ rowptr, const float* __restrict__ W,
                                   const float* __restrict__ root, const float* __restrict__ bias,
                                   const float* __restrict__ lin_w, const float* __restrict__ lin_b,
                                   float* __restrict__ pose, float* __restrict__ act, int N){
    __shared__ float Ws[125*17];
    for (int i = threadIdx.x; i < 125*16; i += blockDim.x)
        Ws[(i >> 4)*17 + (i & 15)] = W[i];
    __syncthreads();
    int n = blockIdx.x*blockDim.x + threadIdx.x;
    if (n >= N) return;

    float agg[16];
    #pragma unroll
    for (int o = 0; o < 16; o++) agg[o] = 0.f;

    int r0 = rowptr[n], r1 = rowptr[n+1];
    for (int s = r0; s < r1; s++){
        float4 pl = payload[s];
        int src = __float_as_int(pl.w);
        float xv = x[src];
        float v0 = pl.x*4.f, v1 = pl.y*4.f, v2 = pl.z*4.f;
        float f0 = fminf(fmaxf(floorf(v0), 0.f), 3.f);
        float f1 = fminf(fmaxf(floorf(v1), 0.f), 3.f);
        float f2 = fminf(fmaxf(floorf(v2), 0.f), 3.f);
        float fr0 = v0 - f0, fr1 = v1 - f1, fr2 = v2 - f2;
        int i0 = (int)f0, i1 = (int)f1, i2 = (int)f2;
        #pragma unroll
        for (int b = 0; b < 8; b++){
            int b0 = (b >> 2) & 1, b1 = (b >> 1) & 1, b2 = b & 1;
            float w = (b0 ? fr0 : 1.f - fr0) * (b1 ? fr1 : 1.f - fr1) * (b2 ? fr2 : 1.f - fr2);
            w *= xv;
            int k = ((i0 + b0)*5 + (i1 + b1))*5 + (i2 + b2);
            const float* Wr = &Ws[k*17];
            #pragma unroll
            for (int o = 0; o < 16; o++) agg[o] += w * Wr[o];
        }
    }

    float deg = fmaxf((float)(r1 - r0), 1.0f);
    float xs = x[n];
    float qv0 = lin_b[0], qv1 = lin_b[1], qv2 = lin_b[2], qv3 = lin_b[3];
    #pragma unroll
    for (int o = 0; o < 16; o++){
        float h = agg[o] / deg + xs * root[o] + bias[o];
        float e = (h > 0.f) ? h : expm1f(h);
        qv0 += e * lin_w[o*4 + 0];
        qv1 += e * lin_w[o*4 + 1];
        qv2 += e * lin_w[o*4 + 2];
        qv3 += e * lin_w[o*4 + 3];
    }
    float inv = 1.0f / (sqrtf(qv0*qv0 + qv1*qv1 + qv2*qv2 + qv3*qv3) + EPS);
    pose[(size_t)n*4 + 0] = qv0*inv;
    pose[(size_t)n*4 + 1] = qv1*inv;
    pose[(size_t)n*4 + 2] = qv2*inv;
    pose[(size_t)n*4 + 3] = qv3*inv;
    act[n] = xs;
}

// ================= capsule routing layer =================
template<int I, int J>
__device__ __forceinline__ void pred_ij(const float* qn, int i, int j,
                                        float rx, float ry, float rz, float rw,
                                        float& ox, float& oy, float& oz, float& ow){
    const float* qq = &qn[(i*J + j)*4];
    float qx = qq[0], qy = qq[1], qz = qq[2], qw = qq[3];
    float tx = qw*rx + qx*rw + qy*rz - qz*ry;
    float ty = qw*ry - qx*rz + qy*rw + qz*rx;
    float tz = qw*rz + qx*ry - qy*rx + qz*rw;
    float tw = qw*rw - qx*rx - qy*ry - qz*rz;
    float inv = 1.0f / (sqrtf(tx*tx + ty*ty + tz*tz + tw*tw) + EPS);
    ox = tx*inv; oy = ty*inv; oz = tz*inv; ow = tw*inv;
}

template<int I, int J>
__global__ void caps_kernel(const float* __restrict__ poseIn, const float* __restrict__ actIn,
                            const float* __restrict__ q, float* __restrict__ poseOut,
                            float* __restrict__ actOut, int N){
    __shared__ float qn[I*J*4];
    for (int t = threadIdx.x; t < I*J; t += blockDim.x){
        float a = q[t*4], b = q[t*4+1], c = q[t*4+2], d = q[t*4+3];
        float inv = 1.0f / (sqrtf(a*a + b*b + c*c + d*d) + EPS);
        qn[t*4] = a*inv; qn[t*4+1] = b*inv; qn[t*4+2] = c*inv; qn[t*4+3] = d*inv;
    }
    __syncthreads();
    int n = blockIdx.x*blockDim.x + threadIdx.x;
    if (n >= N) return;

    float px[I], py[I], pz[I], pw[I], a[I];
    #pragma unroll
    for (int i = 0; i < I; i++){
        size_t base = ((size_t)n*I + i)*4;
        px[i] = poseIn[base]; py[i] = poseIn[base+1];
        pz[i] = poseIn[base+2]; pw[i] = poseIn[base+3];
        a[i] = actIn[(size_t)n*I + i];
    }
    float bb[I][J], cc[I][J], v[J][4], logit[J];
    #pragma unroll
    for (int i = 0; i < I; i++)
        #pragma unroll
        for (int j = 0; j < J; j++) bb[i][j] = 0.f;

    for (int t = 0; t < 3; t++){
        #pragma unroll
        for (int i = 0; i < I; i++){
            float mb = bb[i][0];
            #pragma unroll
            for (int j = 1; j < J; j++) mb = fmaxf(mb, bb[i][j]);
            float sum = 0.f;
            #pragma unroll
            for (int j = 0; j < J; j++){ float e = expf(bb[i][j] - mb); cc[i][j] = e; sum += e; }
            float sc = a[i] / sum;
            #pragma unroll
            for (int j = 0; j < J; j++) cc[i][j] *= sc;
        }
        #pragma unroll
        for (int j = 0; j < J; j++){ v[j][0]=0.f; v[j][1]=0.f; v[j][2]=0.f; v[j][3]=0.f; }
        #pragma unroll
        for (int i = 0; i < I; i++){
            #pragma unroll
            for (int j = 0; j < J; j++){
                float ox, oy, oz, ow;
                pred_ij<I,J>(qn, i, j, px[i], py[i], pz[i], pw[i], ox, oy, oz, ow);
                float ci = cc[i][j];
                v[j][0] += ci*ox; v[j][1] += ci*oy; v[j][2] += ci*oz; v[j][3] += ci*ow;
            }
        }
        #pragma unroll
        for (int j = 0; j < J; j++){
            float inv = 1.0f / (sqrtf(v[j][0]*v[j][0] + v[j][1]*v[j][1] +
                                      v[j][2]*v[j][2] + v[j][3]*v[j][3]) + EPS);
            v[j][0] *= inv; v[j][1] *= inv; v[j][2] *= inv; v[j][3] *= inv;
        }
        if (t < 2){
            #pragma unroll
            for (int i = 0; i < I; i++)
                #pragma unroll
                for (int j = 0; j < J; j++){
                    float ox, oy, oz, ow;
                    pred_ij<I,J>(qn, i, j, px[i], py[i], pz[i], pw[i], ox, oy, oz, ow);
                    bb[i][j] += ox*v[j][0] + oy*v[j][1] + oz*v[j][2] + ow*v[j][3];
                }
        } else {
            #pragma unroll
            for (int j = 0; j < J; j++) logit[j] = 0.f;
            #pragma unroll
            for (int i = 0; i < I; i++)
                #pragma unroll
                for (int j = 0; j < J; j++){
                    float ox, oy, oz, ow;
                    pred_ij<I,J>(qn, i, j, px[i], py[i], pz[i], pw[i], ox, oy, oz, ow);
                    logit[j] += cc[i][j]*(ox*v[j][0] + oy*v[j][1] + oz*v[j][2] + ow*v[j][3]);
                }
        }
    }
    #pragma unroll
    for (int j = 0; j < J; j++){
        size_t base = ((size_t)n*J + j)*4;
        poseOut[base]   = v[j][0];
        poseOut[base+1] = v[j][1];
        poseOut[base+2] = v[j][2];
        poseOut[base+3] = v[j][3];
        actOut[(size_t)n*J + j] = sigmoidf_(logit[j]);
    }
}

// ================= pooling (shared helpers) =================
__device__ __forceinline__ int voxel_id(const float* __restrict__ pos, int n, int G,
                                        float start, float size){
    int g[3];
    #pragma unroll
    for (int k = 0; k < 3; k++){
        float gg = floorf((pos[(size_t)n*3 + k] - start) / size);
        gg = fminf(fmaxf(gg, 0.f), (float)(G - 1));
        g[k] = (int)gg;
    }
    return (g[0]*G + g[1])*G + g[2];
}

__device__ __forceinline__ void pool_geom(const unsigned* mm, int G, int mode,
                                          float& start, float& size){
    float mn = u2f_(mm[0]), mx = u2f_(mm[1]);
    if (mode == 0){ start = mn; size = (mx + 0.001f - mn) / (float)G; }
    else          { start = mn - 0.5f; size = mx - mn + 1.0f; }
}

// ---------- pool1 (large V) : global-atomic path ----------
__global__ void pool_scatter1(const float* __restrict__ pose, const float* __restrict__ act,
                              const float* __restrict__ pos,
                              float* __restrict__ s, float* __restrict__ wsum,
                              float* __restrict__ cnt, float* __restrict__ psum,
                              int N, int J, int G, int mode, const unsigned* __restrict__ mm){
    int n = blockIdx.x*blockDim.x + threadIdx.x;
    if (n >= N) return;
    float start, size; pool_geom(mm, G, mode, start, size);
    int vid = voxel_id(pos, n, G, start, size);
    for (int j = 0; j < J; j++){
        float aj = act[(size_t)n*J + j];
        size_t pb = ((size_t)n*J + j)*4;
        size_t sb = ((size_t)vid*J + j)*4;
        atomicAdd(&s[sb],   aj*pose[pb]);
        atomicAdd(&s[sb+1], aj*pose[pb+1]);
        atomicAdd(&s[sb+2], aj*pose[pb+2]);
        atomicAdd(&s[sb+3], aj*pose[pb+3]);
        atomicAdd(&wsum[(size_t)vid*J + j], aj);
    }
    atomicAdd(&cnt[vid], 1.0f);
    atomicAdd(&psum[(size_t)vid*3 + 0], pos[(size_t)n*3 + 0]);
    atomicAdd(&psum[(size_t)vid*3 + 1], pos[(size_t)n*3 + 1]);
    atomicAdd(&psum[(size_t)vid*3 + 2], pos[(size_t)n*3 + 2]);
}

__global__ void pool_m(const float* __restrict__ s, float* __restrict__ m, int VJ){
    int t = blockIdx.x*blockDim.x + threadIdx.x;
    if (t >= VJ) return;
    float a = s[(size_t)t*4], b = s[(size_t)t*4+1], c = s[(size_t)t*4+2], d = s[(size_t)t*4+3];
    float inv = 1.0f / (sqrtf(a*a + b*b + c*c + d*d) + EPS);
    m[(size_t)t*4]   = a*inv;
    m[(size_t)t*4+1] = b*inv;
    m[(size_t)t*4+2] = c*inv;
    m[(size_t)t*4+3] = d*inv;
}

__global__ void pool_scatter2(const float* __restrict__ pose, const float* __restrict__ act,
                              const float* __restrict__ pos, const float* __restrict__ m,
                              float* __restrict__ agacc,
                              int N, int J, int G, int mode, const unsigned* __restrict__ mm){
    int n = blockIdx.x*blockDim.x + threadIdx.x;
    if (n >= N) return;
    float start, size; pool_geom(mm, G, mode, start, size);
    int vid = voxel_id(pos, n, G, start, size);
    for (int j = 0; j < J; j++){
        size_t pb = ((size_t)n*J + j)*4;
        size_t mb = ((size_t)vid*J + j)*4;
        float agree = pose[pb]*m[mb] + pose[pb+1]*m[mb+1] + pose[pb+2]*m[mb+2] + pose[pb+3]*m[mb+3];
        atomicAdd(&agacc[(size_t)vid*J + j], act[(size_t)n*J + j]*agree);
    }
}

__global__ void pool_fin(const float* __restrict__ agacc, const float* __restrict__ wsum,
                         const float* __restrict__ cnt, const float* __restrict__ psum,
                         float* __restrict__ actOut, float* __restrict__ posOut, int V, int J){
    int t = blockIdx.x*blockDim.x + threadIdx.x;
    if (t >= V*J) return;
    int v = t / J, j = t % J;
    actOut[t] = sigmoidf_(agacc[t] / (wsum[t] + EPS));
    if (j == 0){
        float c = cnt[v] + EPS;
        posOut[(size_t)v*3 + 0] = psum[(size_t)v*3 + 0] / c;
        posOut[(size_t)v*3 + 1] = psum[(size_t)v*3 + 1] / c;
        posOut[(size_t)v*3 + 2] = psum[(size_t)v*3 + 2] / c;
    }
}

// ---------- pool2 (mid V) : multi-block LDS-privatized, global-atomic merge ----------
template<int V, int J, int CH, int NCHUNK>
__global__ void pool_priv1(const float4* __restrict__ poseIn, const float* __restrict__ actIn,
                           const float* __restrict__ posIn,
                           float* __restrict__ s, float* __restrict__ wsum,
                           float* __restrict__ cnt, float* __restrict__ psum,
                           int N, int G, int mode, const unsigned* __restrict__ mm){
    __shared__ float s_[V*CH*4];
    __shared__ float wsum_[V*CH];
    __shared__ float cnt_[V];
    __shared__ float psum_[V*3];
    const int chunk = blockIdx.x % NCHUNK;
    const int slice = blockIdx.x / NCHUNK;
    const int nslices = gridDim.x / NCHUNK;
    const int c0 = chunk * CH;

    for (int t = threadIdx.x; t < V*CH*4; t += blockDim.x) s_[t] = 0.f;
    for (int t = threadIdx.x; t < V*CH; t += blockDim.x) wsum_[t] = 0.f;
    if (chunk == 0){
        for (int t = threadIdx.x; t < V; t += blockDim.x) cnt_[t] = 0.f;
        for (int t = threadIdx.x; t < V*3; t += blockDim.x) psum_[t] = 0.f;
    }
    __syncthreads();

    float start, size; pool_geom(mm, G, mode, start, size);
    int per = (N + nslices - 1) / nslices;
    int n0 = slice * per, n1 = min(N, n0 + per);

    for (int n = n0 + (int)threadIdx.x; n < n1; n += blockDim.x){
        int vid = voxel_id(posIn, n, G, start, size);
        #pragma unroll
        for (int jj = 0; jj < CH; jj++){
            int j = c0 + jj;
            float aj = actIn[(size_t)n*J + j];
            float4 p = poseIn[(size_t)n*J + j];
            int b = (vid*CH + jj)*4;
            atomicAdd(&s_[b+0], aj*p.x);
            atomicAdd(&s_[b+1], aj*p.y);
            atomicAdd(&s_[b+2], aj*p.z);
            atomicAdd(&s_[b+3], aj*p.w);
            atomicAdd(&wsum_[vid*CH + jj], aj);
        }
        if (chunk == 0){
            atomicAdd(&cnt_[vid], 1.0f);
            atomicAdd(&psum_[vid*3+0], posIn[(size_t)n*3+0]);
            atomicAdd(&psum_[vid*3+1], posIn[(size_t)n*3+1]);
            atomicAdd(&psum_[vid*3+2], posIn[(size_t)n*3+2]);
        }
    }
    __syncthreads();

    for (int t = threadIdx.x; t < V*CH*4; t += blockDim.x){
        float val = s_[t];
        if (val != 0.f){
            int v = t / (CH*4), r = t % (CH*4);
            atomicAdd(&s[((size_t)v*J + c0)*4 + r], val);
        }
    }
    for (int t = threadIdx.x; t < V*CH; t += blockDim.x){
        float val = wsum_[t];
        if (val != 0.f){
            int v = t / CH, jj = t % CH;
            atomicAdd(&wsum[(size_t)v*J + c0 + jj], val);
        }
    }
    if (chunk == 0){
        for (int t = threadIdx.x; t < V; t += blockDim.x)
            if (cnt_[t] != 0.f) atomicAdd(&cnt[t], cnt_[t]);
        for (int t = threadIdx.x; t < V*3; t += blockDim.x)
            if (psum_[t] != 0.f) atomicAdd(&psum[t], psum_[t]);
    }
}

template<int V, int J>
__global__ void pool_priv2(const float4* __restrict__ poseIn, const float* __restrict__ actIn,
                           const float* __restrict__ posIn, const float4* __restrict__ m,
                           float* __restrict__ agacc,
                           int N, int G, int mode, const unsigned* __restrict__ mm){
    __shared__ float ag_[V*J];
    for (int t = threadIdx.x; t < V*J; t += blockDim.x) ag_[t] = 0.f;
    __syncthreads();
    float start, size; pool_geom(mm, G, mode, start, size);
    int nslices = gridDim.x;
    int per = (N + nslices - 1) / nslices;
    int n0 = blockIdx.x * per, n1 = min(N, n0 + per);
    for (int n = n0 + (int)threadIdx.x; n < n1; n += blockDim.x){
        int vid = voxel_id(posIn, n, G, start, size);
        #pragma unroll
        for (int j = 0; j < J; j++){
            float4 p  = poseIn[(size_t)n*J + j];
            float4 mv = m[(size_t)vid*J + j];
            float agree = p.x*mv.x + p.y*mv.y + p.z*mv.z + p.w*mv.w;
            atomicAdd(&ag_[vid*J + j], actIn[(size_t)n*J + j]*agree);
        }
    }
    __syncthreads();
    for (int t = threadIdx.x; t < V*J; t += blockDim.x)
        if (ag_[t] != 0.f) atomicAdd(&agacc[t], ag_[t]);
}

// ---------- pools 3-4 (tiny) : single fused LDS kernel ----------
template<int V, int J, int CH>
__global__ void pool_fused_kernel(const float* __restrict__ poseIn, const float* __restrict__ actIn,
                                  const float* __restrict__ posIn,
                                  float* __restrict__ poseOut, float* __restrict__ actOut,
                                  float* __restrict__ posOut,
                                  int N, int G, int mode, const unsigned* __restrict__ mm){
    __shared__ float s_[V*CH*4];
    __shared__ float wsum_[V*CH];
    __shared__ float ag_[V*CH];
    __shared__ float cnt_[V];
    __shared__ float psum_[V*3];
    const int c0 = blockIdx.x * CH;

    for (int t = threadIdx.x; t < V*CH*4; t += blockDim.x) s_[t] = 0.f;
    for (int t = threadIdx.x; t < V*CH; t += blockDim.x){ wsum_[t] = 0.f; ag_[t] = 0.f; }
    if (blockIdx.x == 0){
        for (int t = threadIdx.x; t < V; t += blockDim.x) cnt_[t] = 0.f;
        for (int t = threadIdx.x; t < V*3; t += blockDim.x) psum_[t] = 0.f;
    }
    __syncthreads();

    float start, size; pool_geom(mm, G, mode, start, size);

    for (int n = threadIdx.x; n < N; n += blockDim.x){
        int vid = voxel_id(posIn, n, G, start, size);
        #pragma unroll
        for (int jj = 0; jj < CH; jj++){
            int j = c0 + jj;
            float aj = actIn[(size_t)n*J + j];
            const float* pb = &poseIn[((size_t)n*J + j)*4];
            int b = (vid*CH + jj)*4;
            atomicAdd(&s_[b+0], aj*pb[0]);
            atomicAdd(&s_[b+1], aj*pb[1]);
            atomicAdd(&s_[b+2], aj*pb[2]);
            atomicAdd(&s_[b+3], aj*pb[3]);
            atomicAdd(&wsum_[vid*CH + jj], aj);
        }
        if (blockIdx.x == 0){
            atomicAdd(&cnt_[vid], 1.0f);
            atomicAdd(&psum_[vid*3+0], posIn[(size_t)n*3+0]);
            atomicAdd(&psum_[vid*3+1], posIn[(size_t)n*3+1]);
            atomicAdd(&psum_[vid*3+2], posIn[(size_t)n*3+2]);
        }
    }
    __syncthreads();

    for (int t = threadIdx.x; t < V*CH; t += blockDim.x){
        float a = s_[t*4], b = s_[t*4+1], c = s_[t*4+2], d = s_[t*4+3];
        float inv = 1.0f / (sqrtf(a*a + b*b + c*c + d*d) + EPS);
        s_[t*4] = a*inv; s_[t*4+1] = b*inv; s_[t*4+2] = c*inv; s_[t*4+3] = d*inv;
    }
    __syncthreads();

    for (int n = threadIdx.x; n < N; n += blockDim.x){
        int vid = voxel_id(posIn, n, G, start, size);
        #pragma unroll
        for (int jj = 0; jj < CH; jj++){
            int j = c0 + jj;
            const float* pb = &poseIn[((size_t)n*J + j)*4];
            const float* mb = &s_[(vid*CH + jj)*4];
            float agree = pb[0]*mb[0] + pb[1]*mb[1] + pb[2]*mb[2] + pb[3]*mb[3];
            atomicAdd(&ag_[vid*CH + jj], actIn[(size_t)n*J + j]*agree);
        }
    }
    __syncthreads();

    for (int t = threadIdx.x; t < V*CH; t += blockDim.x){
        int v = t / CH, jj = t % CH;
        size_t o = (size_t)v*J + c0 + jj;
        actOut[o] = sigmoidf_(ag_[t] / (wsum_[t] + EPS));
        poseOut[o*4+0] = s_[t*4+0];
        poseOut[o*4+1] = s_[t*4+1];
        poseOut[o*4+2] = s_[t*4+2];
        poseOut[o*4+3] = s_[t*4+3];
    }
    if (blockIdx.x == 0){
        for (int v = threadIdx.x; v < V; v += blockDim.x){
            float c = cnt_[v] + EPS;
            posOut[(size_t)v*3+0] = psum_[(size_t)v*3+0] / c;
            posOut[(size_t)v*3+1] = psum_[(size_t)v*3+1] / c;
            posOut[(size_t)v*3+2] = psum_[(size_t)v*3+2] / c;
        }
    }
}

extern "C" void kernel_launch(void* const* d_in, const int* in_sizes, int n_in,
                              void* d_out, int out_size, void* d_ws, size_t ws_size,
                              hipStream_t stream){
    const float* x      = (const float*)d_in[0];
    const float* pos    = (const float*)d_in[1];
    const float* pseudo = (const float*)d_in[2];
    const float* Wsp    = (const float*)d_in[3];
    const float* root   = (const float*)d_in[4];
    const float* bias   = (const float*)d_in[5];
    const float* lin_w  = (const float*)d_in[6];
    const float* lin_b  = (const float*)d_in[7];
    const float* q0     = (const float*)d_in[8];
    const float* q1     = (const float*)d_in[9];
    const float* q3     = (const float*)d_in[10];
    const float* q5     = (const float*)d_in[11];
    const float* q6     = (const float*)d_in[12];
    const float* q7     = (const float*)d_in[13];
    const int*   ei     = (const int*)d_in[14];
    const int N = in_sizes[0];
    const int E = in_sizes[2] / 3;

    char* ws = (char*)d_ws;
    size_t off = 0;
    auto alloc = [&](size_t bytes)->void*{
        void* p = ws + off;
        off += (bytes + 255) & ~(size_t)255;
        return p;
    };
    unsigned* mm   = (unsigned*)alloc(8);
    int* ecnt      = (int*)alloc((size_t)N*sizeof(int));
    int* rowptr    = (int*)alloc((size_t)(N+1)*sizeof(int));
    int* cursor    = (int*)alloc((size_t)N*sizeof(int));
    float4* payload= (float4*)alloc((size_t)E*sizeof(float4));
    float* P0  = (float*)alloc((size_t)1250000*sizeof(float));
    float* P1  = (float*)alloc((size_t)1250000*sizeof(float));
    float* A0  = (float*)alloc((size_t)310000*sizeof(float));
    float* A1  = (float*)alloc((size_t)310000*sizeof(float));
    float* PB0 = (float*)alloc((size_t)100000*sizeof(float));
    float* PB1 = (float*)alloc((size_t)100000*sizeof(float));
    float* vs  = (float*)alloc((size_t)800000*sizeof(float));
    float* vw  = (float*)alloc((size_t)200000*sizeof(float));
    float* va  = (float*)alloc((size_t)200000*sizeof(float));
    float* vc  = (float*)alloc((size_t)33000*sizeof(float));
    float* vp  = (float*)alloc((size_t)100000*sizeof(float));

    hipMemsetAsync(mm,     0xFF, 4, stream);
    hipMemsetAsync(mm + 1, 0x00, 4, stream);
    hipMemsetAsync(ecnt, 0, (size_t)N*sizeof(int), stream);

    minmax_kernel<<<80, 256, 0, stream>>>(pos, N*3, mm);

    // CSR build + fused spline gather / node finalize (no float atomics)
    hist_kernel<<<(E + 255)/256, 256, 0, stream>>>(ei, ecnt, E);
    scan_kernel<<<1, 1024, 0, stream>>>(ecnt, rowptr, cursor, N);
    scatter_kernel<<<(E + 255)/256, 256, 0, stream>>>(pseudo, ei, cursor, payload, E);
    spline_node_kernel<<<(N + 255)/256, 256, 0, stream>>>(x, payload, rowptr, Wsp,
                                                          root, bias, lin_w, lin_b, P0, A0, N);

    caps_kernel<1,6><<<(N + 63)/64, 64, 0, stream>>>(P0, A0, q0, P1, A1, N);
    caps_kernel<6,6><<<(N + 63)/64, 64, 0, stream>>>(P1, A1, q1, P0, A0, N);

    // pool1: 50000 nodes -> 32768 voxels (G=32), J=6 — global-atomic path (low contention)
    {
        const int V = 32768, J = 6, G = 32;
        hipMemsetAsync(vs, 0, (size_t)V*J*4*sizeof(float), stream);
        hipMemsetAsync(vw, 0, (size_t)V*J*sizeof(float),   stream);
        hipMemsetAsync(va, 0, (size_t)V*J*sizeof(float),   stream);
        hipMemsetAsync(vc, 0, (size_t)V*sizeof(float),     stream);
        hipMemsetAsync(vp, 0, (size_t)V*3*sizeof(float),   stream);
        int gN = (N + 255)/256, gV = (V*J + 255)/256;
        pool_scatter1<<<gN, 256, 0, stream>>>(P0, A0, pos, vs, vw, vc, vp, N, J, G, 0, mm);
        pool_m<<<gV, 256, 0, stream>>>(vs, P1, V*J);
        pool_scatter2<<<gN, 256, 0, stream>>>(P0, A0, pos, P1, va, N, J, G, 0, mm);
        pool_fin<<<gV, 256, 0, stream>>>(va, vw, vc, vp, A1, PB0, V, J);
    }
    caps_kernel<6,8><<<(32768 + 63)/64, 64, 0, stream>>>(P1, A1, q3, P0, A0, 32768);

    // pool2: 32768 -> 512 (G=8), J=8 — multi-block LDS-privatized path
    {
        const int V = 512, J = 8, G = 8, NSL = 16;
        hipMemsetAsync(vs, 0, (size_t)V*J*4*sizeof(float), stream);
        hipMemsetAsync(vw, 0, (size_t)V*J*sizeof(float),   stream);
        hipMemsetAsync(va, 0, (size_t)V*J*sizeof(float),   stream);
        hipMemsetAsync(vc, 0, (size_t)V*sizeof(float),     stream);
        hipMemsetAsync(vp, 0, (size_t)V*3*sizeof(float),   stream);
        pool_priv1<V,J,4,2><<<2*NSL, 256, 0, stream>>>((const float4*)P0, A0, PB0,
                                                       vs, vw, vc, vp, 32768, G, 0, mm);
        pool_m<<<(V*J + 255)/256, 256, 0, stream>>>(vs, P1, V*J);
        pool_priv2<V,J><<<NSL, 256, 0, stream>>>((const float4*)P0, A0, PB0,
                                                 (const float4*)P1, va, 32768, G, 0, mm);
        pool_fin<<<(V*J + 255)/256, 256, 0, stream>>>(va, vw, vc, vp, A1, PB1, V, J);
    }
    caps_kernel<8,12><<<(512 + 63)/64, 64, 0, stream>>>(P1, A1, q5, P0, A0, 512);

    // pool3: 512 -> 8 (G=2), J=12 — fused LDS path, 1 block
    pool_fused_kernel<8,12,12><<<1, 1024, 0, stream>>>(P0, A0, PB1, P1, A1, PB0, 512, 2, 0, mm);
    caps_kernel<12,14><<<1, 64, 0, stream>>>(P1, A1, q6, P0, A0, 8);

    // pool4: 8 -> 1 (G=1, mode=1), J=14 — fused LDS path, 1 block
    pool_fused_kernel<1,14,14><<<1, 1024, 0, stream>>>(P0, A0, PB0, P1, A1, PB1, 8, 1, 1, mm);
    caps_kernel<14,10><<<1, 64, 0, stream>>>(P1, A1, q7, P0, (float*)d_out, 1);
}

// Round 5
// 923.893 us; speedup vs baseline: 6.1892x; 2.2906x over previous
//
#include <hip/hip_runtime.h>
#include <math.h>

#define EPS 1e-4f

__device__ __forceinline__ float sigmoidf_(float x){ return 1.0f/(1.0f+expf(-x)); }

// ---- ordered-uint mapping for float atomic min/max ----
__device__ __forceinline__ unsigned f2u_(float f){
    unsigned u = __float_as_uint(f);
    return (u & 0x80000000u) ? ~u : (u | 0x80000000u);
}
__device__ __forceinline__ float u2f_(unsigned u){
    unsigned b = (u & 0x80000000u) ? (u & 0x7FFFFFFFu) : ~u;
    return __uint_as_float(b);
}

// ================= min/max of pos =================
__global__ void minmax_kernel(const float* __restrict__ p, int n, unsigned* mm){
    float lo = INFINITY, hi = -INFINITY;
    for (int i = blockIdx.x*blockDim.x + threadIdx.x; i < n; i += gridDim.x*blockDim.x){
        float v = p[i]; lo = fminf(lo, v); hi = fmaxf(hi, v);
    }
    for (int off = 32; off > 0; off >>= 1){
        lo = fminf(lo, __shfl_down(lo, off));
        hi = fmaxf(hi, __shfl_down(hi, off));
    }
    __shared__ float slo[8], shi[8];
    int wid = threadIdx.x >> 6;
    if ((threadIdx.x & 63) == 0){ slo[wid] = lo; shi[wid] = hi; }
    __syncthreads();
    if (threadIdx.x == 0){
        int nw = blockDim.x >> 6;
        for (int w = 1; w < nw; w++){ lo = fminf(lo, slo[w]); hi = fmaxf(hi, shi[w]); }
        atomicMin(&mm[0], f2u_(lo));
        atomicMax(&mm[1], f2u_(hi));
    }
}

// ================= CSR build for spline conv =================
__global__ void hist_kernel(const int* __restrict__ ei, int* __restrict__ cnt, int E){
    int e = blockIdx.x*blockDim.x + threadIdx.x;
    if (e < E) atomicAdd(&cnt[ei[E + e]], 1);
}

__global__ void scan_kernel(const int* __restrict__ cnt, int* __restrict__ rowptr,
                            int* __restrict__ cursor, int N){
    __shared__ int part[1025];
    const int T = blockDim.x;
    int t = threadIdx.x;
    int per = (N + T - 1) / T;
    int b0 = t*per, b1 = min(N, b0 + per);
    int sum = 0;
    for (int i = b0; i < b1; i++) sum += cnt[i];
    part[t+1] = sum;
    __syncthreads();
    if (t == 0){ part[0] = 0; for (int i = 1; i <= T; i++) part[i] += part[i-1]; }
    __syncthreads();
    int run = part[t];
    for (int i = b0; i < b1; i++){ rowptr[i] = run; cursor[i] = run; run += cnt[i]; }
    if (b1 == N && b0 <= N) rowptr[N] = part[T];
}

__global__ void scatter_kernel(const float* __restrict__ pseudo, const int* __restrict__ ei,
                               int* __restrict__ cursor, float4* __restrict__ payload, int E){
    int e = blockIdx.x*blockDim.x + threadIdx.x;
    if (e >= E) return;
    int d = ei[E + e];
    int slot = atomicAdd(&cursor[d], 1);
    payload[slot] = make_float4(pseudo[3*e], pseudo[3*e+1], pseudo[3*e+2],
                                __int_as_float(ei[e]));
}

// ================= fused spline gather + node finalize =================
__global__ void spline_node_kernel(const float* __restrict__ x, const float4* __restrict__ payload,
                                   const int* __restrict__ rowptr, const float* __restrict__ W,
                                   const float* __restrict__ root, const float* __restrict__ bias,
                                   const float* __restrict__ lin_w, const float* __restrict__ lin_b,
                                   float* __restrict__ pose, float* __restrict__ act, int N){
    __shared__ float Ws[125*17];
    for (int i = threadIdx.x; i < 125*16; i += blockDim.x)
        Ws[(i >> 4)*17 + (i & 15)] = W[i];
    __syncthreads();
    int n = blockIdx.x*blockDim.x + threadIdx.x;
    if (n >= N) return;

    float agg[16];
    #pragma unroll
    for (int o = 0; o < 16; o++) agg[o] = 0.f;

    int r0 = rowptr[n], r1 = rowptr[n+1];
    for (int s = r0; s < r1; s++){
        float4 pl = payload[s];
        int src = __float_as_int(pl.w);
        float xv = x[src];
        float v0 = pl.x*4.f, v1 = pl.y*4.f, v2 = pl.z*4.f;
        float f0 = fminf(fmaxf(floorf(v0), 0.f), 3.f);
        float f1 = fminf(fmaxf(floorf(v1), 0.f), 3.f);
        float f2 = fminf(fmaxf(floorf(v2), 0.f), 3.f);
        float fr0 = v0 - f0, fr1 = v1 - f1, fr2 = v2 - f2;
        int i0 = (int)f0, i1 = (int)f1, i2 = (int)f2;
        #pragma unroll
        for (int b = 0; b < 8; b++){
            int b0 = (b >> 2) & 1, b1 = (b >> 1) & 1, b2 = b & 1;
            float w = (b0 ? fr0 : 1.f - fr0) * (b1 ? fr1 : 1.f - fr1) * (b2 ? fr2 : 1.f - fr2);
            w *= xv;
            int k = ((i0 + b0)*5 + (i1 + b1))*5 + (i2 + b2);
            const float* Wr = &Ws[k*17];
            #pragma unroll
            for (int o = 0; o < 16; o++) agg[o] += w * Wr[o];
        }
    }

    float deg = fmaxf((float)(r1 - r0), 1.0f);
    float xs = x[n];
    float qv0 = lin_b[0], qv1 = lin_b[1], qv2 = lin_b[2], qv3 = lin_b[3];
    #pragma unroll
    for (int o = 0; o < 16; o++){
        float h = agg[o] / deg + xs * root[o] + bias[o];
        float e = (h > 0.f) ? h : expm1f(h);
        qv0 += e * lin_w[o*4 + 0];
        qv1 += e * lin_w[o*4 + 1];
        qv2 += e * lin_w[o*4 + 2];
        qv3 += e * lin_w[o*4 + 3];
    }
    float inv = 1.0f / (sqrtf(qv0*qv0 + qv1*qv1 + qv2*qv2 + qv3*qv3) + EPS);
    pose[(size_t)n*4 + 0] = qv0*inv;
    pose[(size_t)n*4 + 1] = qv1*inv;
    pose[(size_t)n*4 + 2] = qv2*inv;
    pose[(size_t)n*4 + 3] = qv3*inv;
    act[n] = xs;
}

// ================= capsule routing — thread-per-node (large N, small I*J) ======
template<int I, int J>
__device__ __forceinline__ void pred_ij(const float* qn, int i, int j,
                                        float rx, float ry, float rz, float rw,
                                        float& ox, float& oy, float& oz, float& ow){
    const float* qq = &qn[(i*J + j)*4];
    float qx = qq[0], qy = qq[1], qz = qq[2], qw = qq[3];
    float tx = qw*rx + qx*rw + qy*rz - qz*ry;
    float ty = qw*ry - qx*rz + qy*rw + qz*rx;
    float tz = qw*rz + qx*ry - qy*rx + qz*rw;
    float tw = qw*rw - qx*rx - qy*ry - qz*rz;
    float inv = 1.0f / (sqrtf(tx*tx + ty*ty + tz*tz + tw*tw) + EPS);
    ox = tx*inv; oy = ty*inv; oz = tz*inv; ow = tw*inv;
}

// __launch_bounds__(64,2): cap VGPR at ~256 so bb/cc/v arrays stay in registers
// (default heuristic picked 64 VGPR and spilled everything to scratch).
template<int I, int J>
__global__ __launch_bounds__(64, 2)
void caps_kernel(const float* __restrict__ poseIn, const float* __restrict__ actIn,
                 const float* __restrict__ q, float* __restrict__ poseOut,
                 float* __restrict__ actOut, int N){
    __shared__ float qn[I*J*4];
    for (int t = threadIdx.x; t < I*J; t += blockDim.x){
        float a = q[t*4], b = q[t*4+1], c = q[t*4+2], d = q[t*4+3];
        float inv = 1.0f / (sqrtf(a*a + b*b + c*c + d*d) + EPS);
        qn[t*4] = a*inv; qn[t*4+1] = b*inv; qn[t*4+2] = c*inv; qn[t*4+3] = d*inv;
    }
    __syncthreads();
    int n = blockIdx.x*blockDim.x + threadIdx.x;
    if (n >= N) return;

    float px[I], py[I], pz[I], pw[I], a[I];
    #pragma unroll
    for (int i = 0; i < I; i++){
        size_t base = ((size_t)n*I + i)*4;
        px[i] = poseIn[base]; py[i] = poseIn[base+1];
        pz[i] = poseIn[base+2]; pw[i] = poseIn[base+3];
        a[i] = actIn[(size_t)n*I + i];
    }
    float bb[I][J], cc[I][J], v[J][4], logit[J];
    #pragma unroll
    for (int i = 0; i < I; i++)
        #pragma unroll
        for (int j = 0; j < J; j++) bb[i][j] = 0.f;

    for (int t = 0; t < 3; t++){
        #pragma unroll
        for (int i = 0; i < I; i++){
            float mb = bb[i][0];
            #pragma unroll
            for (int j = 1; j < J; j++) mb = fmaxf(mb, bb[i][j]);
            float sum = 0.f;
            #pragma unroll
            for (int j = 0; j < J; j++){ float e = expf(bb[i][j] - mb); cc[i][j] = e; sum += e; }
            float sc = a[i] / sum;
            #pragma unroll
            for (int j = 0; j < J; j++) cc[i][j] *= sc;
        }
        #pragma unroll
        for (int j = 0; j < J; j++){ v[j][0]=0.f; v[j][1]=0.f; v[j][2]=0.f; v[j][3]=0.f; }
        #pragma unroll
        for (int i = 0; i < I; i++){
            #pragma unroll
            for (int j = 0; j < J; j++){
                float ox, oy, oz, ow;
                pred_ij<I,J>(qn, i, j, px[i], py[i], pz[i], pw[i], ox, oy, oz, ow);
                float ci = cc[i][j];
                v[j][0] += ci*ox; v[j][1] += ci*oy; v[j][2] += ci*oz; v[j][3] += ci*ow;
            }
        }
        #pragma unroll
        for (int j = 0; j < J; j++){
            float inv = 1.0f / (sqrtf(v[j][0]*v[j][0] + v[j][1]*v[j][1] +
                                      v[j][2]*v[j][2] + v[j][3]*v[j][3]) + EPS);
            v[j][0] *= inv; v[j][1] *= inv; v[j][2] *= inv; v[j][3] *= inv;
        }
        if (t < 2){
            #pragma unroll
            for (int i = 0; i < I; i++)
                #pragma unroll
                for (int j = 0; j < J; j++){
                    float ox, oy, oz, ow;
                    pred_ij<I,J>(qn, i, j, px[i], py[i], pz[i], pw[i], ox, oy, oz, ow);
                    bb[i][j] += ox*v[j][0] + oy*v[j][1] + oz*v[j][2] + ow*v[j][3];
                }
        } else {
            #pragma unroll
            for (int j = 0; j < J; j++) logit[j] = 0.f;
            #pragma unroll
            for (int i = 0; i < I; i++)
                #pragma unroll
                for (int j = 0; j < J; j++){
                    float ox, oy, oz, ow;
                    pred_ij<I,J>(qn, i, j, px[i], py[i], pz[i], pw[i], ox, oy, oz, ow);
                    logit[j] += cc[i][j]*(ox*v[j][0] + oy*v[j][1] + oz*v[j][2] + ow*v[j][3]);
                }
        }
    }
    #pragma unroll
    for (int j = 0; j < J; j++){
        size_t base = ((size_t)n*J + j)*4;
        poseOut[base]   = v[j][0];
        poseOut[base+1] = v[j][1];
        poseOut[base+2] = v[j][2];
        poseOut[base+3] = v[j][3];
        actOut[(size_t)n*J + j] = sigmoidf_(logit[j]);
    }
}

// ====== capsule routing — cooperative block-per-node (small N, large I*J) ======
// One block per node; thread (i,j) holds pred/b/c in registers; LDS reductions.
// No per-thread arrays -> no scratch spills (the 517us/64-VGPR pathology of R4).
template<int I, int J, int T>
__global__ __launch_bounds__(T)
void caps_coop_kernel(const float* __restrict__ poseIn, const float* __restrict__ actIn,
                      const float* __restrict__ q, float* __restrict__ poseOut,
                      float* __restrict__ actOut){
    const int node = blockIdx.x;
    const int tid  = threadIdx.x;
    const int i = tid / J, j = tid - i*J;
    const bool on = (tid < I*J);

    __shared__ float redA[I*J];
    __shared__ float redB[I*J];
    __shared__ float cp[I*J*4];
    __shared__ float vsh[J*4];

    float prx=0.f, pry=0.f, prz=0.f, prw=0.f, ai=0.f;
    if (on){
        float qx = q[(i*J+j)*4+0], qy = q[(i*J+j)*4+1],
              qz = q[(i*J+j)*4+2], qw = q[(i*J+j)*4+3];
        float qinv = 1.0f/(sqrtf(qx*qx+qy*qy+qz*qz+qw*qw)+EPS);
        qx*=qinv; qy*=qinv; qz*=qinv; qw*=qinv;
        const float* pp = &poseIn[((size_t)node*I + i)*4];
        float rx=pp[0], ry=pp[1], rz=pp[2], rw=pp[3];
        ai = actIn[(size_t)node*I + i];
        float tx = qw*rx + qx*rw + qy*rz - qz*ry;
        float ty = qw*ry - qx*rz + qy*rw + qz*rx;
        float tz = qw*rz + qx*ry - qy*rx + qz*rw;
        float tw = qw*rw - qx*rx - qy*ry - qz*rz;
        float pinv = 1.0f/(sqrtf(tx*tx+ty*ty+tz*tz+tw*tw)+EPS);
        prx=tx*pinv; pry=ty*pinv; prz=tz*pinv; prw=tw*pinv;
    }

    float b = 0.f, c = 0.f;
    for (int t = 0; t < 3; t++){
        if (on) redA[tid] = b;
        __syncthreads();
        float e = 0.f;
        if (on){
            float mb = -INFINITY;
            for (int jj = 0; jj < J; jj++) mb = fmaxf(mb, redA[i*J+jj]);
            e = expf(b - mb);
            redB[tid] = e;
        }
        __syncthreads();
        if (on){
            float s = 0.f;
            for (int jj = 0; jj < J; jj++) s += redB[i*J+jj];
            c = ai * e / s;
            cp[tid*4+0] = c*prx; cp[tid*4+1] = c*pry;
            cp[tid*4+2] = c*prz; cp[tid*4+3] = c*prw;
        }
        __syncthreads();
        if (tid < J*4){
            int jj = tid >> 2, comp = tid & 3;
            float s = 0.f;
            for (int ii = 0; ii < I; ii++) s += cp[(ii*J+jj)*4+comp];
            vsh[tid] = s;
        }
        __syncthreads();
        if (tid < J){
            float a0=vsh[tid*4], a1=vsh[tid*4+1], a2=vsh[tid*4+2], a3=vsh[tid*4+3];
            float inv = 1.0f/(sqrtf(a0*a0+a1*a1+a2*a2+a3*a3)+EPS);
            vsh[tid*4]=a0*inv; vsh[tid*4+1]=a1*inv; vsh[tid*4+2]=a2*inv; vsh[tid*4+3]=a3*inv;
        }
        __syncthreads();
        if (t < 2){
            if (on)
                b += prx*vsh[j*4] + pry*vsh[j*4+1] + prz*vsh[j*4+2] + prw*vsh[j*4+3];
        } else {
            if (on)
                redA[tid] = c*(prx*vsh[j*4] + pry*vsh[j*4+1] + prz*vsh[j*4+2] + prw*vsh[j*4+3]);
            __syncthreads();
            if (tid < J){
                float s = 0.f;
                for (int ii = 0; ii < I; ii++) s += redA[ii*J+tid];
                actOut[(size_t)node*J + tid] = sigmoidf_(s);
                poseOut[((size_t)node*J+tid)*4+0] = vsh[tid*4+0];
                poseOut[((size_t)node*J+tid)*4+1] = vsh[tid*4+1];
                poseOut[((size_t)node*J+tid)*4+2] = vsh[tid*4+2];
                poseOut[((size_t)node*J+tid)*4+3] = vsh[tid*4+3];
            }
        }
    }
}

// ================= pooling (shared helpers) =================
__device__ __forceinline__ int voxel_id(const float* __restrict__ pos, int n, int G,
                                        float start, float size){
    int g[3];
    #pragma unroll
    for (int k = 0; k < 3; k++){
        float gg = floorf((pos[(size_t)n*3 + k] - start) / size);
        gg = fminf(fmaxf(gg, 0.f), (float)(G - 1));
        g[k] = (int)gg;
    }
    return (g[0]*G + g[1])*G + g[2];
}

__device__ __forceinline__ void pool_geom(const unsigned* mm, int G, int mode,
                                          float& start, float& size){
    float mn = u2f_(mm[0]), mx = u2f_(mm[1]);
    if (mode == 0){ start = mn; size = (mx + 0.001f - mn) / (float)G; }
    else          { start = mn - 0.5f; size = mx - mn + 1.0f; }
}

// ---------- pool1 (large V) : global-atomic path ----------
__global__ void pool_scatter1(const float* __restrict__ pose, const float* __restrict__ act,
                              const float* __restrict__ pos,
                              float* __restrict__ s, float* __restrict__ wsum,
                              float* __restrict__ cnt, float* __restrict__ psum,
                              int N, int J, int G, int mode, const unsigned* __restrict__ mm){
    int n = blockIdx.x*blockDim.x + threadIdx.x;
    if (n >= N) return;
    float start, size; pool_geom(mm, G, mode, start, size);
    int vid = voxel_id(pos, n, G, start, size);
    for (int j = 0; j < J; j++){
        float aj = act[(size_t)n*J + j];
        size_t pb = ((size_t)n*J + j)*4;
        size_t sb = ((size_t)vid*J + j)*4;
        atomicAdd(&s[sb],   aj*pose[pb]);
        atomicAdd(&s[sb+1], aj*pose[pb+1]);
        atomicAdd(&s[sb+2], aj*pose[pb+2]);
        atomicAdd(&s[sb+3], aj*pose[pb+3]);
        atomicAdd(&wsum[(size_t)vid*J + j], aj);
    }
    atomicAdd(&cnt[vid], 1.0f);
    atomicAdd(&psum[(size_t)vid*3 + 0], pos[(size_t)n*3 + 0]);
    atomicAdd(&psum[(size_t)vid*3 + 1], pos[(size_t)n*3 + 1]);
    atomicAdd(&psum[(size_t)vid*3 + 2], pos[(size_t)n*3 + 2]);
}

__global__ void pool_m(const float* __restrict__ s, float* __restrict__ m, int VJ){
    int t = blockIdx.x*blockDim.x + threadIdx.x;
    if (t >= VJ) return;
    float a = s[(size_t)t*4], b = s[(size_t)t*4+1], c = s[(size_t)t*4+2], d = s[(size_t)t*4+3];
    float inv = 1.0f / (sqrtf(a*a + b*b + c*c + d*d) + EPS);
    m[(size_t)t*4]   = a*inv;
    m[(size_t)t*4+1] = b*inv;
    m[(size_t)t*4+2] = c*inv;
    m[(size_t)t*4+3] = d*inv;
}

__global__ void pool_scatter2(const float* __restrict__ pose, const float* __restrict__ act,
                              const float* __restrict__ pos, const float* __restrict__ m,
                              float* __restrict__ agacc,
                              int N, int J, int G, int mode, const unsigned* __restrict__ mm){
    int n = blockIdx.x*blockDim.x + threadIdx.x;
    if (n >= N) return;
    float start, size; pool_geom(mm, G, mode, start, size);
    int vid = voxel_id(pos, n, G, start, size);
    for (int j = 0; j < J; j++){
        size_t pb = ((size_t)n*J + j)*4;
        size_t mb = ((size_t)vid*J + j)*4;
        float agree = pose[pb]*m[mb] + pose[pb+1]*m[mb+1] + pose[pb+2]*m[mb+2] + pose[pb+3]*m[mb+3];
        atomicAdd(&agacc[(size_t)vid*J + j], act[(size_t)n*J + j]*agree);
    }
}

__global__ void pool_fin(const float* __restrict__ agacc, const float* __restrict__ wsum,
                         const float* __restrict__ cnt, const float* __restrict__ psum,
                         float* __restrict__ actOut, float* __restrict__ posOut, int V, int J){
    int t = blockIdx.x*blockDim.x + threadIdx.x;
    if (t >= V*J) return;
    int v = t / J, j = t % J;
    actOut[t] = sigmoidf_(agacc[t] / (wsum[t] + EPS));
    if (j == 0){
        float c = cnt[v] + EPS;
        posOut[(size_t)v*3 + 0] = psum[(size_t)v*3 + 0] / c;
        posOut[(size_t)v*3 + 1] = psum[(size_t)v*3 + 1] / c;
        posOut[(size_t)v*3 + 2] = psum[(size_t)v*3 + 2] / c;
    }
}

// ---------- pool2 (mid V) : multi-block LDS-privatized, global-atomic merge ----------
template<int V, int J, int CH, int NCHUNK>
__global__ void pool_priv1(const float4* __restrict__ poseIn, const float* __restrict__ actIn,
                           const float* __restrict__ posIn,
                           float* __restrict__ s, float* __restrict__ wsum,
                           float* __restrict__ cnt, float* __restrict__ psum,
                           int N, int G, int mode, const unsigned* __restrict__ mm){
    __shared__ float s_[V*CH*4];
    __shared__ float wsum_[V*CH];
    __shared__ float cnt_[V];
    __shared__ float psum_[V*3];
    const int chunk = blockIdx.x % NCHUNK;
    const int slice = blockIdx.x / NCHUNK;
    const int nslices = gridDim.x / NCHUNK;
    const int c0 = chunk * CH;

    for (int t = threadIdx.x; t < V*CH*4; t += blockDim.x) s_[t] = 0.f;
    for (int t = threadIdx.x; t < V*CH; t += blockDim.x) wsum_[t] = 0.f;
    if (chunk == 0){
        for (int t = threadIdx.x; t < V; t += blockDim.x) cnt_[t] = 0.f;
        for (int t = threadIdx.x; t < V*3; t += blockDim.x) psum_[t] = 0.f;
    }
    __syncthreads();

    float start, size; pool_geom(mm, G, mode, start, size);
    int per = (N + nslices - 1) / nslices;
    int n0 = slice * per, n1 = min(N, n0 + per);

    for (int n = n0 + (int)threadIdx.x; n < n1; n += blockDim.x){
        int vid = voxel_id(posIn, n, G, start, size);
        #pragma unroll
        for (int jj = 0; jj < CH; jj++){
            int j = c0 + jj;
            float aj = actIn[(size_t)n*J + j];
            float4 p = poseIn[(size_t)n*J + j];
            int b = (vid*CH + jj)*4;
            atomicAdd(&s_[b+0], aj*p.x);
            atomicAdd(&s_[b+1], aj*p.y);
            atomicAdd(&s_[b+2], aj*p.z);
            atomicAdd(&s_[b+3], aj*p.w);
            atomicAdd(&wsum_[vid*CH + jj], aj);
        }
        if (chunk == 0){
            atomicAdd(&cnt_[vid], 1.0f);
            atomicAdd(&psum_[vid*3+0], posIn[(size_t)n*3+0]);
            atomicAdd(&psum_[vid*3+1], posIn[(size_t)n*3+1]);
            atomicAdd(&psum_[vid*3+2], posIn[(size_t)n*3+2]);
        }
    }
    __syncthreads();

    for (int t = threadIdx.x; t < V*CH*4; t += blockDim.x){
        float val = s_[t];
        if (val != 0.f){
            int v = t / (CH*4), r = t % (CH*4);
            atomicAdd(&s[((size_t)v*J + c0)*4 + r], val);
        }
    }
    for (int t = threadIdx.x; t < V*CH; t += blockDim.x){
        float val = wsum_[t];
        if (val != 0.f){
            int v = t / CH, jj = t % CH;
            atomicAdd(&wsum[(size_t)v*J + c0 + jj], val);
        }
    }
    if (chunk == 0){
        for (int t = threadIdx.x; t < V; t += blockDim.x)
            if (cnt_[t] != 0.f) atomicAdd(&cnt[t], cnt_[t]);
        for (int t = threadIdx.x; t < V*3; t += blockDim.x)
            if (psum_[t] != 0.f) atomicAdd(&psum[t], psum_[t]);
    }
}

template<int V, int J>
__global__ void pool_priv2(const float4* __restrict__ poseIn, const float* __restrict__ actIn,
                           const float* __restrict__ posIn, const float4* __restrict__ m,
                           float* __restrict__ agacc,
                           int N, int G, int mode, const unsigned* __restrict__ mm){
    __shared__ float ag_[V*J];
    for (int t = threadIdx.x; t < V*J; t += blockDim.x) ag_[t] = 0.f;
    __syncthreads();
    float start, size; pool_geom(mm, G, mode, start, size);
    int nslices = gridDim.x;
    int per = (N + nslices - 1) / nslices;
    int n0 = blockIdx.x * per, n1 = min(N, n0 + per);
    for (int n = n0 + (int)threadIdx.x; n < n1; n += blockDim.x){
        int vid = voxel_id(posIn, n, G, start, size);
        #pragma unroll
        for (int j = 0; j < J; j++){
            float4 p  = poseIn[(size_t)n*J + j];
            float4 mv = m[(size_t)vid*J + j];
            float agree = p.x*mv.x + p.y*mv.y + p.z*mv.z + p.w*mv.w;
            atomicAdd(&ag_[vid*J + j], actIn[(size_t)n*J + j]*agree);
        }
    }
    __syncthreads();
    for (int t = threadIdx.x; t < V*J; t += blockDim.x)
        if (ag_[t] != 0.f) atomicAdd(&agacc[t], ag_[t]);
}

// ---------- pools 3-4 (tiny) : single fused LDS kernel ----------
template<int V, int J, int CH>
__global__ void pool_fused_kernel(const float* __restrict__ poseIn, const float* __restrict__ actIn,
                                  const float* __restrict__ posIn,
                                  float* __restrict__ poseOut, float* __restrict__ actOut,
                                  float* __restrict__ posOut,
                                  int N, int G, int mode, const unsigned* __restrict__ mm){
    __shared__ float s_[V*CH*4];
    __shared__ float wsum_[V*CH];
    __shared__ float ag_[V*CH];
    __shared__ float cnt_[V];
    __shared__ float psum_[V*3];
    const int c0 = blockIdx.x * CH;

    for (int t = threadIdx.x; t < V*CH*4; t += blockDim.x) s_[t] = 0.f;
    for (int t = threadIdx.x; t < V*CH; t += blockDim.x){ wsum_[t] = 0.f; ag_[t] = 0.f; }
    if (blockIdx.x == 0){
        for (int t = threadIdx.x; t < V; t += blockDim.x) cnt_[t] = 0.f;
        for (int t = threadIdx.x; t < V*3; t += blockDim.x) psum_[t] = 0.f;
    }
    __syncthreads();

    float start, size; pool_geom(mm, G, mode, start, size);

    for (int n = threadIdx.x; n < N; n += blockDim.x){
        int vid = voxel_id(posIn, n, G, start, size);
        #pragma unroll
        for (int jj = 0; jj < CH; jj++){
            int j = c0 + jj;
            float aj = actIn[(size_t)n*J + j];
            const float* pb = &poseIn[((size_t)n*J + j)*4];
            int b = (vid*CH + jj)*4;
            atomicAdd(&s_[b+0], aj*pb[0]);
            atomicAdd(&s_[b+1], aj*pb[1]);
            atomicAdd(&s_[b+2], aj*pb[2]);
            atomicAdd(&s_[b+3], aj*pb[3]);
            atomicAdd(&wsum_[vid*CH + jj], aj);
        }
        if (blockIdx.x == 0){
            atomicAdd(&cnt_[vid], 1.0f);
            atomicAdd(&psum_[vid*3+0], posIn[(size_t)n*3+0]);
            atomicAdd(&psum_[vid*3+1], posIn[(size_t)n*3+1]);
            atomicAdd(&psum_[vid*3+2], posIn[(size_t)n*3+2]);
        }
    }
    __syncthreads();

    for (int t = threadIdx.x; t < V*CH; t += blockDim.x){
        float a = s_[t*4], b = s_[t*4+1], c = s_[t*4+2], d = s_[t*4+3];
        float inv = 1.0f / (sqrtf(a*a + b*b + c*c + d*d) + EPS);
        s_[t*4] = a*inv; s_[t*4+1] = b*inv; s_[t*4+2] = c*inv; s_[t*4+3] = d*inv;
    }
    __syncthreads();

    for (int n = threadIdx.x; n < N; n += blockDim.x){
        int vid = voxel_id(posIn, n, G, start, size);
        #pragma unroll
        for (int jj = 0; jj < CH; jj++){
            int j = c0 + jj;
            const float* pb = &poseIn[((size_t)n*J + j)*4];
            const float* mb = &s_[(vid*CH + jj)*4];
            float agree = pb[0]*mb[0] + pb[1]*mb[1] + pb[2]*mb[2] + pb[3]*mb[3];
            atomicAdd(&ag_[vid*CH + jj], actIn[(size_t)n*J + j]*agree);
        }
    }
    __syncthreads();

    for (int t = threadIdx.x; t < V*CH; t += blockDim.x){
        int v = t / CH, jj = t % CH;
        size_t o = (size_t)v*J + c0 + jj;
        actOut[o] = sigmoidf_(ag_[t] / (wsum_[t] + EPS));
        poseOut[o*4+0] = s_[t*4+0];
        poseOut[o*4+1] = s_[t*4+1];
        poseOut[o*4+2] = s_[t*4+2];
        poseOut[o*4+3] = s_[t*4+3];
    }
    if (blockIdx.x == 0){
        for (int v = threadIdx.x; v < V; v += blockDim.x){
            float c = cnt_[v] + EPS;
            posOut[(size_t)v*3+0] = psum_[(size_t)v*3+0] / c;
            posOut[(size_t)v*3+1] = psum_[(size_t)v*3+1] / c;
            posOut[(size_t)v*3+2] = psum_[(size_t)v*3+2] / c;
        }
    }
}

extern "C" void kernel_launch(void* const* d_in, const int* in_sizes, int n_in,
                              void* d_out, int out_size, void* d_ws, size_t ws_size,
                              hipStream_t stream){
    const float* x      = (const float*)d_in[0];
    const float* pos    = (const float*)d_in[1];
    const float* pseudo = (const float*)d_in[2];
    const float* Wsp    = (const float*)d_in[3];
    const float* root   = (const float*)d_in[4];
    const float* bias   = (const float*)d_in[5];
    const float* lin_w  = (const float*)d_in[6];
    const float* lin_b  = (const float*)d_in[7];
    const float* q0     = (const float*)d_in[8];
    const float* q1     = (const float*)d_in[9];
    const float* q3     = (const float*)d_in[10];
    const float* q5     = (const float*)d_in[11];
    const float* q6     = (const float*)d_in[12];
    const float* q7     = (const float*)d_in[13];
    const int*   ei     = (const int*)d_in[14];
    const int N = in_sizes[0];
    const int E = in_sizes[2] / 3;

    char* ws = (char*)d_ws;
    size_t off = 0;
    auto alloc = [&](size_t bytes)->void*{
        void* p = ws + off;
        off += (bytes + 255) & ~(size_t)255;
        return p;
    };
    unsigned* mm   = (unsigned*)alloc(8);
    int* ecnt      = (int*)alloc((size_t)N*sizeof(int));
    int* rowptr    = (int*)alloc((size_t)(N+1)*sizeof(int));
    int* cursor    = (int*)alloc((size_t)N*sizeof(int));
    float4* payload= (float4*)alloc((size_t)E*sizeof(float4));
    float* P0  = (float*)alloc((size_t)1250000*sizeof(float));
    float* P1  = (float*)alloc((size_t)1250000*sizeof(float));
    float* A0  = (float*)alloc((size_t)310000*sizeof(float));
    float* A1  = (float*)alloc((size_t)310000*sizeof(float));
    float* PB0 = (float*)alloc((size_t)100000*sizeof(float));
    float* PB1 = (float*)alloc((size_t)100000*sizeof(float));
    float* vs  = (float*)alloc((size_t)800000*sizeof(float));
    float* vw  = (float*)alloc((size_t)200000*sizeof(float));
    float* va  = (float*)alloc((size_t)200000*sizeof(float));
    float* vc  = (float*)alloc((size_t)33000*sizeof(float));
    float* vp  = (float*)alloc((size_t)100000*sizeof(float));

    hipMemsetAsync(mm,     0xFF, 4, stream);
    hipMemsetAsync(mm + 1, 0x00, 4, stream);
    hipMemsetAsync(ecnt, 0, (size_t)N*sizeof(int), stream);

    minmax_kernel<<<80, 256, 0, stream>>>(pos, N*3, mm);

    // CSR build + fused spline gather / node finalize (no float atomics)
    hist_kernel<<<(E + 255)/256, 256, 0, stream>>>(ei, ecnt, E);
    scan_kernel<<<1, 1024, 0, stream>>>(ecnt, rowptr, cursor, N);
    scatter_kernel<<<(E + 255)/256, 256, 0, stream>>>(pseudo, ei, cursor, payload, E);
    spline_node_kernel<<<(N + 255)/256, 256, 0, stream>>>(x, payload, rowptr, Wsp,
                                                          root, bias, lin_w, lin_b, P0, A0, N);

    caps_kernel<1,6><<<(N + 63)/64, 64, 0, stream>>>(P0, A0, q0, P1, A1, N);
    caps_kernel<6,6><<<(N + 63)/64, 64, 0, stream>>>(P1, A1, q1, P0, A0, N);

    // pool1: 50000 nodes -> 32768 voxels (G=32), J=6 — global-atomic path (low contention)
    {
        const int V = 32768, J = 6, G = 32;
        hipMemsetAsync(vs, 0, (size_t)V*J*4*sizeof(float), stream);
        hipMemsetAsync(vw, 0, (size_t)V*J*sizeof(float),   stream);
        hipMemsetAsync(va, 0, (size_t)V*J*sizeof(float),   stream);
        hipMemsetAsync(vc, 0, (size_t)V*sizeof(float),     stream);
        hipMemsetAsync(vp, 0, (size_t)V*3*sizeof(float),   stream);
        int gN = (N + 255)/256, gV = (V*J + 255)/256;
        pool_scatter1<<<gN, 256, 0, stream>>>(P0, A0, pos, vs, vw, vc, vp, N, J, G, 0, mm);
        pool_m<<<gV, 256, 0, stream>>>(vs, P1, V*J);
        pool_scatter2<<<gN, 256, 0, stream>>>(P0, A0, pos, P1, va, N, J, G, 0, mm);
        pool_fin<<<gV, 256, 0, stream>>>(va, vw, vc, vp, A1, PB0, V, J);
    }
    caps_kernel<6,8><<<(32768 + 63)/64, 64, 0, stream>>>(P1, A1, q3, P0, A0, 32768);

    // pool2: 32768 -> 512 (G=8), J=8 — multi-block LDS-privatized path
    {
        const int V = 512, J = 8, G = 8, NSL = 16;
        hipMemsetAsync(vs, 0, (size_t)V*J*4*sizeof(float), stream);
        hipMemsetAsync(vw, 0, (size_t)V*J*sizeof(float),   stream);
        hipMemsetAsync(va, 0, (size_t)V*J*sizeof(float),   stream);
        hipMemsetAsync(vc, 0, (size_t)V*sizeof(float),     stream);
        hipMemsetAsync(vp, 0, (size_t)V*3*sizeof(float),   stream);
        pool_priv1<V,J,4,2><<<2*NSL, 256, 0, stream>>>((const float4*)P0, A0, PB0,
                                                       vs, vw, vc, vp, 32768, G, 0, mm);
        pool_m<<<(V*J + 255)/256, 256, 0, stream>>>(vs, P1, V*J);
        pool_priv2<V,J><<<NSL, 256, 0, stream>>>((const float4*)P0, A0, PB0,
                                                 (const float4*)P1, va, 32768, G, 0, mm);
        pool_fin<<<(V*J + 255)/256, 256, 0, stream>>>(va, vw, vc, vp, A1, PB1, V, J);
    }
    // caps 8->12 over 512 voxels: cooperative block-per-node (I*J=96, T=128)
    caps_coop_kernel<8,12,128><<<512, 128, 0, stream>>>(P1, A1, q5, P0, A0);

    // pool3: 512 -> 8 (G=2), J=12 — fused LDS path, 1 block
    pool_fused_kernel<8,12,12><<<1, 1024, 0, stream>>>(P0, A0, PB1, P1, A1, PB0, 512, 2, 0, mm);
    // caps 12->14 over 8 nodes: cooperative (I*J=168, T=192)
    caps_coop_kernel<12,14,192><<<8, 192, 0, stream>>>(P1, A1, q6, P0, A0);

    // pool4: 8 -> 1 (G=1, mode=1), J=14 — fused LDS path, 1 block
    pool_fused_kernel<1,14,14><<<1, 1024, 0, stream>>>(P0, A0, PB0, P1, A1, PB1, 8, 1, 1, mm);
    // caps 14->10 over 1 node: cooperative (I*J=140, T=192)
    caps_coop_kernel<14,10,192><<<1, 192, 0, stream>>>(P1, A1, q7, P0, (float*)d_out);
}

// Round 7
// 730.631 us; speedup vs baseline: 7.8263x; 1.2645x over previous
//
#include <hip/hip_runtime.h>
#include <math.h>

#define EPS 1e-4f

__device__ __forceinline__ float sigmoidf_(float x){ return 1.0f/(1.0f+expf(-x)); }

// ---- ordered-uint mapping for float atomic min/max ----
__device__ __forceinline__ unsigned f2u_(float f){
    unsigned u = __float_as_uint(f);
    return (u & 0x80000000u) ? ~u : (u | 0x80000000u);
}
__device__ __forceinline__ float u2f_(unsigned u){
    unsigned b = (u & 0x80000000u) ? (u & 0x7FFFFFFFu) : ~u;
    return __uint_as_float(b);
}

// ================= min/max of pos =================
__global__ void minmax_kernel(const float* __restrict__ p, int n, unsigned* mm){
    float lo = INFINITY, hi = -INFINITY;
    for (int i = blockIdx.x*blockDim.x + threadIdx.x; i < n; i += gridDim.x*blockDim.x){
        float v = p[i]; lo = fminf(lo, v); hi = fmaxf(hi, v);
    }
    for (int off = 32; off > 0; off >>= 1){
        lo = fminf(lo, __shfl_down(lo, off));
        hi = fmaxf(hi, __shfl_down(hi, off));
    }
    __shared__ float slo[8], shi[8];
    int wid = threadIdx.x >> 6;
    if ((threadIdx.x & 63) == 0){ slo[wid] = lo; shi[wid] = hi; }
    __syncthreads();
    if (threadIdx.x == 0){
        int nw = blockDim.x >> 6;
        for (int w = 1; w < nw; w++){ lo = fminf(lo, slo[w]); hi = fmaxf(hi, shi[w]); }
        atomicMin(&mm[0], f2u_(lo));
        atomicMax(&mm[1], f2u_(hi));
    }
}

// ================= CSR build for spline conv =================
__global__ void hist_kernel(const int* __restrict__ ei, int* __restrict__ cnt, int E){
    int e = blockIdx.x*blockDim.x + threadIdx.x;
    if (e < E) atomicAdd(&cnt[ei[E + e]], 1);
}

__global__ void scan_kernel(const int* __restrict__ cnt, int* __restrict__ rowptr,
                            int* __restrict__ cursor, int N){
    __shared__ int part[1025];
    const int T = blockDim.x;
    int t = threadIdx.x;
    int per = (N + T - 1) / T;
    int b0 = t*per, b1 = min(N, b0 + per);
    int sum = 0;
    for (int i = b0; i < b1; i++) sum += cnt[i];
    part[t+1] = sum;
    __syncthreads();
    if (t == 0){ part[0] = 0; for (int i = 1; i <= T; i++) part[i] += part[i-1]; }
    __syncthreads();
    int run = part[t];
    for (int i = b0; i < b1; i++){ rowptr[i] = run; cursor[i] = run; run += cnt[i]; }
    if (b1 == N && b0 <= N) rowptr[N] = part[T];
}

__global__ void scatter_kernel(const float* __restrict__ pseudo, const int* __restrict__ ei,
                               int* __restrict__ cursor, float4* __restrict__ payload, int E){
    int e = blockIdx.x*blockDim.x + threadIdx.x;
    if (e >= E) return;
    int d = ei[E + e];
    int slot = atomicAdd(&cursor[d], 1);
    payload[slot] = make_float4(pseudo[3*e], pseudo[3*e+1], pseudo[3*e+2],
                                __int_as_float(ei[e]));
}

// ================= fused spline gather + node finalize =================
__global__ void spline_node_kernel(const float* __restrict__ x, const float4* __restrict__ payload,
                                   const int* __restrict__ rowptr, const float* __restrict__ W,
                                   const float* __restrict__ root, const float* __restrict__ bias,
                                   const float* __restrict__ lin_w, const float* __restrict__ lin_b,
                                   float* __restrict__ pose, float* __restrict__ act, int N){
    __shared__ float Ws[125*17];
    for (int i = threadIdx.x; i < 125*16; i += blockDim.x)
        Ws[(i >> 4)*17 + (i & 15)] = W[i];
    __syncthreads();
    int n = blockIdx.x*blockDim.x + threadIdx.x;
    if (n >= N) return;

    float agg[16];
    #pragma unroll
    for (int o = 0; o < 16; o++) agg[o] = 0.f;

    int r0 = rowptr[n], r1 = rowptr[n+1];
    for (int s = r0; s < r1; s++){
        float4 pl = payload[s];
        int src = __float_as_int(pl.w);
        float xv = x[src];
        float v0 = pl.x*4.f, v1 = pl.y*4.f, v2 = pl.z*4.f;
        float f0 = fminf(fmaxf(floorf(v0), 0.f), 3.f);
        float f1 = fminf(fmaxf(floorf(v1), 0.f), 3.f);
        float f2 = fminf(fmaxf(floorf(v2), 0.f), 3.f);
        float fr0 = v0 - f0, fr1 = v1 - f1, fr2 = v2 - f2;
        int i0 = (int)f0, i1 = (int)f1, i2 = (int)f2;
        #pragma unroll
        for (int b = 0; b < 8; b++){
            int b0 = (b >> 2) & 1, b1 = (b >> 1) & 1, b2 = b & 1;
            float w = (b0 ? fr0 : 1.f - fr0) * (b1 ? fr1 : 1.f - fr1) * (b2 ? fr2 : 1.f - fr2);
            w *= xv;
            int k = ((i0 + b0)*5 + (i1 + b1))*5 + (i2 + b2);
            const float* Wr = &Ws[k*17];
            #pragma unroll
            for (int o = 0; o < 16; o++) agg[o] += w * Wr[o];
        }
    }

    float deg = fmaxf((float)(r1 - r0), 1.0f);
    float xs = x[n];
    float qv0 = lin_b[0], qv1 = lin_b[1], qv2 = lin_b[2], qv3 = lin_b[3];
    #pragma unroll
    for (int o = 0; o < 16; o++){
        float h = agg[o] / deg + xs * root[o] + bias[o];
        float e = (h > 0.f) ? h : expm1f(h);
        qv0 += e * lin_w[o*4 + 0];
        qv1 += e * lin_w[o*4 + 1];
        qv2 += e * lin_w[o*4 + 2];
        qv3 += e * lin_w[o*4 + 3];
    }
    float inv = 1.0f / (sqrtf(qv0*qv0 + qv1*qv1 + qv2*qv2 + qv3*qv3) + EPS);
    pose[(size_t)n*4 + 0] = qv0*inv;
    pose[(size_t)n*4 + 1] = qv1*inv;
    pose[(size_t)n*4 + 2] = qv2*inv;
    pose[(size_t)n*4 + 3] = qv3*inv;
    act[n] = xs;
}

// ====== capsule routing — cooperative, NPB nodes per block ======
// Thread (nl, i, j): pred/b/c in 4 registers; per-node LDS segments for the
// softmax-over-j, sum-over-i, and normalize reductions. No per-thread arrays
// -> no scratch spills. BUGFIX vs R6: the vsh (sum-over-i) reduction is a
// strided loop over J*4 entries — a node slot only has I*J threads, which is
// < J*4 when I < 4 (the <1,6> layer silently read unwritten LDS in R6).
template<int I, int J, int NPB>
__global__ __launch_bounds__(NPB*I*J)
void caps_coop_kernel(const float* __restrict__ poseIn, const float* __restrict__ actIn,
                      const float* __restrict__ q, float* __restrict__ poseOut,
                      float* __restrict__ actOut, int N){
    const int IJ = I*J;
    const int tid = threadIdx.x;
    const int nl  = tid / IJ;
    const int li  = tid - nl*IJ;
    const int i   = li / J;
    const int j   = li - i*J;
    const int node = blockIdx.x*NPB + nl;
    const bool on = (node < N);

    __shared__ float redA[NPB][I*J];
    __shared__ float redB[NPB][I*J];
    __shared__ float cp[NPB][I*J*4];
    __shared__ float vsh[NPB][J*4];

    float prx=0.f, pry=0.f, prz=0.f, prw=0.f, ai=0.f;
    if (on){
        float qx = q[li*4+0], qy = q[li*4+1], qz = q[li*4+2], qw = q[li*4+3];
        float qinv = 1.0f/(sqrtf(qx*qx+qy*qy+qz*qz+qw*qw)+EPS);
        qx*=qinv; qy*=qinv; qz*=qinv; qw*=qinv;
        const float* pp = &poseIn[((size_t)node*I + i)*4];
        float rx=pp[0], ry=pp[1], rz=pp[2], rw=pp[3];
        ai = actIn[(size_t)node*I + i];
        float tx = qw*rx + qx*rw + qy*rz - qz*ry;
        float ty = qw*ry - qx*rz + qy*rw + qz*rx;
        float tz = qw*rz + qx*ry - qy*rx + qz*rw;
        float tw = qw*rw - qx*rx - qy*ry - qz*rz;
        float pinv = 1.0f/(sqrtf(tx*tx+ty*ty+tz*tz+tw*tw)+EPS);
        prx=tx*pinv; pry=ty*pinv; prz=tz*pinv; prw=tw*pinv;
    }

    float b = 0.f, c = 0.f;
    for (int t = 0; t < 3; t++){
        redA[nl][li] = b;
        __syncthreads();
        float mb = -INFINITY;
        #pragma unroll
        for (int jj = 0; jj < J; jj++) mb = fmaxf(mb, redA[nl][i*J+jj]);
        float e = expf(b - mb);
        redB[nl][li] = e;
        __syncthreads();
        float s = 0.f;
        #pragma unroll
        for (int jj = 0; jj < J; jj++) s += redB[nl][i*J+jj];
        c = ai * e / s;
        cp[nl][li*4+0] = c*prx; cp[nl][li*4+1] = c*pry;
        cp[nl][li*4+2] = c*prz; cp[nl][li*4+3] = c*prw;
        __syncthreads();
        // sum over i: J*4 entries, strided by the I*J threads of this node slot
        for (int idx = li; idx < J*4; idx += IJ){
            int jj = idx >> 2, comp = idx & 3;
            float acc = 0.f;
            #pragma unroll
            for (int ii = 0; ii < I; ii++) acc += cp[nl][(ii*J+jj)*4+comp];
            vsh[nl][idx] = acc;
        }
        __syncthreads();
        if (li < J){
            float a0=vsh[nl][li*4], a1=vsh[nl][li*4+1], a2=vsh[nl][li*4+2], a3=vsh[nl][li*4+3];
            float inv = 1.0f/(sqrtf(a0*a0+a1*a1+a2*a2+a3*a3)+EPS);
            vsh[nl][li*4]=a0*inv; vsh[nl][li*4+1]=a1*inv;
            vsh[nl][li*4+2]=a2*inv; vsh[nl][li*4+3]=a3*inv;
        }
        __syncthreads();
        if (t < 2){
            b += prx*vsh[nl][j*4] + pry*vsh[nl][j*4+1] + prz*vsh[nl][j*4+2] + prw*vsh[nl][j*4+3];
            __syncthreads();   // vsh reused next iter only after all read it
        } else {
            redA[nl][li] = c*(prx*vsh[nl][j*4] + pry*vsh[nl][j*4+1]
                            + prz*vsh[nl][j*4+2] + prw*vsh[nl][j*4+3]);
            __syncthreads();
            if (li < J && on){
                float acc = 0.f;
                #pragma unroll
                for (int ii = 0; ii < I; ii++) acc += redA[nl][ii*J+li];
                actOut[(size_t)node*J + li] = sigmoidf_(acc);
                poseOut[((size_t)node*J+li)*4+0] = vsh[nl][li*4+0];
                poseOut[((size_t)node*J+li)*4+1] = vsh[nl][li*4+1];
                poseOut[((size_t)node*J+li)*4+2] = vsh[nl][li*4+2];
                poseOut[((size_t)node*J+li)*4+3] = vsh[nl][li*4+3];
            }
        }
    }
}

// ================= pooling (shared helpers) =================
__device__ __forceinline__ int voxel_id(const float* __restrict__ pos, int n, int G,
                                        float start, float size){
    int g[3];
    #pragma unroll
    for (int k = 0; k < 3; k++){
        float gg = floorf((pos[(size_t)n*3 + k] - start) / size);
        gg = fminf(fmaxf(gg, 0.f), (float)(G - 1));
        g[k] = (int)gg;
    }
    return (g[0]*G + g[1])*G + g[2];
}

__device__ __forceinline__ void pool_geom(const unsigned* mm, int G, int mode,
                                          float& start, float& size){
    float mn = u2f_(mm[0]), mx = u2f_(mm[1]);
    if (mode == 0){ start = mn; size = (mx + 0.001f - mn) / (float)G; }
    else          { start = mn - 0.5f; size = mx - mn + 1.0f; }
}

// ---------- pool1 (large V) : global-atomic path ----------
__global__ void pool_scatter1(const float* __restrict__ pose, const float* __restrict__ act,
                              const float* __restrict__ pos,
                              float* __restrict__ s, float* __restrict__ wsum,
                              float* __restrict__ cnt, float* __restrict__ psum,
                              int N, int J, int G, int mode, const unsigned* __restrict__ mm){
    int n = blockIdx.x*blockDim.x + threadIdx.x;
    if (n >= N) return;
    float start, size; pool_geom(mm, G, mode, start, size);
    int vid = voxel_id(pos, n, G, start, size);
    for (int j = 0; j < J; j++){
        float aj = act[(size_t)n*J + j];
        size_t pb = ((size_t)n*J + j)*4;
        size_t sb = ((size_t)vid*J + j)*4;
        atomicAdd(&s[sb],   aj*pose[pb]);
        atomicAdd(&s[sb+1], aj*pose[pb+1]);
        atomicAdd(&s[sb+2], aj*pose[pb+2]);
        atomicAdd(&s[sb+3], aj*pose[pb+3]);
        atomicAdd(&wsum[(size_t)vid*J + j], aj);
    }
    atomicAdd(&cnt[vid], 1.0f);
    atomicAdd(&psum[(size_t)vid*3 + 0], pos[(size_t)n*3 + 0]);
    atomicAdd(&psum[(size_t)vid*3 + 1], pos[(size_t)n*3 + 1]);
    atomicAdd(&psum[(size_t)vid*3 + 2], pos[(size_t)n*3 + 2]);
}

__global__ void pool_m(const float* __restrict__ s, float* __restrict__ m, int VJ){
    int t = blockIdx.x*blockDim.x + threadIdx.x;
    if (t >= VJ) return;
    float a = s[(size_t)t*4], b = s[(size_t)t*4+1], c = s[(size_t)t*4+2], d = s[(size_t)t*4+3];
    float inv = 1.0f / (sqrtf(a*a + b*b + c*c + d*d) + EPS);
    m[(size_t)t*4]   = a*inv;
    m[(size_t)t*4+1] = b*inv;
    m[(size_t)t*4+2] = c*inv;
    m[(size_t)t*4+3] = d*inv;
}

__global__ void pool_scatter2(const float* __restrict__ pose, const float* __restrict__ act,
                              const float* __restrict__ pos, const float* __restrict__ m,
                              float* __restrict__ agacc,
                              int N, int J, int G, int mode, const unsigned* __restrict__ mm){
    int n = blockIdx.x*blockDim.x + threadIdx.x;
    if (n >= N) return;
    float start, size; pool_geom(mm, G, mode, start, size);
    int vid = voxel_id(pos, n, G, start, size);
    for (int j = 0; j < J; j++){
        size_t pb = ((size_t)n*J + j)*4;
        size_t mb = ((size_t)vid*J + j)*4;
        float agree = pose[pb]*m[mb] + pose[pb+1]*m[mb+1] + pose[pb+2]*m[mb+2] + pose[pb+3]*m[mb+3];
        atomicAdd(&agacc[(size_t)vid*J + j], act[(size_t)n*J + j]*agree);
    }
}

__global__ void pool_fin(const float* __restrict__ agacc, const float* __restrict__ wsum,
                         const float* __restrict__ cnt, const float* __restrict__ psum,
                         float* __restrict__ actOut, float* __restrict__ posOut, int V, int J){
    int t = blockIdx.x*blockDim.x + threadIdx.x;
    if (t >= V*J) return;
    int v = t / J, j = t % J;
    actOut[t] = sigmoidf_(agacc[t] / (wsum[t] + EPS));
    if (j == 0){
        float c = cnt[v] + EPS;
        posOut[(size_t)v*3 + 0] = psum[(size_t)v*3 + 0] / c;
        posOut[(size_t)v*3 + 1] = psum[(size_t)v*3 + 1] / c;
        posOut[(size_t)v*3 + 2] = psum[(size_t)v*3 + 2] / c;
    }
}

// ---------- pool2 (mid V) : multi-block LDS-privatized, global-atomic merge ----------
template<int V, int J, int CH, int NCHUNK>
__global__ void pool_priv1(const float4* __restrict__ poseIn, const float* __restrict__ actIn,
                           const float* __restrict__ posIn,
                           float* __restrict__ s, float* __restrict__ wsum,
                           float* __restrict__ cnt, float* __restrict__ psum,
                           int N, int G, int mode, const unsigned* __restrict__ mm){
    __shared__ float s_[V*CH*4];
    __shared__ float wsum_[V*CH];
    __shared__ float cnt_[V];
    __shared__ float psum_[V*3];
    const int chunk = blockIdx.x % NCHUNK;
    const int slice = blockIdx.x / NCHUNK;
    const int nslices = gridDim.x / NCHUNK;
    const int c0 = chunk * CH;

    for (int t = threadIdx.x; t < V*CH*4; t += blockDim.x) s_[t] = 0.f;
    for (int t = threadIdx.x; t < V*CH; t += blockDim.x) wsum_[t] = 0.f;
    if (chunk == 0){
        for (int t = threadIdx.x; t < V; t += blockDim.x) cnt_[t] = 0.f;
        for (int t = threadIdx.x; t < V*3; t += blockDim.x) psum_[t] = 0.f;
    }
    __syncthreads();

    float start, size; pool_geom(mm, G, mode, start, size);
    int per = (N + nslices - 1) / nslices;
    int n0 = slice * per, n1 = min(N, n0 + per);

    for (int n = n0 + (int)threadIdx.x; n < n1; n += blockDim.x){
        int vid = voxel_id(posIn, n, G, start, size);
        #pragma unroll
        for (int jj = 0; jj < CH; jj++){
            int j = c0 + jj;
            float aj = actIn[(size_t)n*J + j];
            float4 p = poseIn[(size_t)n*J + j];
            int b = (vid*CH + jj)*4;
            atomicAdd(&s_[b+0], aj*p.x);
            atomicAdd(&s_[b+1], aj*p.y);
            atomicAdd(&s_[b+2], aj*p.z);
            atomicAdd(&s_[b+3], aj*p.w);
            atomicAdd(&wsum_[vid*CH + jj], aj);
        }
        if (chunk == 0){
            atomicAdd(&cnt_[vid], 1.0f);
            atomicAdd(&psum_[vid*3+0], posIn[(size_t)n*3+0]);
            atomicAdd(&psum_[vid*3+1], posIn[(size_t)n*3+1]);
            atomicAdd(&psum_[vid*3+2], posIn[(size_t)n*3+2]);
        }
    }
    __syncthreads();

    for (int t = threadIdx.x; t < V*CH*4; t += blockDim.x){
        float val = s_[t];
        if (val != 0.f){
            int v = t / (CH*4), r = t % (CH*4);
            atomicAdd(&s[((size_t)v*J + c0)*4 + r], val);
        }
    }
    for (int t = threadIdx.x; t < V*CH; t += blockDim.x){
        float val = wsum_[t];
        if (val != 0.f){
            int v = t / CH, jj = t % CH;
            atomicAdd(&wsum[(size_t)v*J + c0 + jj], val);
        }
    }
    if (chunk == 0){
        for (int t = threadIdx.x; t < V; t += blockDim.x)
            if (cnt_[t] != 0.f) atomicAdd(&cnt[t], cnt_[t]);
        for (int t = threadIdx.x; t < V*3; t += blockDim.x)
            if (psum_[t] != 0.f) atomicAdd(&psum[t], psum_[t]);
    }
}

template<int V, int J>
__global__ void pool_priv2(const float4* __restrict__ poseIn, const float* __restrict__ actIn,
                           const float* __restrict__ posIn, const float4* __restrict__ m,
                           float* __restrict__ agacc,
                           int N, int G, int mode, const unsigned* __restrict__ mm){
    __shared__ float ag_[V*J];
    for (int t = threadIdx.x; t < V*J; t += blockDim.x) ag_[t] = 0.f;
    __syncthreads();
    float start, size; pool_geom(mm, G, mode, start, size);
    int nslices = gridDim.x;
    int per = (N + nslices - 1) / nslices;
    int n0 = blockIdx.x * per, n1 = min(N, n0 + per);
    for (int n = n0 + (int)threadIdx.x; n < n1; n += blockDim.x){
        int vid = voxel_id(posIn, n, G, start, size);
        #pragma unroll
        for (int j = 0; j < J; j++){
            float4 p  = poseIn[(size_t)n*J + j];
            float4 mv = m[(size_t)vid*J + j];
            float agree = p.x*mv.x + p.y*mv.y + p.z*mv.z + p.w*mv.w;
            atomicAdd(&ag_[vid*J + j], actIn[(size_t)n*J + j]*agree);
        }
    }
    __syncthreads();
    for (int t = threadIdx.x; t < V*J; t += blockDim.x)
        if (ag_[t] != 0.f) atomicAdd(&agacc[t], ag_[t]);
}

// ---------- pools 3-4 (tiny) : single fused LDS kernel ----------
template<int V, int J, int CH>
__global__ void pool_fused_kernel(const float* __restrict__ poseIn, const float* __restrict__ actIn,
                                  const float* __restrict__ posIn,
                                  float* __restrict__ poseOut, float* __restrict__ actOut,
                                  float* __restrict__ posOut,
                                  int N, int G, int mode, const unsigned* __restrict__ mm){
    __shared__ float s_[V*CH*4];
    __shared__ float wsum_[V*CH];
    __shared__ float ag_[V*CH];
    __shared__ float cnt_[V];
    __shared__ float psum_[V*3];
    const int c0 = blockIdx.x * CH;

    for (int t = threadIdx.x; t < V*CH*4; t += blockDim.x) s_[t] = 0.f;
    for (int t = threadIdx.x; t < V*CH; t += blockDim.x){ wsum_[t] = 0.f; ag_[t] = 0.f; }
    if (blockIdx.x == 0){
        for (int t = threadIdx.x; t < V; t += blockDim.x) cnt_[t] = 0.f;
        for (int t = threadIdx.x; t < V*3; t += blockDim.x) psum_[t] = 0.f;
    }
    __syncthreads();

    float start, size; pool_geom(mm, G, mode, start, size);

    for (int n = threadIdx.x; n < N; n += blockDim.x){
        int vid = voxel_id(posIn, n, G, start, size);
        #pragma unroll
        for (int jj = 0; jj < CH; jj++){
            int j = c0 + jj;
            float aj = actIn[(size_t)n*J + j];
            const float* pb = &poseIn[((size_t)n*J + j)*4];
            int b = (vid*CH + jj)*4;
            atomicAdd(&s_[b+0], aj*pb[0]);
            atomicAdd(&s_[b+1], aj*pb[1]);
            atomicAdd(&s_[b+2], aj*pb[2]);
            atomicAdd(&s_[b+3], aj*pb[3]);
            atomicAdd(&wsum_[vid*CH + jj], aj);
        }
        if (blockIdx.x == 0){
            atomicAdd(&cnt_[vid], 1.0f);
            atomicAdd(&psum_[vid*3+0], posIn[(size_t)n*3+0]);
            atomicAdd(&psum_[vid*3+1], posIn[(size_t)n*3+1]);
            atomicAdd(&psum_[vid*3+2], posIn[(size_t)n*3+2]);
        }
    }
    __syncthreads();

    for (int t = threadIdx.x; t < V*CH; t += blockDim.x){
        float a = s_[t*4], b = s_[t*4+1], c = s_[t*4+2], d = s_[t*4+3];
        float inv = 1.0f / (sqrtf(a*a + b*b + c*c + d*d) + EPS);
        s_[t*4] = a*inv; s_[t*4+1] = b*inv; s_[t*4+2] = c*inv; s_[t*4+3] = d*inv;
    }
    __syncthreads();

    for (int n = threadIdx.x; n < N; n += blockDim.x){
        int vid = voxel_id(posIn, n, G, start, size);
        #pragma unroll
        for (int jj = 0; jj < CH; jj++){
            int j = c0 + jj;
            const float* pb = &poseIn[((size_t)n*J + j)*4];
            const float* mb = &s_[(vid*CH + jj)*4];
            float agree = pb[0]*mb[0] + pb[1]*mb[1] + pb[2]*mb[2] + pb[3]*mb[3];
            atomicAdd(&ag_[vid*CH + jj], actIn[(size_t)n*J + j]*agree);
        }
    }
    __syncthreads();

    for (int t = threadIdx.x; t < V*CH; t += blockDim.x){
        int v = t / CH, jj = t % CH;
        size_t o = (size_t)v*J + c0 + jj;
        actOut[o] = sigmoidf_(ag_[t] / (wsum_[t] + EPS));
        poseOut[o*4+0] = s_[t*4+0];
        poseOut[o*4+1] = s_[t*4+1];
        poseOut[o*4+2] = s_[t*4+2];
        poseOut[o*4+3] = s_[t*4+3];
    }
    if (blockIdx.x == 0){
        for (int v = threadIdx.x; v < V; v += blockDim.x){
            float c = cnt_[v] + EPS;
            posOut[(size_t)v*3+0] = psum_[(size_t)v*3+0] / c;
            posOut[(size_t)v*3+1] = psum_[(size_t)v*3+1] / c;
            posOut[(size_t)v*3+2] = psum_[(size_t)v*3+2] / c;
        }
    }
}

extern "C" void kernel_launch(void* const* d_in, const int* in_sizes, int n_in,
                              void* d_out, int out_size, void* d_ws, size_t ws_size,
                              hipStream_t stream){
    const float* x      = (const float*)d_in[0];
    const float* pos    = (const float*)d_in[1];
    const float* pseudo = (const float*)d_in[2];
    const float* Wsp    = (const float*)d_in[3];
    const float* root   = (const float*)d_in[4];
    const float* bias   = (const float*)d_in[5];
    const float* lin_w  = (const float*)d_in[6];
    const float* lin_b  = (const float*)d_in[7];
    const float* q0     = (const float*)d_in[8];
    const float* q1     = (const float*)d_in[9];
    const float* q3     = (const float*)d_in[10];
    const float* q5     = (const float*)d_in[11];
    const float* q6     = (const float*)d_in[12];
    const float* q7     = (const float*)d_in[13];
    const int*   ei     = (const int*)d_in[14];
    const int N = in_sizes[0];
    const int E = in_sizes[2] / 3;

    char* ws = (char*)d_ws;
    size_t off = 0;
    auto alloc = [&](size_t bytes)->void*{
        void* p = ws + off;
        off += (bytes + 255) & ~(size_t)255;
        return p;
    };
    unsigned* mm   = (unsigned*)alloc(8);
    int* ecnt      = (int*)alloc((size_t)N*sizeof(int));
    int* rowptr    = (int*)alloc((size_t)(N+1)*sizeof(int));
    int* cursor    = (int*)alloc((size_t)N*sizeof(int));
    float4* payload= (float4*)alloc((size_t)E*sizeof(float4));
    float* P0  = (float*)alloc((size_t)1250000*sizeof(float));
    float* P1  = (float*)alloc((size_t)1250000*sizeof(float));
    float* A0  = (float*)alloc((size_t)310000*sizeof(float));
    float* A1  = (float*)alloc((size_t)310000*sizeof(float));
    float* PB0 = (float*)alloc((size_t)100000*sizeof(float));
    float* PB1 = (float*)alloc((size_t)100000*sizeof(float));
    float* vs  = (float*)alloc((size_t)800000*sizeof(float));
    float* vw  = (float*)alloc((size_t)200000*sizeof(float));
    float* va  = (float*)alloc((size_t)200000*sizeof(float));
    float* vc  = (float*)alloc((size_t)33000*sizeof(float));
    float* vp  = (float*)alloc((size_t)100000*sizeof(float));

    hipMemsetAsync(mm,     0xFF, 4, stream);
    hipMemsetAsync(mm + 1, 0x00, 4, stream);
    hipMemsetAsync(ecnt, 0, (size_t)N*sizeof(int), stream);

    minmax_kernel<<<80, 256, 0, stream>>>(pos, N*3, mm);

    // CSR build + fused spline gather / node finalize (no float atomics)
    hist_kernel<<<(E + 255)/256, 256, 0, stream>>>(ei, ecnt, E);
    scan_kernel<<<1, 1024, 0, stream>>>(ecnt, rowptr, cursor, N);
    scatter_kernel<<<(E + 255)/256, 256, 0, stream>>>(pseudo, ei, cursor, payload, E);
    spline_node_kernel<<<(N + 255)/256, 256, 0, stream>>>(x, payload, rowptr, Wsp,
                                                          root, bias, lin_w, lin_b, P0, A0, N);

    // capsule layers: all cooperative (spill-free)
    caps_coop_kernel<1,6,32><<<(N + 31)/32, 32*6, 0, stream>>>(P0, A0, q0, P1, A1, N);
    caps_coop_kernel<6,6,7><<<(N + 6)/7, 7*36, 0, stream>>>(P1, A1, q1, P0, A0, N);

    // pool1: 50000 nodes -> 32768 voxels (G=32), J=6 — global-atomic path (low contention)
    {
        const int V = 32768, J = 6, G = 32;
        hipMemsetAsync(vs, 0, (size_t)V*J*4*sizeof(float), stream);
        hipMemsetAsync(vw, 0, (size_t)V*J*sizeof(float),   stream);
        hipMemsetAsync(va, 0, (size_t)V*J*sizeof(float),   stream);
        hipMemsetAsync(vc, 0, (size_t)V*sizeof(float),     stream);
        hipMemsetAsync(vp, 0, (size_t)V*3*sizeof(float),   stream);
        int gN = (N + 255)/256, gV = (V*J + 255)/256;
        pool_scatter1<<<gN, 256, 0, stream>>>(P0, A0, pos, vs, vw, vc, vp, N, J, G, 0, mm);
        pool_m<<<gV, 256, 0, stream>>>(vs, P1, V*J);
        pool_scatter2<<<gN, 256, 0, stream>>>(P0, A0, pos, P1, va, N, J, G, 0, mm);
        pool_fin<<<gV, 256, 0, stream>>>(va, vw, vc, vp, A1, PB0, V, J);
    }
    caps_coop_kernel<6,8,5><<<(32768 + 4)/5, 5*48, 0, stream>>>(P1, A1, q3, P0, A0, 32768);

    // pool2: 32768 -> 512 (G=8), J=8 — multi-block LDS-privatized path
    {
        const int V = 512, J = 8, G = 8, NSL = 16;
        hipMemsetAsync(vs, 0, (size_t)V*J*4*sizeof(float), stream);
        hipMemsetAsync(vw, 0, (size_t)V*J*sizeof(float),   stream);
        hipMemsetAsync(va, 0, (size_t)V*J*sizeof(float),   stream);
        hipMemsetAsync(vc, 0, (size_t)V*sizeof(float),     stream);
        hipMemsetAsync(vp, 0, (size_t)V*3*sizeof(float),   stream);
        pool_priv1<V,J,4,2><<<2*NSL, 256, 0, stream>>>((const float4*)P0, A0, PB0,
                                                       vs, vw, vc, vp, 32768, G, 0, mm);
        pool_m<<<(V*J + 255)/256, 256, 0, stream>>>(vs, P1, V*J);
        pool_priv2<V,J><<<NSL, 256, 0, stream>>>((const float4*)P0, A0, PB0,
                                                 (const float4*)P1, va, 32768, G, 0, mm);
        pool_fin<<<(V*J + 255)/256, 256, 0, stream>>>(va, vw, vc, vp, A1, PB1, V, J);
    }
    caps_coop_kernel<8,12,2><<<256, 2*96, 0, stream>>>(P1, A1, q5, P0, A0, 512);

    // pool3: 512 -> 8 (G=2), J=12 — fused LDS path, 1 block
    pool_fused_kernel<8,12,12><<<1, 1024, 0, stream>>>(P0, A0, PB1, P1, A1, PB0, 512, 2, 0, mm);
    caps_coop_kernel<12,14,1><<<8, 168, 0, stream>>>(P1, A1, q6, P0, A0, 8);

    // pool4: 8 -> 1 (G=1, mode=1), J=14 — fused LDS path, 1 block
    pool_fused_kernel<1,14,14><<<1, 1024, 0, stream>>>(P0, A0, PB0, P1, A1, PB1, 8, 1, 1, mm);
    caps_coop_kernel<14,10,1><<<1, 140, 0, stream>>>(P1, A1, q7, P0, (float*)d_out, 1);
}

// Round 8
// 642.278 us; speedup vs baseline: 8.9030x; 1.1376x over previous
//
#include <hip/hip_runtime.h>
#include <math.h>

#define EPS 1e-4f

__device__ __forceinline__ float sigmoidf_(float x){ return 1.0f/(1.0f+expf(-x)); }

// ---- ordered-uint mapping for float atomic min/max ----
__device__ __forceinline__ unsigned f2u_(float f){
    unsigned u = __float_as_uint(f);
    return (u & 0x80000000u) ? ~u : (u | 0x80000000u);
}
__device__ __forceinline__ float u2f_(unsigned u){
    unsigned b = (u & 0x80000000u) ? (u & 0x7FFFFFFFu) : ~u;
    return __uint_as_float(b);
}

// ================= min/max of pos =================
__global__ void minmax_kernel(const float* __restrict__ p, int n, unsigned* mm){
    float lo = INFINITY, hi = -INFINITY;
    for (int i = blockIdx.x*blockDim.x + threadIdx.x; i < n; i += gridDim.x*blockDim.x){
        float v = p[i]; lo = fminf(lo, v); hi = fmaxf(hi, v);
    }
    for (int off = 32; off > 0; off >>= 1){
        lo = fminf(lo, __shfl_down(lo, off));
        hi = fmaxf(hi, __shfl_down(hi, off));
    }
    __shared__ float slo[8], shi[8];
    int wid = threadIdx.x >> 6;
    if ((threadIdx.x & 63) == 0){ slo[wid] = lo; shi[wid] = hi; }
    __syncthreads();
    if (threadIdx.x == 0){
        int nw = blockDim.x >> 6;
        for (int w = 1; w < nw; w++){ lo = fminf(lo, slo[w]); hi = fmaxf(hi, shi[w]); }
        atomicMin(&mm[0], f2u_(lo));
        atomicMax(&mm[1], f2u_(hi));
    }
}

// ================= CSR build for spline conv =================
__global__ void hist_kernel(const int* __restrict__ ei, int* __restrict__ cnt, int E){
    int e = blockIdx.x*blockDim.x + threadIdx.x;
    if (e < E) atomicAdd(&cnt[ei[E + e]], 1);
}

// single block, tile-wise parallel exclusive scan (R7's version spent ~50us in a
// serial 1024-iter thread-0 loop + ~70us of uncoalesced per-thread-chunk reads).
__global__ void scan_kernel(const int* __restrict__ cnt, int* __restrict__ rowptr,
                            int* __restrict__ cursor, int N){
    __shared__ int wsum[16];
    __shared__ int woff[17];
    const int T = blockDim.x;            // 1024 = 16 waves
    int t = threadIdx.x;
    int lane = t & 63, wid = t >> 6;
    int carry = 0;
    int ntiles = (N + T - 1) / T;
    for (int tile = 0; tile < ntiles; tile++){
        int idx = tile*T + t;
        int v = (idx < N) ? cnt[idx] : 0;    // coalesced
        int inc = v;
        #pragma unroll
        for (int off = 1; off < 64; off <<= 1){
            int u = __shfl_up(inc, off);
            if (lane >= off) inc += u;
        }
        if (lane == 63) wsum[wid] = inc;
        __syncthreads();
        if (t == 0){
            int acc = 0;
            #pragma unroll
            for (int w = 0; w < 16; w++){ woff[w] = acc; acc += wsum[w]; }
            woff[16] = acc;
        }
        __syncthreads();
        int excl = carry + woff[wid] + inc - v;
        if (idx < N){ rowptr[idx] = excl; cursor[idx] = excl; }
        carry += woff[16];
        __syncthreads();   // wsum reused next tile
    }
    if (t == 0) rowptr[N] = carry;
}

__global__ void scatter_kernel(const float* __restrict__ pseudo, const int* __restrict__ ei,
                               int* __restrict__ cursor, float4* __restrict__ payload, int E){
    int e = blockIdx.x*blockDim.x + threadIdx.x;
    if (e >= E) return;
    int d = ei[E + e];
    int slot = atomicAdd(&cursor[d], 1);
    payload[slot] = make_float4(pseudo[3*e], pseudo[3*e+1], pseudo[3*e+2],
                                __int_as_float(ei[e]));
}

// ================= fused spline gather + node finalize =================
__global__ void spline_node_kernel(const float* __restrict__ x, const float4* __restrict__ payload,
                                   const int* __restrict__ rowptr, const float* __restrict__ W,
                                   const float* __restrict__ root, const float* __restrict__ bias,
                                   const float* __restrict__ lin_w, const float* __restrict__ lin_b,
                                   float* __restrict__ pose, float* __restrict__ act, int N){
    __shared__ float Ws[125*17];
    for (int i = threadIdx.x; i < 125*16; i += blockDim.x)
        Ws[(i >> 4)*17 + (i & 15)] = W[i];
    __syncthreads();
    int n = blockIdx.x*blockDim.x + threadIdx.x;
    if (n >= N) return;

    float agg[16];
    #pragma unroll
    for (int o = 0; o < 16; o++) agg[o] = 0.f;

    int r0 = rowptr[n], r1 = rowptr[n+1];
    for (int s = r0; s < r1; s++){
        float4 pl = payload[s];
        int src = __float_as_int(pl.w);
        float xv = x[src];
        float v0 = pl.x*4.f, v1 = pl.y*4.f, v2 = pl.z*4.f;
        float f0 = fminf(fmaxf(floorf(v0), 0.f), 3.f);
        float f1 = fminf(fmaxf(floorf(v1), 0.f), 3.f);
        float f2 = fminf(fmaxf(floorf(v2), 0.f), 3.f);
        float fr0 = v0 - f0, fr1 = v1 - f1, fr2 = v2 - f2;
        int i0 = (int)f0, i1 = (int)f1, i2 = (int)f2;
        #pragma unroll
        for (int b = 0; b < 8; b++){
            int b0 = (b >> 2) & 1, b1 = (b >> 1) & 1, b2 = b & 1;
            float w = (b0 ? fr0 : 1.f - fr0) * (b1 ? fr1 : 1.f - fr1) * (b2 ? fr2 : 1.f - fr2);
            w *= xv;
            int k = ((i0 + b0)*5 + (i1 + b1))*5 + (i2 + b2);
            const float* Wr = &Ws[k*17];
            #pragma unroll
            for (int o = 0; o < 16; o++) agg[o] += w * Wr[o];
        }
    }

    float deg = fmaxf((float)(r1 - r0), 1.0f);
    float xs = x[n];
    float qv0 = lin_b[0], qv1 = lin_b[1], qv2 = lin_b[2], qv3 = lin_b[3];
    #pragma unroll
    for (int o = 0; o < 16; o++){
        float h = agg[o] / deg + xs * root[o] + bias[o];
        float e = (h > 0.f) ? h : expm1f(h);
        qv0 += e * lin_w[o*4 + 0];
        qv1 += e * lin_w[o*4 + 1];
        qv2 += e * lin_w[o*4 + 2];
        qv3 += e * lin_w[o*4 + 3];
    }
    float inv = 1.0f / (sqrtf(qv0*qv0 + qv1*qv1 + qv2*qv2 + qv3*qv3) + EPS);
    pose[(size_t)n*4 + 0] = qv0*inv;
    pose[(size_t)n*4 + 1] = qv1*inv;
    pose[(size_t)n*4 + 2] = qv2*inv;
    pose[(size_t)n*4 + 3] = qv3*inv;
    act[n] = xs;
}

// ====== capsule routing — cooperative, NPB nodes per block ======
template<int I, int J, int NPB>
__global__ __launch_bounds__(NPB*I*J)
void caps_coop_kernel(const float* __restrict__ poseIn, const float* __restrict__ actIn,
                      const float* __restrict__ q, float* __restrict__ poseOut,
                      float* __restrict__ actOut, int N){
    const int IJ = I*J;
    const int tid = threadIdx.x;
    const int nl  = tid / IJ;
    const int li  = tid - nl*IJ;
    const int i   = li / J;
    const int j   = li - i*J;
    const int node = blockIdx.x*NPB + nl;
    const bool on = (node < N);

    __shared__ float redA[NPB][I*J];
    __shared__ float redB[NPB][I*J];
    __shared__ float cp[NPB][I*J*4];
    __shared__ float vsh[NPB][J*4];

    float prx=0.f, pry=0.f, prz=0.f, prw=0.f, ai=0.f;
    if (on){
        float qx = q[li*4+0], qy = q[li*4+1], qz = q[li*4+2], qw = q[li*4+3];
        float qinv = 1.0f/(sqrtf(qx*qx+qy*qy+qz*qz+qw*qw)+EPS);
        qx*=qinv; qy*=qinv; qz*=qinv; qw*=qinv;
        const float* pp = &poseIn[((size_t)node*I + i)*4];
        float rx=pp[0], ry=pp[1], rz=pp[2], rw=pp[3];
        ai = actIn[(size_t)node*I + i];
        float tx = qw*rx + qx*rw + qy*rz - qz*ry;
        float ty = qw*ry - qx*rz + qy*rw + qz*rx;
        float tz = qw*rz + qx*ry - qy*rx + qz*rw;
        float tw = qw*rw - qx*rx - qy*ry - qz*rz;
        float pinv = 1.0f/(sqrtf(tx*tx+ty*ty+tz*tz+tw*tw)+EPS);
        prx=tx*pinv; pry=ty*pinv; prz=tz*pinv; prw=tw*pinv;
    }

    float b = 0.f, c = 0.f;
    for (int t = 0; t < 3; t++){
        redA[nl][li] = b;
        __syncthreads();
        float mb = -INFINITY;
        #pragma unroll
        for (int jj = 0; jj < J; jj++) mb = fmaxf(mb, redA[nl][i*J+jj]);
        float e = expf(b - mb);
        redB[nl][li] = e;
        __syncthreads();
        float s = 0.f;
        #pragma unroll
        for (int jj = 0; jj < J; jj++) s += redB[nl][i*J+jj];
        c = ai * e / s;
        cp[nl][li*4+0] = c*prx; cp[nl][li*4+1] = c*pry;
        cp[nl][li*4+2] = c*prz; cp[nl][li*4+3] = c*prw;
        __syncthreads();
        // sum over i: J*4 entries, strided by the I*J threads of this node slot
        for (int idx = li; idx < J*4; idx += IJ){
            int jj = idx >> 2, comp = idx & 3;
            float acc = 0.f;
            #pragma unroll
            for (int ii = 0; ii < I; ii++) acc += cp[nl][(ii*J+jj)*4+comp];
            vsh[nl][idx] = acc;
        }
        __syncthreads();
        if (li < J){
            float a0=vsh[nl][li*4], a1=vsh[nl][li*4+1], a2=vsh[nl][li*4+2], a3=vsh[nl][li*4+3];
            float inv = 1.0f/(sqrtf(a0*a0+a1*a1+a2*a2+a3*a3)+EPS);
            vsh[nl][li*4]=a0*inv; vsh[nl][li*4+1]=a1*inv;
            vsh[nl][li*4+2]=a2*inv; vsh[nl][li*4+3]=a3*inv;
        }
        __syncthreads();
        if (t < 2){
            b += prx*vsh[nl][j*4] + pry*vsh[nl][j*4+1] + prz*vsh[nl][j*4+2] + prw*vsh[nl][j*4+3];
            __syncthreads();
        } else {
            redA[nl][li] = c*(prx*vsh[nl][j*4] + pry*vsh[nl][j*4+1]
                            + prz*vsh[nl][j*4+2] + prw*vsh[nl][j*4+3]);
            __syncthreads();
            if (li < J && on){
                float acc = 0.f;
                #pragma unroll
                for (int ii = 0; ii < I; ii++) acc += redA[nl][ii*J+li];
                actOut[(size_t)node*J + li] = sigmoidf_(acc);
                poseOut[((size_t)node*J+li)*4+0] = vsh[nl][li*4+0];
                poseOut[((size_t)node*J+li)*4+1] = vsh[nl][li*4+1];
                poseOut[((size_t)node*J+li)*4+2] = vsh[nl][li*4+2];
                poseOut[((size_t)node*J+li)*4+3] = vsh[nl][li*4+3];
            }
        }
    }
}

// ================= pooling (shared helpers) =================
__device__ __forceinline__ int voxel_id(const float* __restrict__ pos, int n, int G,
                                        float start, float size){
    int g[3];
    #pragma unroll
    for (int k = 0; k < 3; k++){
        float gg = floorf((pos[(size_t)n*3 + k] - start) / size);
        gg = fminf(fmaxf(gg, 0.f), (float)(G - 1));
        g[k] = (int)gg;
    }
    return (g[0]*G + g[1])*G + g[2];
}

__device__ __forceinline__ void pool_geom(const unsigned* mm, int G, int mode,
                                          float& start, float& size){
    float mn = u2f_(mm[0]), mx = u2f_(mm[1]);
    if (mode == 0){ start = mn; size = (mx + 0.001f - mn) / (float)G; }
    else          { start = mn - 0.5f; size = mx - mn + 1.0f; }
}

// ---------- pool1 (large V) : global-atomic path ----------
__global__ void pool_scatter1(const float* __restrict__ pose, const float* __restrict__ act,
                              const float* __restrict__ pos,
                              float* __restrict__ s, float* __restrict__ wsum,
                              float* __restrict__ cnt, float* __restrict__ psum,
                              int N, int J, int G, int mode, const unsigned* __restrict__ mm){
    int n = blockIdx.x*blockDim.x + threadIdx.x;
    if (n >= N) return;
    float start, size; pool_geom(mm, G, mode, start, size);
    int vid = voxel_id(pos, n, G, start, size);
    for (int j = 0; j < J; j++){
        float aj = act[(size_t)n*J + j];
        size_t pb = ((size_t)n*J + j)*4;
        size_t sb = ((size_t)vid*J + j)*4;
        atomicAdd(&s[sb],   aj*pose[pb]);
        atomicAdd(&s[sb+1], aj*pose[pb+1]);
        atomicAdd(&s[sb+2], aj*pose[pb+2]);
        atomicAdd(&s[sb+3], aj*pose[pb+3]);
        atomicAdd(&wsum[(size_t)vid*J + j], aj);
    }
    atomicAdd(&cnt[vid], 1.0f);
    atomicAdd(&psum[(size_t)vid*3 + 0], pos[(size_t)n*3 + 0]);
    atomicAdd(&psum[(size_t)vid*3 + 1], pos[(size_t)n*3 + 1]);
    atomicAdd(&psum[(size_t)vid*3 + 2], pos[(size_t)n*3 + 2]);
}

__global__ void pool_m(const float* __restrict__ s, float* __restrict__ m, int VJ){
    int t = blockIdx.x*blockDim.x + threadIdx.x;
    if (t >= VJ) return;
    float a = s[(size_t)t*4], b = s[(size_t)t*4+1], c = s[(size_t)t*4+2], d = s[(size_t)t*4+3];
    float inv = 1.0f / (sqrtf(a*a + b*b + c*c + d*d) + EPS);
    m[(size_t)t*4]   = a*inv;
    m[(size_t)t*4+1] = b*inv;
    m[(size_t)t*4+2] = c*inv;
    m[(size_t)t*4+3] = d*inv;
}

__global__ void pool_scatter2(const float* __restrict__ pose, const float* __restrict__ act,
                              const float* __restrict__ pos, const float* __restrict__ m,
                              float* __restrict__ agacc,
                              int N, int J, int G, int mode, const unsigned* __restrict__ mm){
    int n = blockIdx.x*blockDim.x + threadIdx.x;
    if (n >= N) return;
    float start, size; pool_geom(mm, G, mode, start, size);
    int vid = voxel_id(pos, n, G, start, size);
    for (int j = 0; j < J; j++){
        size_t pb = ((size_t)n*J + j)*4;
        size_t mb = ((size_t)vid*J + j)*4;
        float agree = pose[pb]*m[mb] + pose[pb+1]*m[mb+1] + pose[pb+2]*m[mb+2] + pose[pb+3]*m[mb+3];
        atomicAdd(&agacc[(size_t)vid*J + j], act[(size_t)n*J + j]*agree);
    }
}

__global__ void pool_fin(const float* __restrict__ agacc, const float* __restrict__ wsum,
                         const float* __restrict__ cnt, const float* __restrict__ psum,
                         float* __restrict__ actOut, float* __restrict__ posOut, int V, int J){
    int t = blockIdx.x*blockDim.x + threadIdx.x;
    if (t >= V*J) return;
    int v = t / J, j = t % J;
    actOut[t] = sigmoidf_(agacc[t] / (wsum[t] + EPS));
    if (j == 0){
        float c = cnt[v] + EPS;
        posOut[(size_t)v*3 + 0] = psum[(size_t)v*3 + 0] / c;
        posOut[(size_t)v*3 + 1] = psum[(size_t)v*3 + 1] / c;
        posOut[(size_t)v*3 + 2] = psum[(size_t)v*3 + 2] / c;
    }
}

// ---------- pool2 (mid V) : multi-block LDS-privatized, global-atomic merge ----------
template<int V, int J, int CH, int NCHUNK>
__global__ void pool_priv1(const float4* __restrict__ poseIn, const float* __restrict__ actIn,
                           const float* __restrict__ posIn,
                           float* __restrict__ s, float* __restrict__ wsum,
                           float* __restrict__ cnt, float* __restrict__ psum,
                           int N, int G, int mode, const unsigned* __restrict__ mm){
    __shared__ float s_[V*CH*4];
    __shared__ float wsum_[V*CH];
    __shared__ float cnt_[V];
    __shared__ float psum_[V*3];
    const int chunk = blockIdx.x % NCHUNK;
    const int slice = blockIdx.x / NCHUNK;
    const int nslices = gridDim.x / NCHUNK;
    const int c0 = chunk * CH;

    for (int t = threadIdx.x; t < V*CH*4; t += blockDim.x) s_[t] = 0.f;
    for (int t = threadIdx.x; t < V*CH; t += blockDim.x) wsum_[t] = 0.f;
    if (chunk == 0){
        for (int t = threadIdx.x; t < V; t += blockDim.x) cnt_[t] = 0.f;
        for (int t = threadIdx.x; t < V*3; t += blockDim.x) psum_[t] = 0.f;
    }
    __syncthreads();

    float start, size; pool_geom(mm, G, mode, start, size);
    int per = (N + nslices - 1) / nslices;
    int n0 = slice * per, n1 = min(N, n0 + per);

    for (int n = n0 + (int)threadIdx.x; n < n1; n += blockDim.x){
        int vid = voxel_id(posIn, n, G, start, size);
        #pragma unroll
        for (int jj = 0; jj < CH; jj++){
            int j = c0 + jj;
            float aj = actIn[(size_t)n*J + j];
            float4 p = poseIn[(size_t)n*J + j];
            int b = (vid*CH + jj)*4;
            atomicAdd(&s_[b+0], aj*p.x);
            atomicAdd(&s_[b+1], aj*p.y);
            atomicAdd(&s_[b+2], aj*p.z);
            atomicAdd(&s_[b+3], aj*p.w);
            atomicAdd(&wsum_[vid*CH + jj], aj);
        }
        if (chunk == 0){
            atomicAdd(&cnt_[vid], 1.0f);
            atomicAdd(&psum_[vid*3+0], posIn[(size_t)n*3+0]);
            atomicAdd(&psum_[vid*3+1], posIn[(size_t)n*3+1]);
            atomicAdd(&psum_[vid*3+2], posIn[(size_t)n*3+2]);
        }
    }
    __syncthreads();

    for (int t = threadIdx.x; t < V*CH*4; t += blockDim.x){
        float val = s_[t];
        if (val != 0.f){
            int v = t / (CH*4), r = t % (CH*4);
            atomicAdd(&s[((size_t)v*J + c0)*4 + r], val);
        }
    }
    for (int t = threadIdx.x; t < V*CH; t += blockDim.x){
        float val = wsum_[t];
        if (val != 0.f){
            int v = t / CH, jj = t % CH;
            atomicAdd(&wsum[(size_t)v*J + c0 + jj], val);
        }
    }
    if (chunk == 0){
        for (int t = threadIdx.x; t < V; t += blockDim.x)
            if (cnt_[t] != 0.f) atomicAdd(&cnt[t], cnt_[t]);
        for (int t = threadIdx.x; t < V*3; t += blockDim.x)
            if (psum_[t] != 0.f) atomicAdd(&psum[t], psum_[t]);
    }
}

template<int V, int J>
__global__ void pool_priv2(const float4* __restrict__ poseIn, const float* __restrict__ actIn,
                           const float* __restrict__ posIn, const float4* __restrict__ m,
                           float* __restrict__ agacc,
                           int N, int G, int mode, const unsigned* __restrict__ mm){
    __shared__ float ag_[V*J];
    for (int t = threadIdx.x; t < V*J; t += blockDim.x) ag_[t] = 0.f;
    __syncthreads();
    float start, size; pool_geom(mm, G, mode, start, size);
    int nslices = gridDim.x;
    int per = (N + nslices - 1) / nslices;
    int n0 = blockIdx.x * per, n1 = min(N, n0 + per);
    for (int n = n0 + (int)threadIdx.x; n < n1; n += blockDim.x){
        int vid = voxel_id(posIn, n, G, start, size);
        #pragma unroll
        for (int j = 0; j < J; j++){
            float4 p  = poseIn[(size_t)n*J + j];
            float4 mv = m[(size_t)vid*J + j];
            float agree = p.x*mv.x + p.y*mv.y + p.z*mv.z + p.w*mv.w;
            atomicAdd(&ag_[vid*J + j], actIn[(size_t)n*J + j]*agree);
        }
    }
    __syncthreads();
    for (int t = threadIdx.x; t < V*J; t += blockDim.x)
        if (ag_[t] != 0.f) atomicAdd(&agacc[t], ag_[t]);
}

// ---------- pools 3-4 (tiny) : single fused LDS kernel ----------
template<int V, int J, int CH>
__global__ void pool_fused_kernel(const float* __restrict__ poseIn, const float* __restrict__ actIn,
                                  const float* __restrict__ posIn,
                                  float* __restrict__ poseOut, float* __restrict__ actOut,
                                  float* __restrict__ posOut,
                                  int N, int G, int mode, const unsigned* __restrict__ mm){
    __shared__ float s_[V*CH*4];
    __shared__ float wsum_[V*CH];
    __shared__ float ag_[V*CH];
    __shared__ float cnt_[V];
    __shared__ float psum_[V*3];
    const int c0 = blockIdx.x * CH;

    for (int t = threadIdx.x; t < V*CH*4; t += blockDim.x) s_[t] = 0.f;
    for (int t = threadIdx.x; t < V*CH; t += blockDim.x){ wsum_[t] = 0.f; ag_[t] = 0.f; }
    if (blockIdx.x == 0){
        for (int t = threadIdx.x; t < V; t += blockDim.x) cnt_[t] = 0.f;
        for (int t = threadIdx.x; t < V*3; t += blockDim.x) psum_[t] = 0.f;
    }
    __syncthreads();

    float start, size; pool_geom(mm, G, mode, start, size);

    for (int n = threadIdx.x; n < N; n += blockDim.x){
        int vid = voxel_id(posIn, n, G, start, size);
        #pragma unroll
        for (int jj = 0; jj < CH; jj++){
            int j = c0 + jj;
            float aj = actIn[(size_t)n*J + j];
            const float* pb = &poseIn[((size_t)n*J + j)*4];
            int b = (vid*CH + jj)*4;
            atomicAdd(&s_[b+0], aj*pb[0]);
            atomicAdd(&s_[b+1], aj*pb[1]);
            atomicAdd(&s_[b+2], aj*pb[2]);
            atomicAdd(&s_[b+3], aj*pb[3]);
            atomicAdd(&wsum_[vid*CH + jj], aj);
        }
        if (blockIdx.x == 0){
            atomicAdd(&cnt_[vid], 1.0f);
            atomicAdd(&psum_[vid*3+0], posIn[(size_t)n*3+0]);
            atomicAdd(&psum_[vid*3+1], posIn[(size_t)n*3+1]);
            atomicAdd(&psum_[vid*3+2], posIn[(size_t)n*3+2]);
        }
    }
    __syncthreads();

    for (int t = threadIdx.x; t < V*CH; t += blockDim.x){
        float a = s_[t*4], b = s_[t*4+1], c = s_[t*4+2], d = s_[t*4+3];
        float inv = 1.0f / (sqrtf(a*a + b*b + c*c + d*d) + EPS);
        s_[t*4] = a*inv; s_[t*4+1] = b*inv; s_[t*4+2] = c*inv; s_[t*4+3] = d*inv;
    }
    __syncthreads();

    for (int n = threadIdx.x; n < N; n += blockDim.x){
        int vid = voxel_id(posIn, n, G, start, size);
        #pragma unroll
        for (int jj = 0; jj < CH; jj++){
            int j = c0 + jj;
            const float* pb = &poseIn[((size_t)n*J + j)*4];
            const float* mb = &s_[(vid*CH + jj)*4];
            float agree = pb[0]*mb[0] + pb[1]*mb[1] + pb[2]*mb[2] + pb[3]*mb[3];
            atomicAdd(&ag_[vid*CH + jj], actIn[(size_t)n*J + j]*agree);
        }
    }
    __syncthreads();

    for (int t = threadIdx.x; t < V*CH; t += blockDim.x){
        int v = t / CH, jj = t % CH;
        size_t o = (size_t)v*J + c0 + jj;
        actOut[o] = sigmoidf_(ag_[t] / (wsum_[t] + EPS));
        poseOut[o*4+0] = s_[t*4+0];
        poseOut[o*4+1] = s_[t*4+1];
        poseOut[o*4+2] = s_[t*4+2];
        poseOut[o*4+3] = s_[t*4+3];
    }
    if (blockIdx.x == 0){
        for (int v = threadIdx.x; v < V; v += blockDim.x){
            float c = cnt_[v] + EPS;
            posOut[(size_t)v*3+0] = psum_[(size_t)v*3+0] / c;
            posOut[(size_t)v*3+1] = psum_[(size_t)v*3+1] / c;
            posOut[(size_t)v*3+2] = psum_[(size_t)v*3+2] / c;
        }
    }
}

extern "C" void kernel_launch(void* const* d_in, const int* in_sizes, int n_in,
                              void* d_out, int out_size, void* d_ws, size_t ws_size,
                              hipStream_t stream){
    const float* x      = (const float*)d_in[0];
    const float* pos    = (const float*)d_in[1];
    const float* pseudo = (const float*)d_in[2];
    const float* Wsp    = (const float*)d_in[3];
    const float* root   = (const float*)d_in[4];
    const float* bias   = (const float*)d_in[5];
    const float* lin_w  = (const float*)d_in[6];
    const float* lin_b  = (const float*)d_in[7];
    const float* q0     = (const float*)d_in[8];
    const float* q1     = (const float*)d_in[9];
    const float* q3     = (const float*)d_in[10];
    const float* q5     = (const float*)d_in[11];
    const float* q6     = (const float*)d_in[12];
    const float* q7     = (const float*)d_in[13];
    const int*   ei     = (const int*)d_in[14];
    const int N = in_sizes[0];
    const int E = in_sizes[2] / 3;

    char* ws = (char*)d_ws;
    size_t off = 0;
    auto alloc = [&](size_t bytes)->void*{
        void* p = ws + off;
        off += (bytes + 255) & ~(size_t)255;
        return p;
    };
    unsigned* mm   = (unsigned*)alloc(8);
    int* ecnt      = (int*)alloc((size_t)N*sizeof(int));
    int* rowptr    = (int*)alloc((size_t)(N+1)*sizeof(int));
    int* cursor    = (int*)alloc((size_t)N*sizeof(int));
    float4* payload= (float4*)alloc((size_t)E*sizeof(float4));
    float* P0  = (float*)alloc((size_t)1250000*sizeof(float));
    float* P1  = (float*)alloc((size_t)1250000*sizeof(float));
    float* A0  = (float*)alloc((size_t)310000*sizeof(float));
    float* A1  = (float*)alloc((size_t)310000*sizeof(float));
    float* PB0 = (float*)alloc((size_t)100000*sizeof(float));
    float* PB1 = (float*)alloc((size_t)100000*sizeof(float));
    size_t pool_off0 = off;                     // pool scratch region start
    float* vs  = (float*)alloc((size_t)800000*sizeof(float));
    float* vw  = (float*)alloc((size_t)200000*sizeof(float));
    float* va  = (float*)alloc((size_t)200000*sizeof(float));
    float* vc  = (float*)alloc((size_t)33000*sizeof(float));
    float* vp  = (float*)alloc((size_t)100000*sizeof(float));
    size_t pool_bytes = off - pool_off0;        // one memset covers vs..vp

    hipMemsetAsync(mm,     0xFF, 4, stream);
    hipMemsetAsync(mm + 1, 0x00, 4, stream);
    hipMemsetAsync(ecnt, 0, (size_t)N*sizeof(int), stream);

    minmax_kernel<<<80, 256, 0, stream>>>(pos, N*3, mm);

    // CSR build + fused spline gather / node finalize (no float atomics)
    hist_kernel<<<(E + 255)/256, 256, 0, stream>>>(ei, ecnt, E);
    scan_kernel<<<1, 1024, 0, stream>>>(ecnt, rowptr, cursor, N);
    scatter_kernel<<<(E + 255)/256, 256, 0, stream>>>(pseudo, ei, cursor, payload, E);
    spline_node_kernel<<<(N + 255)/256, 256, 0, stream>>>(x, payload, rowptr, Wsp,
                                                          root, bias, lin_w, lin_b, P0, A0, N);

    // capsule layers: all cooperative (spill-free)
    caps_coop_kernel<1,6,32><<<(N + 31)/32, 32*6, 0, stream>>>(P0, A0, q0, P1, A1, N);
    caps_coop_kernel<6,6,7><<<(N + 6)/7, 7*36, 0, stream>>>(P1, A1, q1, P0, A0, N);

    // pool1: 50000 nodes -> 32768 voxels (G=32), J=6 — global-atomic path (low contention)
    {
        const int V = 32768, J = 6, G = 32;
        hipMemsetAsync(vs, 0, pool_bytes, stream);   // vs..vp in one shot
        int gN = (N + 255)/256, gV = (V*J + 255)/256;
        pool_scatter1<<<gN, 256, 0, stream>>>(P0, A0, pos, vs, vw, vc, vp, N, J, G, 0, mm);
        pool_m<<<gV, 256, 0, stream>>>(vs, P1, V*J);
        pool_scatter2<<<gN, 256, 0, stream>>>(P0, A0, pos, P1, va, N, J, G, 0, mm);
        pool_fin<<<gV, 256, 0, stream>>>(va, vw, vc, vp, A1, PB0, V, J);
    }
    caps_coop_kernel<6,8,5><<<(32768 + 4)/5, 5*48, 0, stream>>>(P1, A1, q3, P0, A0, 32768);

    // pool2: 32768 -> 512 (G=8), J=8 — multi-block LDS-privatized path
    {
        const int V = 512, J = 8, G = 8, NSL = 16;
        hipMemsetAsync(vs, 0, pool_bytes, stream);
        pool_priv1<V,J,4,2><<<2*NSL, 256, 0, stream>>>((const float4*)P0, A0, PB0,
                                                       vs, vw, vc, vp, 32768, G, 0, mm);
        pool_m<<<(V*J + 255)/256, 256, 0, stream>>>(vs, P1, V*J);
        pool_priv2<V,J><<<NSL, 256, 0, stream>>>((const float4*)P0, A0, PB0,
                                                 (const float4*)P1, va, 32768, G, 0, mm);
        pool_fin<<<(V*J + 255)/256, 256, 0, stream>>>(va, vw, vc, vp, A1, PB1, V, J);
    }
    caps_coop_kernel<8,12,2><<<256, 2*96, 0, stream>>>(P1, A1, q5, P0, A0, 512);

    // pool3: 512 -> 8 (G=2), J=12 — fused LDS path, 1 block
    pool_fused_kernel<8,12,12><<<1, 1024, 0, stream>>>(P0, A0, PB1, P1, A1, PB0, 512, 2, 0, mm);
    caps_coop_kernel<12,14,1><<<8, 168, 0, stream>>>(P1, A1, q6, P0, A0, 8);

    // pool4: 8 -> 1 (G=1, mode=1), J=14 — fused LDS path, 1 block
    pool_fused_kernel<1,14,14><<<1, 1024, 0, stream>>>(P0, A0, PB0, P1, A1, PB1, 8, 1, 1, mm);
    caps_coop_kernel<14,10,1><<<1, 140, 0, stream>>>(P1, A1, q7, P0, (float*)d_out, 1);
}

// Round 9
// 577.346 us; speedup vs baseline: 9.9042x; 1.1125x over previous
//
#include <hip/hip_runtime.h>
#include <math.h>

#define EPS 1e-4f

__device__ __forceinline__ float sigmoidf_(float x){ return 1.0f/(1.0f+expf(-x)); }

// ---- ordered-uint mapping for float atomic min/max ----
__device__ __forceinline__ unsigned f2u_(float f){
    unsigned u = __float_as_uint(f);
    return (u & 0x80000000u) ? ~u : (u | 0x80000000u);
}
__device__ __forceinline__ float u2f_(unsigned u){
    unsigned b = (u & 0x80000000u) ? (u & 0x7FFFFFFFu) : ~u;
    return __uint_as_float(b);
}

// ================= min/max of pos =================
__global__ void minmax_kernel(const float* __restrict__ p, int n, unsigned* mm){
    float lo = INFINITY, hi = -INFINITY;
    for (int i = blockIdx.x*blockDim.x + threadIdx.x; i < n; i += gridDim.x*blockDim.x){
        float v = p[i]; lo = fminf(lo, v); hi = fmaxf(hi, v);
    }
    for (int off = 32; off > 0; off >>= 1){
        lo = fminf(lo, __shfl_down(lo, off));
        hi = fmaxf(hi, __shfl_down(hi, off));
    }
    __shared__ float slo[8], shi[8];
    int wid = threadIdx.x >> 6;
    if ((threadIdx.x & 63) == 0){ slo[wid] = lo; shi[wid] = hi; }
    __syncthreads();
    if (threadIdx.x == 0){
        int nw = blockDim.x >> 6;
        for (int w = 1; w < nw; w++){ lo = fminf(lo, slo[w]); hi = fmaxf(hi, shi[w]); }
        atomicMin(&mm[0], f2u_(lo));
        atomicMax(&mm[1], f2u_(hi));
    }
}

// ================= generic tile-wise parallel exclusive scan (1 block) ========
__global__ void scan_kernel(const int* __restrict__ cnt, int* __restrict__ rowptr,
                            int* __restrict__ cursor, int N){
    __shared__ int wsum[16];
    __shared__ int woff[17];
    const int T = blockDim.x;            // 1024 = 16 waves
    int t = threadIdx.x;
    int lane = t & 63, wid = t >> 6;
    int carry = 0;
    int ntiles = (N + T - 1) / T;
    for (int tile = 0; tile < ntiles; tile++){
        int idx = tile*T + t;
        int v = (idx < N) ? cnt[idx] : 0;    // coalesced
        int inc = v;
        #pragma unroll
        for (int off = 1; off < 64; off <<= 1){
            int u = __shfl_up(inc, off);
            if (lane >= off) inc += u;
        }
        if (lane == 63) wsum[wid] = inc;
        __syncthreads();
        if (t == 0){
            int acc = 0;
            #pragma unroll
            for (int w = 0; w < 16; w++){ woff[w] = acc; acc += wsum[w]; }
            woff[16] = acc;
        }
        __syncthreads();
        int excl = carry + woff[wid] + inc - v;
        if (idx < N){ rowptr[idx] = excl; cursor[idx] = excl; }
        carry += woff[16];
        __syncthreads();
    }
    if (t == 0) rowptr[N] = carry;
}

// ================= CSR build for spline conv =================
__global__ void hist_kernel(const int* __restrict__ ei, int* __restrict__ cnt, int E){
    int e = blockIdx.x*blockDim.x + threadIdx.x;
    if (e < E) atomicAdd(&cnt[ei[E + e]], 1);
}

__global__ void scatter_kernel(const float* __restrict__ pseudo, const int* __restrict__ ei,
                               int* __restrict__ cursor, float4* __restrict__ payload, int E){
    int e = blockIdx.x*blockDim.x + threadIdx.x;
    if (e >= E) return;
    int d = ei[E + e];
    int slot = atomicAdd(&cursor[d], 1);
    payload[slot] = make_float4(pseudo[3*e], pseudo[3*e+1], pseudo[3*e+2],
                                __int_as_float(ei[e]));
}

// ================= fused spline gather + node finalize =================
__global__ void spline_node_kernel(const float* __restrict__ x, const float4* __restrict__ payload,
                                   const int* __restrict__ rowptr, const float* __restrict__ W,
                                   const float* __restrict__ root, const float* __restrict__ bias,
                                   const float* __restrict__ lin_w, const float* __restrict__ lin_b,
                                   float* __restrict__ pose, float* __restrict__ act, int N){
    __shared__ float Ws[125*17];
    for (int i = threadIdx.x; i < 125*16; i += blockDim.x)
        Ws[(i >> 4)*17 + (i & 15)] = W[i];
    __syncthreads();
    int n = blockIdx.x*blockDim.x + threadIdx.x;
    if (n >= N) return;

    float agg[16];
    #pragma unroll
    for (int o = 0; o < 16; o++) agg[o] = 0.f;

    int r0 = rowptr[n], r1 = rowptr[n+1];
    for (int s = r0; s < r1; s++){
        float4 pl = payload[s];
        int src = __float_as_int(pl.w);
        float xv = x[src];
        float v0 = pl.x*4.f, v1 = pl.y*4.f, v2 = pl.z*4.f;
        float f0 = fminf(fmaxf(floorf(v0), 0.f), 3.f);
        float f1 = fminf(fmaxf(floorf(v1), 0.f), 3.f);
        float f2 = fminf(fmaxf(floorf(v2), 0.f), 3.f);
        float fr0 = v0 - f0, fr1 = v1 - f1, fr2 = v2 - f2;
        int i0 = (int)f0, i1 = (int)f1, i2 = (int)f2;
        #pragma unroll
        for (int b = 0; b < 8; b++){
            int b0 = (b >> 2) & 1, b1 = (b >> 1) & 1, b2 = b & 1;
            float w = (b0 ? fr0 : 1.f - fr0) * (b1 ? fr1 : 1.f - fr1) * (b2 ? fr2 : 1.f - fr2);
            w *= xv;
            int k = ((i0 + b0)*5 + (i1 + b1))*5 + (i2 + b2);
            const float* Wr = &Ws[k*17];
            #pragma unroll
            for (int o = 0; o < 16; o++) agg[o] += w * Wr[o];
        }
    }

    float deg = fmaxf((float)(r1 - r0), 1.0f);
    float xs = x[n];
    float qv0 = lin_b[0], qv1 = lin_b[1], qv2 = lin_b[2], qv3 = lin_b[3];
    #pragma unroll
    for (int o = 0; o < 16; o++){
        float h = agg[o] / deg + xs * root[o] + bias[o];
        float e = (h > 0.f) ? h : expm1f(h);
        qv0 += e * lin_w[o*4 + 0];
        qv1 += e * lin_w[o*4 + 1];
        qv2 += e * lin_w[o*4 + 2];
        qv3 += e * lin_w[o*4 + 3];
    }
    float inv = 1.0f / (sqrtf(qv0*qv0 + qv1*qv1 + qv2*qv2 + qv3*qv3) + EPS);
    pose[(size_t)n*4 + 0] = qv0*inv;
    pose[(size_t)n*4 + 1] = qv1*inv;
    pose[(size_t)n*4 + 2] = qv2*inv;
    pose[(size_t)n*4 + 3] = qv3*inv;
    act[n] = xs;
}

// ====== capsule routing — cooperative, NPB nodes per block ======
template<int I, int J, int NPB>
__global__ __launch_bounds__(NPB*I*J)
void caps_coop_kernel(const float* __restrict__ poseIn, const float* __restrict__ actIn,
                      const float* __restrict__ q, float* __restrict__ poseOut,
                      float* __restrict__ actOut, int N){
    const int IJ = I*J;
    const int tid = threadIdx.x;
    const int nl  = tid / IJ;
    const int li  = tid - nl*IJ;
    const int i   = li / J;
    const int j   = li - i*J;
    const int node = blockIdx.x*NPB + nl;
    const bool on = (node < N);

    __shared__ float redA[NPB][I*J];
    __shared__ float redB[NPB][I*J];
    __shared__ float cp[NPB][I*J*4];
    __shared__ float vsh[NPB][J*4];

    float prx=0.f, pry=0.f, prz=0.f, prw=0.f, ai=0.f;
    if (on){
        float qx = q[li*4+0], qy = q[li*4+1], qz = q[li*4+2], qw = q[li*4+3];
        float qinv = 1.0f/(sqrtf(qx*qx+qy*qy+qz*qz+qw*qw)+EPS);
        qx*=qinv; qy*=qinv; qz*=qinv; qw*=qinv;
        const float* pp = &poseIn[((size_t)node*I + i)*4];
        float rx=pp[0], ry=pp[1], rz=pp[2], rw=pp[3];
        ai = actIn[(size_t)node*I + i];
        float tx = qw*rx + qx*rw + qy*rz - qz*ry;
        float ty = qw*ry - qx*rz + qy*rw + qz*rx;
        float tz = qw*rz + qx*ry - qy*rx + qz*rw;
        float tw = qw*rw - qx*rx - qy*ry - qz*rz;
        float pinv = 1.0f/(sqrtf(tx*tx+ty*ty+tz*tz+tw*tw)+EPS);
        prx=tx*pinv; pry=ty*pinv; prz=tz*pinv; prw=tw*pinv;
    }

    float b = 0.f, c = 0.f;
    for (int t = 0; t < 3; t++){
        redA[nl][li] = b;
        __syncthreads();
        float mb = -INFINITY;
        #pragma unroll
        for (int jj = 0; jj < J; jj++) mb = fmaxf(mb, redA[nl][i*J+jj]);
        float e = expf(b - mb);
        redB[nl][li] = e;
        __syncthreads();
        float s = 0.f;
        #pragma unroll
        for (int jj = 0; jj < J; jj++) s += redB[nl][i*J+jj];
        c = ai * e / s;
        cp[nl][li*4+0] = c*prx; cp[nl][li*4+1] = c*pry;
        cp[nl][li*4+2] = c*prz; cp[nl][li*4+3] = c*prw;
        __syncthreads();
        for (int idx = li; idx < J*4; idx += IJ){
            int jj = idx >> 2, comp = idx & 3;
            float acc = 0.f;
            #pragma unroll
            for (int ii = 0; ii < I; ii++) acc += cp[nl][(ii*J+jj)*4+comp];
            vsh[nl][idx] = acc;
        }
        __syncthreads();
        if (li < J){
            float a0=vsh[nl][li*4], a1=vsh[nl][li*4+1], a2=vsh[nl][li*4+2], a3=vsh[nl][li*4+3];
            float inv = 1.0f/(sqrtf(a0*a0+a1*a1+a2*a2+a3*a3)+EPS);
            vsh[nl][li*4]=a0*inv; vsh[nl][li*4+1]=a1*inv;
            vsh[nl][li*4+2]=a2*inv; vsh[nl][li*4+3]=a3*inv;
        }
        __syncthreads();
        if (t < 2){
            b += prx*vsh[nl][j*4] + pry*vsh[nl][j*4+1] + prz*vsh[nl][j*4+2] + prw*vsh[nl][j*4+3];
            __syncthreads();
        } else {
            redA[nl][li] = c*(prx*vsh[nl][j*4] + pry*vsh[nl][j*4+1]
                            + prz*vsh[nl][j*4+2] + prw*vsh[nl][j*4+3]);
            __syncthreads();
            if (li < J && on){
                float acc = 0.f;
                #pragma unroll
                for (int ii = 0; ii < I; ii++) acc += redA[nl][ii*J+li];
                actOut[(size_t)node*J + li] = sigmoidf_(acc);
                poseOut[((size_t)node*J+li)*4+0] = vsh[nl][li*4+0];
                poseOut[((size_t)node*J+li)*4+1] = vsh[nl][li*4+1];
                poseOut[((size_t)node*J+li)*4+2] = vsh[nl][li*4+2];
                poseOut[((size_t)node*J+li)*4+3] = vsh[nl][li*4+3];
            }
        }
    }
}

// ================= pooling (shared helpers) =================
__device__ __forceinline__ int voxel_id(const float* __restrict__ pos, int n, int G,
                                        float start, float size){
    int g[3];
    #pragma unroll
    for (int k = 0; k < 3; k++){
        float gg = floorf((pos[(size_t)n*3 + k] - start) / size);
        gg = fminf(fmaxf(gg, 0.f), (float)(G - 1));
        g[k] = (int)gg;
    }
    return (g[0]*G + g[1])*G + g[2];
}

__device__ __forceinline__ void pool_geom(const unsigned* mm, int G, int mode,
                                          float& start, float& size){
    float mn = u2f_(mm[0]), mx = u2f_(mm[1]);
    if (mode == 0){ start = mn; size = (mx + 0.001f - mn) / (float)G; }
    else          { start = mn - 0.5f; size = mx - mn + 1.0f; }
}

// ---------- pool1 (large V) : CSR-gather path (no float atomics) ----------
__global__ void vid_kernel(const float* __restrict__ pos, int* __restrict__ vid,
                           int* __restrict__ hist, int N, int G, int mode,
                           const unsigned* __restrict__ mm){
    int n = blockIdx.x*blockDim.x + threadIdx.x;
    if (n >= N) return;
    float start, size; pool_geom(mm, G, mode, start, size);
    int v = voxel_id(pos, n, G, start, size);
    vid[n] = v;
    atomicAdd(&hist[v], 1);
}

__global__ void nscatter_kernel(const int* __restrict__ vid, int* __restrict__ cursor,
                                int* __restrict__ nidx, int N){
    int n = blockIdx.x*blockDim.x + threadIdx.x;
    if (n >= N) return;
    int slot = atomicAdd(&cursor[vid[n]], 1);
    nidx[slot] = n;
}

// one thread per voxel: full pool computation in registers, outputs written directly
template<int J>
__global__ __launch_bounds__(256)
void pool1_gather_kernel(const float* __restrict__ pose, const float* __restrict__ act,
                         const float* __restrict__ pos,
                         const int* __restrict__ nidx, const int* __restrict__ vrow,
                         float* __restrict__ poseOut, float* __restrict__ actOut,
                         float* __restrict__ posOut, int V){
    int v = blockIdx.x*blockDim.x + threadIdx.x;
    if (v >= V) return;
    int r0 = vrow[v], r1 = vrow[v+1];

    float s[J][4], w[J], ps0=0.f, ps1=0.f, ps2=0.f;
    #pragma unroll
    for (int j = 0; j < J; j++){ s[j][0]=0.f; s[j][1]=0.f; s[j][2]=0.f; s[j][3]=0.f; w[j]=0.f; }

    for (int r = r0; r < r1; r++){
        int n = nidx[r];
        const float* pb = &pose[(size_t)n*J*4];
        const float* ab = &act[(size_t)n*J];
        #pragma unroll
        for (int j = 0; j < J; j++){
            float aj = ab[j];
            s[j][0] += aj*pb[j*4+0];
            s[j][1] += aj*pb[j*4+1];
            s[j][2] += aj*pb[j*4+2];
            s[j][3] += aj*pb[j*4+3];
            w[j] += aj;
        }
        ps0 += pos[(size_t)n*3+0];
        ps1 += pos[(size_t)n*3+1];
        ps2 += pos[(size_t)n*3+2];
    }
    // m = normalize(s) in place
    #pragma unroll
    for (int j = 0; j < J; j++){
        float inv = 1.0f/(sqrtf(s[j][0]*s[j][0]+s[j][1]*s[j][1]+
                                s[j][2]*s[j][2]+s[j][3]*s[j][3])+EPS);
        s[j][0]*=inv; s[j][1]*=inv; s[j][2]*=inv; s[j][3]*=inv;
    }
    // pass 2: agreement
    float ag[J];
    #pragma unroll
    for (int j = 0; j < J; j++) ag[j] = 0.f;
    for (int r = r0; r < r1; r++){
        int n = nidx[r];
        const float* pb = &pose[(size_t)n*J*4];
        const float* ab = &act[(size_t)n*J];
        #pragma unroll
        for (int j = 0; j < J; j++){
            float agree = pb[j*4+0]*s[j][0] + pb[j*4+1]*s[j][1]
                        + pb[j*4+2]*s[j][2] + pb[j*4+3]*s[j][3];
            ag[j] += ab[j]*agree;
        }
    }
    #pragma unroll
    for (int j = 0; j < J; j++){
        size_t o = (size_t)v*J + j;
        actOut[o] = sigmoidf_(ag[j] / (w[j] + EPS));
        poseOut[o*4+0] = s[j][0];
        poseOut[o*4+1] = s[j][1];
        poseOut[o*4+2] = s[j][2];
        poseOut[o*4+3] = s[j][3];
    }
    float c = (float)(r1 - r0) + EPS;
    posOut[(size_t)v*3+0] = ps0 / c;
    posOut[(size_t)v*3+1] = ps1 / c;
    posOut[(size_t)v*3+2] = ps2 / c;
}

// ---------- pool2 (mid V) : multi-block LDS-privatized, global-atomic merge ----------
template<int V, int J, int CH, int NCHUNK>
__global__ void pool_priv1(const float4* __restrict__ poseIn, const float* __restrict__ actIn,
                           const float* __restrict__ posIn,
                           float* __restrict__ s, float* __restrict__ wsum,
                           float* __restrict__ cnt, float* __restrict__ psum,
                           int N, int G, int mode, const unsigned* __restrict__ mm){
    __shared__ float s_[V*CH*4];
    __shared__ float wsum_[V*CH];
    __shared__ float cnt_[V];
    __shared__ float psum_[V*3];
    const int chunk = blockIdx.x % NCHUNK;
    const int slice = blockIdx.x / NCHUNK;
    const int nslices = gridDim.x / NCHUNK;
    const int c0 = chunk * CH;

    for (int t = threadIdx.x; t < V*CH*4; t += blockDim.x) s_[t] = 0.f;
    for (int t = threadIdx.x; t < V*CH; t += blockDim.x) wsum_[t] = 0.f;
    if (chunk == 0){
        for (int t = threadIdx.x; t < V; t += blockDim.x) cnt_[t] = 0.f;
        for (int t = threadIdx.x; t < V*3; t += blockDim.x) psum_[t] = 0.f;
    }
    __syncthreads();

    float start, size; pool_geom(mm, G, mode, start, size);
    int per = (N + nslices - 1) / nslices;
    int n0 = slice * per, n1 = min(N, n0 + per);

    for (int n = n0 + (int)threadIdx.x; n < n1; n += blockDim.x){
        int vid = voxel_id(posIn, n, G, start, size);
        #pragma unroll
        for (int jj = 0; jj < CH; jj++){
            int j = c0 + jj;
            float aj = actIn[(size_t)n*J + j];
            float4 p = poseIn[(size_t)n*J + j];
            int b = (vid*CH + jj)*4;
            atomicAdd(&s_[b+0], aj*p.x);
            atomicAdd(&s_[b+1], aj*p.y);
            atomicAdd(&s_[b+2], aj*p.z);
            atomicAdd(&s_[b+3], aj*p.w);
            atomicAdd(&wsum_[vid*CH + jj], aj);
        }
        if (chunk == 0){
            atomicAdd(&cnt_[vid], 1.0f);
            atomicAdd(&psum_[vid*3+0], posIn[(size_t)n*3+0]);
            atomicAdd(&psum_[vid*3+1], posIn[(size_t)n*3+1]);
            atomicAdd(&psum_[vid*3+2], posIn[(size_t)n*3+2]);
        }
    }
    __syncthreads();

    for (int t = threadIdx.x; t < V*CH*4; t += blockDim.x){
        float val = s_[t];
        if (val != 0.f){
            int v = t / (CH*4), r = t % (CH*4);
            atomicAdd(&s[((size_t)v*J + c0)*4 + r], val);
        }
    }
    for (int t = threadIdx.x; t < V*CH; t += blockDim.x){
        float val = wsum_[t];
        if (val != 0.f){
            int v = t / CH, jj = t % CH;
            atomicAdd(&wsum[(size_t)v*J + c0 + jj], val);
        }
    }
    if (chunk == 0){
        for (int t = threadIdx.x; t < V; t += blockDim.x)
            if (cnt_[t] != 0.f) atomicAdd(&cnt[t], cnt_[t]);
        for (int t = threadIdx.x; t < V*3; t += blockDim.x)
            if (psum_[t] != 0.f) atomicAdd(&psum[t], psum_[t]);
    }
}

template<int V, int J>
__global__ void pool_priv2(const float4* __restrict__ poseIn, const float* __restrict__ actIn,
                           const float* __restrict__ posIn, const float4* __restrict__ m,
                           float* __restrict__ agacc,
                           int N, int G, int mode, const unsigned* __restrict__ mm){
    __shared__ float ag_[V*J];
    for (int t = threadIdx.x; t < V*J; t += blockDim.x) ag_[t] = 0.f;
    __syncthreads();
    float start, size; pool_geom(mm, G, mode, start, size);
    int nslices = gridDim.x;
    int per = (N + nslices - 1) / nslices;
    int n0 = blockIdx.x * per, n1 = min(N, n0 + per);
    for (int n = n0 + (int)threadIdx.x; n < n1; n += blockDim.x){
        int vid = voxel_id(posIn, n, G, start, size);
        #pragma unroll
        for (int j = 0; j < J; j++){
            float4 p  = poseIn[(size_t)n*J + j];
            float4 mv = m[(size_t)vid*J + j];
            float agree = p.x*mv.x + p.y*mv.y + p.z*mv.z + p.w*mv.w;
            atomicAdd(&ag_[vid*J + j], actIn[(size_t)n*J + j]*agree);
        }
    }
    __syncthreads();
    for (int t = threadIdx.x; t < V*J; t += blockDim.x)
        if (ag_[t] != 0.f) atomicAdd(&agacc[t], ag_[t]);
}

__global__ void pool_m(const float* __restrict__ s, float* __restrict__ m, int VJ){
    int t = blockIdx.x*blockDim.x + threadIdx.x;
    if (t >= VJ) return;
    float a = s[(size_t)t*4], b = s[(size_t)t*4+1], c = s[(size_t)t*4+2], d = s[(size_t)t*4+3];
    float inv = 1.0f / (sqrtf(a*a + b*b + c*c + d*d) + EPS);
    m[(size_t)t*4]   = a*inv;
    m[(size_t)t*4+1] = b*inv;
    m[(size_t)t*4+2] = c*inv;
    m[(size_t)t*4+3] = d*inv;
}

__global__ void pool_fin(const float* __restrict__ agacc, const float* __restrict__ wsum,
                         const float* __restrict__ cnt, const float* __restrict__ psum,
                         float* __restrict__ actOut, float* __restrict__ posOut, int V, int J){
    int t = blockIdx.x*blockDim.x + threadIdx.x;
    if (t >= V*J) return;
    int v = t / J, j = t % J;
    actOut[t] = sigmoidf_(agacc[t] / (wsum[t] + EPS));
    if (j == 0){
        float c = cnt[v] + EPS;
        posOut[(size_t)v*3 + 0] = psum[(size_t)v*3 + 0] / c;
        posOut[(size_t)v*3 + 1] = psum[(size_t)v*3 + 1] / c;
        posOut[(size_t)v*3 + 2] = psum[(size_t)v*3 + 2] / c;
    }
}

// ---------- pools 3-4 (tiny) : single fused LDS kernel ----------
template<int V, int J, int CH>
__global__ void pool_fused_kernel(const float* __restrict__ poseIn, const float* __restrict__ actIn,
                                  const float* __restrict__ posIn,
                                  float* __restrict__ poseOut, float* __restrict__ actOut,
                                  float* __restrict__ posOut,
                                  int N, int G, int mode, const unsigned* __restrict__ mm){
    __shared__ float s_[V*CH*4];
    __shared__ float wsum_[V*CH];
    __shared__ float ag_[V*CH];
    __shared__ float cnt_[V];
    __shared__ float psum_[V*3];
    const int c0 = blockIdx.x * CH;

    for (int t = threadIdx.x; t < V*CH*4; t += blockDim.x) s_[t] = 0.f;
    for (int t = threadIdx.x; t < V*CH; t += blockDim.x){ wsum_[t] = 0.f; ag_[t] = 0.f; }
    if (blockIdx.x == 0){
        for (int t = threadIdx.x; t < V; t += blockDim.x) cnt_[t] = 0.f;
        for (int t = threadIdx.x; t < V*3; t += blockDim.x) psum_[t] = 0.f;
    }
    __syncthreads();

    float start, size; pool_geom(mm, G, mode, start, size);

    for (int n = threadIdx.x; n < N; n += blockDim.x){
        int vid = voxel_id(posIn, n, G, start, size);
        #pragma unroll
        for (int jj = 0; jj < CH; jj++){
            int j = c0 + jj;
            float aj = actIn[(size_t)n*J + j];
            const float* pb = &poseIn[((size_t)n*J + j)*4];
            int b = (vid*CH + jj)*4;
            atomicAdd(&s_[b+0], aj*pb[0]);
            atomicAdd(&s_[b+1], aj*pb[1]);
            atomicAdd(&s_[b+2], aj*pb[2]);
            atomicAdd(&s_[b+3], aj*pb[3]);
            atomicAdd(&wsum_[vid*CH + jj], aj);
        }
        if (blockIdx.x == 0){
            atomicAdd(&cnt_[vid], 1.0f);
            atomicAdd(&psum_[vid*3+0], posIn[(size_t)n*3+0]);
            atomicAdd(&psum_[vid*3+1], posIn[(size_t)n*3+1]);
            atomicAdd(&psum_[vid*3+2], posIn[(size_t)n*3+2]);
        }
    }
    __syncthreads();

    for (int t = threadIdx.x; t < V*CH; t += blockDim.x){
        float a = s_[t*4], b = s_[t*4+1], c = s_[t*4+2], d = s_[t*4+3];
        float inv = 1.0f / (sqrtf(a*a + b*b + c*c + d*d) + EPS);
        s_[t*4] = a*inv; s_[t*4+1] = b*inv; s_[t*4+2] = c*inv; s_[t*4+3] = d*inv;
    }
    __syncthreads();

    for (int n = threadIdx.x; n < N; n += blockDim.x){
        int vid = voxel_id(posIn, n, G, start, size);
        #pragma unroll
        for (int jj = 0; jj < CH; jj++){
            int j = c0 + jj;
            const float* pb = &poseIn[((size_t)n*J + j)*4];
            const float* mb = &s_[(vid*CH + jj)*4];
            float agree = pb[0]*mb[0] + pb[1]*mb[1] + pb[2]*mb[2] + pb[3]*mb[3];
            atomicAdd(&ag_[vid*CH + jj], actIn[(size_t)n*J + j]*agree);
        }
    }
    __syncthreads();

    for (int t = threadIdx.x; t < V*CH; t += blockDim.x){
        int v = t / CH, jj = t % CH;
        size_t o = (size_t)v*J + c0 + jj;
        actOut[o] = sigmoidf_(ag_[t] / (wsum_[t] + EPS));
        poseOut[o*4+0] = s_[t*4+0];
        poseOut[o*4+1] = s_[t*4+1];
        poseOut[o*4+2] = s_[t*4+2];
        poseOut[o*4+3] = s_[t*4+3];
    }
    if (blockIdx.x == 0){
        for (int v = threadIdx.x; v < V; v += blockDim.x){
            float c = cnt_[v] + EPS;
            posOut[(size_t)v*3+0] = psum_[(size_t)v*3+0] / c;
            posOut[(size_t)v*3+1] = psum_[(size_t)v*3+1] / c;
            posOut[(size_t)v*3+2] = psum_[(size_t)v*3+2] / c;
        }
    }
}

extern "C" void kernel_launch(void* const* d_in, const int* in_sizes, int n_in,
                              void* d_out, int out_size, void* d_ws, size_t ws_size,
                              hipStream_t stream){
    const float* x      = (const float*)d_in[0];
    const float* pos    = (const float*)d_in[1];
    const float* pseudo = (const float*)d_in[2];
    const float* Wsp    = (const float*)d_in[3];
    const float* root   = (const float*)d_in[4];
    const float* bias   = (const float*)d_in[5];
    const float* lin_w  = (const float*)d_in[6];
    const float* lin_b  = (const float*)d_in[7];
    const float* q0     = (const float*)d_in[8];
    const float* q1     = (const float*)d_in[9];
    const float* q3     = (const float*)d_in[10];
    const float* q5     = (const float*)d_in[11];
    const float* q6     = (const float*)d_in[12];
    const float* q7     = (const float*)d_in[13];
    const int*   ei     = (const int*)d_in[14];
    const int N = in_sizes[0];
    const int E = in_sizes[2] / 3;
    const int V1 = 32768;

    char* ws = (char*)d_ws;
    size_t off = 0;
    auto alloc = [&](size_t bytes)->void*{
        void* p = ws + off;
        off += (bytes + 255) & ~(size_t)255;
        return p;
    };
    unsigned* mm   = (unsigned*)alloc(8);
    int* ecnt      = (int*)alloc((size_t)N*sizeof(int));
    int* rowptr    = (int*)alloc((size_t)(N+1)*sizeof(int));
    int* cursor    = (int*)alloc((size_t)N*sizeof(int));
    float4* payload= (float4*)alloc((size_t)E*sizeof(float4));
    int* vid       = (int*)alloc((size_t)N*sizeof(int));
    int* vhist     = (int*)alloc((size_t)V1*sizeof(int));
    int* vrow      = (int*)alloc((size_t)(V1+1)*sizeof(int));
    int* vcursor   = (int*)alloc((size_t)V1*sizeof(int));
    int* nidx      = (int*)alloc((size_t)N*sizeof(int));
    float* P0  = (float*)alloc((size_t)1250000*sizeof(float));
    float* P1  = (float*)alloc((size_t)1250000*sizeof(float));
    float* A0  = (float*)alloc((size_t)310000*sizeof(float));
    float* A1  = (float*)alloc((size_t)310000*sizeof(float));
    float* PB0 = (float*)alloc((size_t)100000*sizeof(float));
    float* PB1 = (float*)alloc((size_t)100000*sizeof(float));
    size_t pool_off0 = off;
    float* vs  = (float*)alloc((size_t)800000*sizeof(float));
    float* vw  = (float*)alloc((size_t)200000*sizeof(float));
    float* va  = (float*)alloc((size_t)200000*sizeof(float));
    float* vc  = (float*)alloc((size_t)33000*sizeof(float));
    float* vp  = (float*)alloc((size_t)100000*sizeof(float));
    size_t pool_bytes = off - pool_off0;

    hipMemsetAsync(mm,     0xFF, 4, stream);
    hipMemsetAsync(mm + 1, 0x00, 4, stream);
    hipMemsetAsync(ecnt, 0, (size_t)N*sizeof(int), stream);
    hipMemsetAsync(vhist, 0, (size_t)V1*sizeof(int), stream);

    minmax_kernel<<<80, 256, 0, stream>>>(pos, N*3, mm);

    // CSR build + fused spline gather / node finalize (no float atomics)
    hist_kernel<<<(E + 255)/256, 256, 0, stream>>>(ei, ecnt, E);
    scan_kernel<<<1, 1024, 0, stream>>>(ecnt, rowptr, cursor, N);
    scatter_kernel<<<(E + 255)/256, 256, 0, stream>>>(pseudo, ei, cursor, payload, E);
    spline_node_kernel<<<(N + 255)/256, 256, 0, stream>>>(x, payload, rowptr, Wsp,
                                                          root, bias, lin_w, lin_b, P0, A0, N);

    // capsule layers: all cooperative (spill-free)
    caps_coop_kernel<1,6,32><<<(N + 31)/32, 32*6, 0, stream>>>(P0, A0, q0, P1, A1, N);
    caps_coop_kernel<6,6,7><<<(N + 6)/7, 7*36, 0, stream>>>(P1, A1, q1, P0, A0, N);

    // pool1: 50000 nodes -> 32768 voxels (G=32), J=6 — CSR-gather (no float atomics)
    {
        const int G = 32;
        vid_kernel<<<(N + 255)/256, 256, 0, stream>>>(pos, vid, vhist, N, G, 0, mm);
        scan_kernel<<<1, 1024, 0, stream>>>(vhist, vrow, vcursor, V1);
        nscatter_kernel<<<(N + 255)/256, 256, 0, stream>>>(vid, vcursor, nidx, N);
        pool1_gather_kernel<6><<<(V1 + 255)/256, 256, 0, stream>>>(P0, A0, pos, nidx, vrow,
                                                                   P1, A1, PB0, V1);
    }
    caps_coop_kernel<6,8,5><<<(32768 + 4)/5, 5*48, 0, stream>>>(P1, A1, q3, P0, A0, 32768);

    // pool2: 32768 -> 512 (G=8), J=8 — multi-block LDS-privatized path
    {
        const int V = 512, J = 8, G = 8, NSL = 16;
        hipMemsetAsync(vs, 0, pool_bytes, stream);
        pool_priv1<V,J,4,2><<<2*NSL, 256, 0, stream>>>((const float4*)P0, A0, PB0,
                                                       vs, vw, vc, vp, 32768, G, 0, mm);
        pool_m<<<(V*J + 255)/256, 256, 0, stream>>>(vs, P1, V*J);
        pool_priv2<V,J><<<NSL, 256, 0, stream>>>((const float4*)P0, A0, PB0,
                                                 (const float4*)P1, va, 32768, G, 0, mm);
        pool_fin<<<(V*J + 255)/256, 256, 0, stream>>>(va, vw, vc, vp, A1, PB1, V, J);
    }
    caps_coop_kernel<8,12,2><<<256, 2*96, 0, stream>>>(P1, A1, q5, P0, A0, 512);

    // pool3: 512 -> 8 (G=2), J=12 — fused LDS path, 1 block
    pool_fused_kernel<8,12,12><<<1, 1024, 0, stream>>>(P0, A0, PB1, P1, A1, PB0, 512, 2, 0, mm);
    caps_coop_kernel<12,14,1><<<8, 168, 0, stream>>>(P1, A1, q6, P0, A0, 8);

    // pool4: 8 -> 1 (G=1, mode=1), J=14 — fused LDS path, 1 block
    pool_fused_kernel<1,14,14><<<1, 1024, 0, stream>>>(P0, A0, PB0, P1, A1, PB1, 8, 1, 1, mm);
    caps_coop_kernel<14,10,1><<<1, 140, 0, stream>>>(P1, A1, q7, P0, (float*)d_out, 1);
}